// Round 1
// baseline (7359.142 us; speedup 1.0000x reference)
//
#include <hip/hip_runtime.h>

#define TPB 256
#define NLB 64   // LSTM blocks

// ---------- helpers ----------
__device__ __forceinline__ float bf2f(unsigned short u) {
  union { unsigned int i; float f; } x; x.i = ((unsigned int)u) << 16; return x.f;
}
__device__ __forceinline__ unsigned short f2bf(float v) {
  union { float f; unsigned int i; } x; x.f = v;
  unsigned int r = (x.i + 0x7fffu + ((x.i >> 16) & 1u)) >> 16;
  return (unsigned short)r;
}
__device__ __forceinline__ float sigf(float x) { return 1.f / (1.f + __expf(-x)); }

// ---------- conv1: fused crop-gather + 3x3 s2 conv + bias ----------
// out: [512][16][64][64], reads full_map directly with crop+pad bounds.
__global__ __launch_bounds__(TPB) void conv1_kernel(
    const float* __restrict__ fmap, const float* __restrict__ iseq,
    const float* __restrict__ w, const float* __restrict__ bias,
    float* __restrict__ out) {
  int o = blockIdx.x * TPB + threadIdx.x;
  if (o >= 512 * 16 * 64 * 64) return;
  int oj = o & 63;
  int oi = (o >> 6) & 63;
  int oc = (o >> 12) & 15;
  int n  = o >> 16;
  int y = (int)iseq[n * 2 + 0];
  int x = (int)iseq[n * 2 + 1];
  int b = n >> 6;
  float acc = bias[oc];
  for (int ic = 0; ic < 3; ++ic) {
    const float* ip = fmap + ((b * 3 + ic) << 20);
    const float* wp = w + (oc * 3 + ic) * 9;
#pragma unroll
    for (int ki = 0; ki < 3; ++ki) {
      int i = 2 * oi - 1 + ki;
      int fr = y + i - 64;
      bool rok = (i >= 0) && (fr >= 0) && (fr < 1024);
#pragma unroll
      for (int kj = 0; kj < 3; ++kj) {
        int j = 2 * oj - 1 + kj;
        int fc = x + j - 64;
        bool ok = rok && (j >= 0) && (fc >= 0) && (fc < 1024);
        float v = ok ? ip[(fr << 10) + fc] : 0.f;
        acc = fmaf(wp[ki * 3 + kj], v, acc);
      }
    }
  }
  out[o] = acc;
}

// ---------- generic stride-2 3x3 conv; input is pre-BN, BN+ReLU applied on load ----------
__global__ __launch_bounds__(TPB) void conv_s2_kernel(
    const float* __restrict__ in, const float* __restrict__ ss,
    const float* __restrict__ w, const float* __restrict__ bias,
    float* __restrict__ out, int Cin, int Cout, int Hin, int Hout, int total) {
  int o = blockIdx.x * TPB + threadIdx.x;
  if (o >= total) return;
  int hw2 = Hout * Hout;
  int oj = o % Hout;
  int oi = (o / Hout) % Hout;
  int t = o / hw2;
  int oc = t % Cout;
  int n  = t / Cout;
  float acc = bias[oc];
  for (int ic = 0; ic < Cin; ++ic) {
    float sc = ss[2 * ic], sh = ss[2 * ic + 1];
    const float* ip = in + (n * Cin + ic) * Hin * Hin;
    const float* wp = w + (oc * Cin + ic) * 9;
#pragma unroll
    for (int ki = 0; ki < 3; ++ki) {
      int ii = 2 * oi - 1 + ki;
      if ((unsigned)ii >= (unsigned)Hin) continue;
      const float* rp = ip + ii * Hin;
#pragma unroll
      for (int kj = 0; kj < 3; ++kj) {
        int jj = 2 * oj - 1 + kj;
        if ((unsigned)jj >= (unsigned)Hin) continue;
        float v = rp[jj];
        v = fmaxf(fmaf(v, sc, sh), 0.f);
        acc = fmaf(wp[ki * 3 + kj], v, acc);
      }
    }
  }
  out[o] = acc;
}

// ---------- BN statistics (deterministic two-stage) ----------
// partial: grid = C*64 blocks; block (c, s) sums n in [s*8, s*8+8)
__global__ __launch_bounds__(TPB) void stats_partial_kernel(
    const float* __restrict__ y, float* __restrict__ part, int C, int HW) {
  int bid = blockIdx.x;
  int c = bid >> 6;
  int s = bid & 63;
  float sum = 0.f, sq = 0.f;
  for (int nn = 0; nn < 8; ++nn) {
    int n = s * 8 + nn;
    const float* p = y + (n * C + c) * HW;
    for (int i = threadIdx.x; i < HW; i += TPB) {
      float v = p[i];
      sum += v; sq = fmaf(v, v, sq);
    }
  }
  __shared__ float rs[TPB], rq[TPB];
  rs[threadIdx.x] = sum; rq[threadIdx.x] = sq;
  __syncthreads();
  for (int off = TPB / 2; off > 0; off >>= 1) {
    if (threadIdx.x < off) { rs[threadIdx.x] += rs[threadIdx.x + off]; rq[threadIdx.x] += rq[threadIdx.x + off]; }
    __syncthreads();
  }
  if (threadIdx.x == 0) { part[bid * 2] = rs[0]; part[bid * 2 + 1] = rq[0]; }
}

// final: grid = C blocks, 64 threads; writes folded (scale, shift)
__global__ void stats_final_kernel(const float* __restrict__ part,
    const float* __restrict__ gamma, const float* __restrict__ beta,
    float* __restrict__ ss, float inv_count) {
  int c = blockIdx.x;
  int t = threadIdx.x;  // 64
  float sum = part[(c * 64 + t) * 2];
  float sq  = part[(c * 64 + t) * 2 + 1];
  for (int off = 32; off > 0; off >>= 1) {
    sum += __shfl_down(sum, off);
    sq  += __shfl_down(sq, off);
  }
  if (t == 0) {
    float mean = sum * inv_count;
    float var  = sq * inv_count - mean * mean;
    float rstd = rsqrtf(var + 1e-5f);
    float scl  = gamma[c] * rstd;
    ss[2 * c] = scl;
    ss[2 * c + 1] = beta[c] - mean * scl;
  }
}

// ---------- elementwise BN+ReLU (only needed for layer 4 before FC) ----------
__global__ __launch_bounds__(TPB) void bnrelu_kernel(float* __restrict__ y,
    const float* __restrict__ ss, int C, int HW, int total) {
  int i = blockIdx.x * TPB + threadIdx.x;
  if (i >= total) return;
  int c = (i / HW) % C;
  y[i] = fmaxf(fmaf(y[i], ss[2 * c], ss[2 * c + 1]), 0.f);
}

// ---------- generic tiled GEMM: out[m,n] = act(sum_k A[m,k]*W[n,k] + b[n]) ----------
__global__ __launch_bounds__(TPB) void gemm_rt(const float* __restrict__ A,
    const float* __restrict__ W, const float* __restrict__ bias,
    float* __restrict__ out, int M, int N, int K, int dorelu) {
  __shared__ float As[32][33];
  __shared__ float Ws[32][33];
  int tid = threadIdx.x;
  int tx = tid & 15, ty = tid >> 4;
  int bm = blockIdx.y << 5, bn = blockIdx.x << 5;
  float a00 = 0.f, a01 = 0.f, a10 = 0.f, a11 = 0.f;
  int nk = (K + 31) >> 5;
  for (int kt = 0; kt < nk; ++kt) {
    int k0 = kt << 5;
#pragma unroll
    for (int l = 0; l < 4; ++l) {
      int idx = tid + (l << 8);
      int r = idx >> 5, c = idx & 31;
      int gc = k0 + c;
      int ga = bm + r;
      As[c][r] = (ga < M && gc < K) ? A[ga * K + gc] : 0.f;
      int gw = bn + r;
      Ws[c][r] = (gw < N && gc < K) ? W[gw * K + gc] : 0.f;
    }
    __syncthreads();
#pragma unroll
    for (int k = 0; k < 32; ++k) {
      float x0 = As[k][ty], x1 = As[k][ty + 16];
      float y0 = Ws[k][tx], y1 = Ws[k][tx + 16];
      a00 = fmaf(x0, y0, a00); a01 = fmaf(x0, y1, a01);
      a10 = fmaf(x1, y0, a10); a11 = fmaf(x1, y1, a11);
    }
    __syncthreads();
  }
  int m0 = bm + ty, m1 = m0 + 16, n0 = bn + tx, n1 = n0 + 16;
  if (m0 < M && n0 < N) { float v = a00 + bias[n0]; out[m0 * N + n0] = dorelu ? fmaxf(v, 0.f) : v; }
  if (m0 < M && n1 < N) { float v = a01 + bias[n1]; out[m0 * N + n1] = dorelu ? fmaxf(v, 0.f) : v; }
  if (m1 < M && n0 < N) { float v = a10 + bias[n0]; out[m1 * N + n0] = dorelu ? fmaxf(v, 0.f) : v; }
  if (m1 < M && n1 < N) { float v = a11 + bias[n1]; out[m1 * N + n1] = dorelu ? fmaxf(v, 0.f) : v; }
}

// ---------- small builders ----------
__global__ __launch_bounds__(TPB) void build_enh_kernel(const float* __restrict__ cond,
    const float* __restrict__ steps, float* __restrict__ enh) {
  int i = blockIdx.x * TPB + threadIdx.x;
  if (i >= 512 * 6) return;
  int n = i / 6, k = i % 6;
  int b = n >> 6, s = n & 63;
  enh[i] = (k < 5) ? cond[b * 5 + k] : steps[b * 64 + s];
}

__global__ __launch_bounds__(TPB) void build_comb_kernel(const float* __restrict__ lo,
    const float* __restrict__ mapf, const float* __restrict__ condf, float* __restrict__ comb) {
  int i = blockIdx.x * TPB + threadIdx.x;
  if (i >= 512 * 576) return;
  int n = i / 576, k = i % 576;
  float v;
  if (k < 256)      v = lo[n * 256 + k];
  else if (k < 512) v = mapf[n * 256 + (k - 256)];
  else              v = condf[n * 64 + (k - 512)];
  comb[i] = v;
}

// ---------- LSTM: 64 blocks, weight-partitioned (4 hidden units/block/layer), ----------
// pipelined: phase p computes layer0 step p and layer1 step p-1; device barrier per phase.
__global__ __launch_bounds__(TPB) void lstm_kernel(
    const float* __restrict__ embv,
    const float* __restrict__ w_ih0, const float* __restrict__ w_hh0,
    const float* __restrict__ b_ih0, const float* __restrict__ b_hh0,
    const float* __restrict__ w_ih1, const float* __restrict__ w_hh1,
    const float* __restrict__ b_ih1, const float* __restrict__ b_hh1,
    float* __restrict__ h0_steps,   // [64][8][256]
    float* __restrict__ lstm_out,   // [8][64][256]
    int* __restrict__ bar) {
  const int tid = threadIdx.x;
  const int u0 = blockIdx.x * 4;

  __shared__ float whh0s[16][260];
  __shared__ float wih1s[16][260];
  __shared__ float whh1s[16][260];
  __shared__ float wih0s[16][32];
  __shared__ unsigned short hps[8][260];   // bf16 h0(prev)
  __shared__ unsigned short h1ps[8][260];  // bf16 h1(prev)
  __shared__ float x0s[8][32];
  __shared__ float zg0s[8][16];
  __shared__ float zg1s[8][16];
  __shared__ float bias0s[16], bias1s[16];
  __shared__ float c0s[8][4], c1s[8][4];

  // stage weights (rows: gate-major, 4 gates x 4 units)
  for (int idx = tid; idx < 16 * 256; idx += TPB) {
    int r = idx >> 8, k = idx & 255;
    int gate = r >> 2, uu = r & 3;
    int R = gate * 256 + u0 + uu;
    whh0s[r][k] = w_hh0[R * 256 + k];
    wih1s[r][k] = w_ih1[R * 256 + k];
    whh1s[r][k] = w_hh1[R * 256 + k];
  }
  for (int idx = tid; idx < 16 * 32; idx += TPB) {
    int r = idx >> 5, k = idx & 31;
    int gate = r >> 2, uu = r & 3;
    int R = gate * 256 + u0 + uu;
    wih0s[r][k] = w_ih0[R * 32 + k];
  }
  if (tid < 16) {
    int gate = tid >> 2, uu = tid & 3;
    int R = gate * 256 + u0 + uu;
    bias0s[tid] = b_ih0[R] + b_hh0[R];
    bias1s[tid] = b_ih1[R] + b_hh1[R];
  }
  if (tid < 32) c0s[tid >> 2][tid & 3] = 0.f;
  else if (tid < 64) { int t = tid - 32; c1s[t >> 2][t & 3] = 0.f; }
  __syncthreads();

  for (int p = 0; p <= 64; ++p) {
    // stage h-states (all units, written by all blocks last phase) + x
    for (int idx = tid; idx < 2048; idx += TPB) {
      int b = idx >> 8, k = idx & 255;
      float h0v = (p == 0) ? 0.f : h0_steps[(p - 1) * 2048 + idx];
      hps[b][k] = f2bf(h0v);
      float h1v = (p < 2) ? 0.f : lstm_out[(b * 64 + (p - 2)) * 256 + k];
      h1ps[b][k] = f2bf(h1v);
    }
    {
      int b = tid >> 5, k = tid & 31;
      x0s[b][k] = (p < 64) ? embv[(b * 64 + p) * 32 + k] : 0.f;
    }
    __syncthreads();

    if (tid < 128) {
      if (p < 64) {                       // layer 0, step p
        int b = tid >> 4, r = tid & 15;
        float acc = bias0s[r];
#pragma unroll
        for (int k = 0; k < 32; k += 4) {
          float4 w4 = *(const float4*)&wih0s[r][k];
          acc = fmaf(w4.x, x0s[b][k],     acc);
          acc = fmaf(w4.y, x0s[b][k + 1], acc);
          acc = fmaf(w4.z, x0s[b][k + 2], acc);
          acc = fmaf(w4.w, x0s[b][k + 3], acc);
        }
        for (int k = 0; k < 256; k += 4) {
          float4 w4 = *(const float4*)&whh0s[r][k];
          ushort4 u = *(const ushort4*)&hps[b][k];
          acc = fmaf(w4.x, bf2f(u.x), acc);
          acc = fmaf(w4.y, bf2f(u.y), acc);
          acc = fmaf(w4.z, bf2f(u.z), acc);
          acc = fmaf(w4.w, bf2f(u.w), acc);
        }
        zg0s[b][r] = acc;
      }
    } else {
      if (p >= 1) {                       // layer 1, step p-1 (input = h0(p-1) = hps)
        int t = tid - 128;
        int b = t >> 4, r = t & 15;
        float acc = bias1s[r];
        for (int k = 0; k < 256; k += 4) {
          float4 wa = *(const float4*)&wih1s[r][k];
          ushort4 ux = *(const ushort4*)&hps[b][k];
          float4 wb = *(const float4*)&whh1s[r][k];
          ushort4 uh = *(const ushort4*)&h1ps[b][k];
          acc = fmaf(wa.x, bf2f(ux.x), acc);
          acc = fmaf(wa.y, bf2f(ux.y), acc);
          acc = fmaf(wa.z, bf2f(ux.z), acc);
          acc = fmaf(wa.w, bf2f(ux.w), acc);
          acc = fmaf(wb.x, bf2f(uh.x), acc);
          acc = fmaf(wb.y, bf2f(uh.y), acc);
          acc = fmaf(wb.z, bf2f(uh.z), acc);
          acc = fmaf(wb.w, bf2f(uh.w), acc);
        }
        zg1s[b][r] = acc;
      }
    }
    __syncthreads();

    if (tid < 32 && p < 64) {             // layer 0 state update
      int b = tid >> 2, uu = tid & 3;
      float zi = zg0s[b][uu], zf = zg0s[b][4 + uu], zg = zg0s[b][8 + uu], zo = zg0s[b][12 + uu];
      float c = sigf(zf) * c0s[b][uu] + sigf(zi) * tanhf(zg);
      c0s[b][uu] = c;
      h0_steps[p * 2048 + b * 256 + u0 + uu] = sigf(zo) * tanhf(c);
    }
    if (tid >= 32 && tid < 64 && p >= 1) { // layer 1 state update
      int t = tid - 32;
      int b = t >> 2, uu = t & 3;
      float zi = zg1s[b][uu], zf = zg1s[b][4 + uu], zg = zg1s[b][8 + uu], zo = zg1s[b][12 + uu];
      float c = sigf(zf) * c1s[b][uu] + sigf(zi) * tanhf(zg);
      c1s[b][uu] = c;
      lstm_out[(b * 64 + (p - 1)) * 256 + u0 + uu] = sigf(zo) * tanhf(c);
    }

    // device-scope barrier (per-phase counter; zeroed by memset each launch)
    __syncthreads();
    if (tid == 0) {
      __threadfence();
      atomicAdd(&bar[p], 1);
      while (__hip_atomic_load(&bar[p], __ATOMIC_ACQUIRE, __HIP_MEMORY_SCOPE_AGENT) < NLB) {
        __builtin_amdgcn_s_sleep(2);
      }
      __threadfence();
    }
    __syncthreads();
  }
}

// ---------- launcher ----------
extern "C" void kernel_launch(void* const* d_in, const int* in_sizes, int n_in,
                              void* d_out, int out_size, void* d_ws, size_t ws_size,
                              hipStream_t stream) {
  const float* fmap  = (const float*)d_in[0];
  const float* cond  = (const float*)d_in[1];
  const float* iseq  = (const float*)d_in[2];
  const float* steps = (const float*)d_in[3];
  const float* cw1 = (const float*)d_in[4];  const float* cb1 = (const float*)d_in[5];
  const float* g1  = (const float*)d_in[6];  const float* be1 = (const float*)d_in[7];
  const float* cw2 = (const float*)d_in[8];  const float* cb2 = (const float*)d_in[9];
  const float* g2  = (const float*)d_in[10]; const float* be2 = (const float*)d_in[11];
  const float* cw3 = (const float*)d_in[12]; const float* cb3 = (const float*)d_in[13];
  const float* g3  = (const float*)d_in[14]; const float* be3 = (const float*)d_in[15];
  const float* cw4 = (const float*)d_in[16]; const float* cb4 = (const float*)d_in[17];
  const float* g4  = (const float*)d_in[18]; const float* be4 = (const float*)d_in[19];
  const float* fw1 = (const float*)d_in[20]; const float* fb1 = (const float*)d_in[21];
  const float* fw2 = (const float*)d_in[22]; const float* fb2 = (const float*)d_in[23];
  const float* ew1 = (const float*)d_in[24]; const float* eb1 = (const float*)d_in[25];
  const float* ew2 = (const float*)d_in[26]; const float* eb2 = (const float*)d_in[27];
  const float* mw  = (const float*)d_in[28]; const float* mb  = (const float*)d_in[29];
  const float* w_ih0 = (const float*)d_in[30]; const float* w_hh0 = (const float*)d_in[31];
  const float* b_ih0 = (const float*)d_in[32]; const float* b_hh0 = (const float*)d_in[33];
  const float* w_ih1 = (const float*)d_in[34]; const float* w_hh1 = (const float*)d_in[35];
  const float* b_ih1 = (const float*)d_in[36]; const float* b_hh1 = (const float*)d_in[37];
  const float* xw1 = (const float*)d_in[38]; const float* xb1 = (const float*)d_in[39];
  const float* xw2 = (const float*)d_in[40]; const float* xb2 = (const float*)d_in[41];
  const float* ow  = (const float*)d_in[42]; const float* ob  = (const float*)d_in[43];

  float* ws = (float*)d_ws;
  // big buffers with reuse: y3 overlays y1, y4 overlays y2
  float* y1 = ws;                    // 33,554,432 f
  float* y2 = ws + 33554432;         // 16,777,216 f
  float* y3 = ws;                    //  8,388,608 f (y1 dead)
  float* y4 = ws + 33554432;         //  4,194,304 f (y2 dead)
  size_t base = 50331648;
  float* part  = ws + base; base += 16384;
  float* ss1   = ws + base; base += 32;
  float* ss2   = ws + base; base += 64;
  float* ss3   = ws + base; base += 128;
  float* ss4   = ws + base; base += 256;
  float* f1    = ws + base; base += 262144;
  float* mapf  = ws + base; base += 131072;
  float* enh   = ws + base; base += 3072;
  float* ceh   = ws + base; base += 65536;
  float* condf = ws + base; base += 32768;
  float* embb  = ws + base; base += 16384;
  float* h0st  = ws + base; base += 131072;
  float* lout  = ws + base; base += 131072;
  float* comb  = ws + base; base += 294912;
  float* cx1   = ws + base; base += 65536;
  float* cx2   = ws + base; base += 32768;
  int*   bar   = (int*)(ws + base); base += 128;

  // --- encoder convs with batch-stat BN folded to scale/shift ---
  conv1_kernel<<<131072, TPB, 0, stream>>>(fmap, iseq, cw1, cb1, y1);
  stats_partial_kernel<<<16 * 64, TPB, 0, stream>>>(y1, part, 16, 4096);
  stats_final_kernel<<<16, 64, 0, stream>>>(part, g1, be1, ss1, 1.f / 2097152.f);
  conv_s2_kernel<<<65536, TPB, 0, stream>>>(y1, ss1, cw2, cb2, y2, 16, 32, 64, 32, 16777216);
  stats_partial_kernel<<<32 * 64, TPB, 0, stream>>>(y2, part, 32, 1024);
  stats_final_kernel<<<32, 64, 0, stream>>>(part, g2, be2, ss2, 1.f / 524288.f);
  conv_s2_kernel<<<32768, TPB, 0, stream>>>(y2, ss2, cw3, cb3, y3, 32, 64, 32, 16, 8388608);
  stats_partial_kernel<<<64 * 64, TPB, 0, stream>>>(y3, part, 64, 256);
  stats_final_kernel<<<64, 64, 0, stream>>>(part, g3, be3, ss3, 1.f / 131072.f);
  conv_s2_kernel<<<16384, TPB, 0, stream>>>(y3, ss3, cw4, cb4, y4, 64, 128, 16, 8, 4194304);
  stats_partial_kernel<<<128 * 64, TPB, 0, stream>>>(y4, part, 128, 64);
  stats_final_kernel<<<128, 64, 0, stream>>>(part, g4, be4, ss4, 1.f / 32768.f);
  bnrelu_kernel<<<16384, TPB, 0, stream>>>(y4, ss4, 128, 64, 4194304);

  // --- map-feature MLP ---
  gemm_rt<<<dim3(16, 16), TPB, 0, stream>>>(y4, fw1, fb1, f1, 512, 512, 8192, 1);
  gemm_rt<<<dim3(8, 16),  TPB, 0, stream>>>(f1, fw2, fb2, mapf, 512, 256, 512, 0);

  // --- condition encoder ---
  build_enh_kernel<<<12, TPB, 0, stream>>>(cond, steps, enh);
  gemm_rt<<<dim3(4, 16), TPB, 0, stream>>>(enh, ew1, eb1, ceh, 512, 128, 6, 1);
  gemm_rt<<<dim3(2, 16), TPB, 0, stream>>>(ceh, ew2, eb2, condf, 512, 64, 128, 0);

  // --- coord embed + LSTM ---
  gemm_rt<<<dim3(1, 16), TPB, 0, stream>>>(iseq, mw, mb, embb, 512, 32, 2, 1);
  hipMemsetAsync(bar, 0, 65 * sizeof(int), stream);
  lstm_kernel<<<NLB, TPB, 0, stream>>>(embb, w_ih0, w_hh0, b_ih0, b_hh0,
                                       w_ih1, w_hh1, b_ih1, b_hh1, h0st, lout, bar);

  // --- head ---
  build_comb_kernel<<<1152, TPB, 0, stream>>>(lout, mapf, condf, comb);
  gemm_rt<<<dim3(4, 16), TPB, 0, stream>>>(comb, xw1, xb1, cx1, 512, 128, 576, 1);
  gemm_rt<<<dim3(2, 16), TPB, 0, stream>>>(cx1, xw2, xb2, cx2, 512, 64, 128, 1);
  gemm_rt<<<dim3(1, 16), TPB, 0, stream>>>(cx2, ow, ob, (float*)d_out, 512, 2, 64, 0);
}

// Round 2
// 2495.643 us; speedup vs baseline: 2.9488x; 2.9488x over previous
//
#include <hip/hip_runtime.h>

#define TPB 256
#define NLB 64   // LSTM blocks

// ---------- helpers ----------
__device__ __forceinline__ float bf2f(unsigned short u) {
  union { unsigned int i; float f; } x; x.i = ((unsigned int)u) << 16; return x.f;
}
__device__ __forceinline__ unsigned short f2bf(float v) {
  union { float f; unsigned int i; } x; x.f = v;
  unsigned int r = (x.i + 0x7fffu + ((x.i >> 16) & 1u)) >> 16;
  return (unsigned short)r;
}
__device__ __forceinline__ float sigf(float x) { return 1.f / (1.f + __expf(-x)); }

// ================= conv1: fused crop-gather + 3x3 s2 conv (tiled) =================
// grid 2048 = 512 crops x 4 row-quarters (16 out rows each). out [512][16][64][64].
__global__ __launch_bounds__(TPB, 2) void conv1_tiled(
    const float* __restrict__ fmap, const float* __restrict__ iseq,
    const float* __restrict__ w, const float* __restrict__ bias,
    float* __restrict__ out) {
  __shared__ float xin[3][33][133];   // l: input row (2R0-1+l), c: col j+1 (j in -1..128)
  __shared__ float ws[3][16][12];
  __shared__ float bs[16];
  const int tid = threadIdx.x;
  const int blk = blockIdx.x;
  const int n = blk >> 2, R0 = (blk & 3) << 4;
  const int y = (int)iseq[n * 2 + 0];
  const int x = (int)iseq[n * 2 + 1];
  const int b = n >> 6;

  for (int s = tid; s < 3 * 16 * 12; s += TPB) {
    int t = s % 12; int oc = (s / 12) & 15; int ic = s / 192;
    ws[ic][oc][t] = (t < 9) ? w[(oc * 3 + ic) * 9 + t] : 0.f;
  }
  if (tid < 16) bs[tid] = bias[tid];
  for (int s = tid; s < 3 * 33 * 130; s += TPB) {
    int c = s % 130; int l = (s / 130) % 33; int ic = s / 4290;
    int i = 2 * R0 - 1 + l;
    int j = c - 1;
    float v = 0.f;
    if ((unsigned)i < 128u && (unsigned)j < 128u) {
      int r = y + i - 64, cc = x + j - 64;
      if ((unsigned)r < 1024u && (unsigned)cc < 1024u)
        v = fmap[(((size_t)b * 3 + ic) << 20) + ((size_t)r << 10) + cc];
    }
    xin[ic][l][c] = v;
  }
  __syncthreads();

  const int ocg = (tid >> 4) & 3;                      // in-wave
  const int spg = (tid & 15) | ((tid >> 6) << 4);
  const int cg = spg & 7, rg = spg >> 3;
  float acc[4][16];
#pragma unroll
  for (int a = 0; a < 4; ++a)
#pragma unroll
    for (int s2 = 0; s2 < 16; ++s2) acc[a][s2] = 0.f;

  for (int ic = 0; ic < 3; ++ic) {
    float wv[4][9];
#pragma unroll
    for (int oi = 0; oi < 4; ++oi) {
      int oc = oi * 4 + ocg;
      float4 w0 = *(const float4*)&ws[ic][oc][0];
      float4 w1 = *(const float4*)&ws[ic][oc][4];
      float4 w2 = *(const float4*)&ws[ic][oc][8];
      wv[oi][0] = w0.x; wv[oi][1] = w0.y; wv[oi][2] = w0.z; wv[oi][3] = w0.w;
      wv[oi][4] = w1.x; wv[oi][5] = w1.y; wv[oi][6] = w1.z; wv[oi][7] = w1.w;
      wv[oi][8] = w2.x;
    }
#pragma unroll
    for (int r = 0; r < 2; ++r) {
#pragma unroll
      for (int ki = 0; ki < 3; ++ki) {
        int l = 4 * rg + 2 * r + ki;
        float xr[17];
#pragma unroll
        for (int t = 0; t < 17; ++t) xr[t] = xin[ic][l][16 * cg + t];
#pragma unroll
        for (int oi = 0; oi < 4; ++oi)
#pragma unroll
          for (int kj = 0; kj < 3; ++kj) {
            float wc = wv[oi][ki * 3 + kj];
#pragma unroll
            for (int q = 0; q < 8; ++q)
              acc[oi][r * 8 + q] = fmaf(wc, xr[2 * q + kj], acc[oi][r * 8 + q]);
          }
      }
    }
  }
#pragma unroll
  for (int oi = 0; oi < 4; ++oi) {
    int oc = oi * 4 + ocg;
    float bb = bs[oc];
#pragma unroll
    for (int r = 0; r < 2; ++r) {
      int orow = R0 + 2 * rg + r;
#pragma unroll
      for (int q = 0; q < 8; ++q)
        out[((n * 16 + oc) * 64 + orow) * 64 + 8 * cg + q] = acc[oi][r * 8 + q] + bb;
    }
  }
}

// ================= conv2: 16->32, 64->32, BN+ReLU on staging =================
// grid 2048 = 512 x 4 row-blocks (8 out rows). in y1 [512][16][64][64] pre-BN.
__global__ __launch_bounds__(TPB, 2) void conv2_tiled(
    const float* __restrict__ in, const float* __restrict__ ss,
    const float* __restrict__ w, const float* __restrict__ bias,
    float* __restrict__ out) {
  __shared__ float xin[8][17][67];
  __shared__ float ws[16][32][12];
  __shared__ float bs[32];
  const int tid = threadIdx.x;
  const int blk = blockIdx.x;
  const int n = blk >> 2, R0 = (blk & 3) << 3;
  for (int s = tid; s < 16 * 32 * 12; s += TPB) {
    int t = s % 12; int oc = (s / 12) & 31; int ic = s / 384;
    ws[ic][oc][t] = (t < 9) ? w[(oc * 16 + ic) * 9 + t] : 0.f;
  }
  if (tid < 32) bs[tid] = bias[tid];

  const int ocg = (tid >> 3) & 7;
  const int cg = tid & 7;
  const int rg = tid >> 6;
  float acc[4][2][4];
#pragma unroll
  for (int a = 0; a < 4; ++a)
#pragma unroll
    for (int r = 0; r < 2; ++r)
#pragma unroll
      for (int q = 0; q < 4; ++q) acc[a][r][q] = 0.f;

  for (int ch = 0; ch < 2; ++ch) {
    __syncthreads();
    for (int s = tid; s < 8 * 17 * 16; s += TPB) {
      int g = s & 15; int l = (s >> 4) % 17; int ic = s / 272;
      int icg = ch * 8 + ic;
      int i = 2 * R0 - 1 + l;
      int j0 = g * 4;
      float4 v = make_float4(0.f, 0.f, 0.f, 0.f);
      if (i >= 0) v = *(const float4*)&in[((n * 16 + icg) << 12) + (i << 6) + j0];
      float sc = ss[2 * icg], sh = ss[2 * icg + 1];
      xin[ic][l][1 + j0]     = fmaxf(fmaf(v.x, sc, sh), 0.f);
      xin[ic][l][1 + j0 + 1] = fmaxf(fmaf(v.y, sc, sh), 0.f);
      xin[ic][l][1 + j0 + 2] = fmaxf(fmaf(v.z, sc, sh), 0.f);
      xin[ic][l][1 + j0 + 3] = fmaxf(fmaf(v.w, sc, sh), 0.f);
      if (g == 0) xin[ic][l][0] = 0.f;
      if (i < 0) {
        xin[ic][l][1+j0] = 0.f; xin[ic][l][2+j0] = 0.f; xin[ic][l][3+j0] = 0.f; xin[ic][l][4+j0] = 0.f;
      }
    }
    __syncthreads();
    for (int ic = 0; ic < 8; ++ic) {
      float wv[4][9];
#pragma unroll
      for (int oi = 0; oi < 4; ++oi) {
        int oc = oi * 8 + ocg;
        float4 w0 = *(const float4*)&ws[ch * 8 + ic][oc][0];
        float4 w1 = *(const float4*)&ws[ch * 8 + ic][oc][4];
        float4 w2 = *(const float4*)&ws[ch * 8 + ic][oc][8];
        wv[oi][0] = w0.x; wv[oi][1] = w0.y; wv[oi][2] = w0.z; wv[oi][3] = w0.w;
        wv[oi][4] = w1.x; wv[oi][5] = w1.y; wv[oi][6] = w1.z; wv[oi][7] = w1.w;
        wv[oi][8] = w2.x;
      }
#pragma unroll
      for (int r = 0; r < 2; ++r) {
#pragma unroll
        for (int ki = 0; ki < 3; ++ki) {
          int l = 4 * rg + 2 * r + ki;
          float xr[9];
#pragma unroll
          for (int t = 0; t < 9; ++t) xr[t] = xin[ic][l][8 * cg + t];
#pragma unroll
          for (int oi = 0; oi < 4; ++oi)
#pragma unroll
            for (int kj = 0; kj < 3; ++kj) {
              float wc = wv[oi][ki * 3 + kj];
#pragma unroll
              for (int q = 0; q < 4; ++q)
                acc[oi][r][q] = fmaf(wc, xr[2 * q + kj], acc[oi][r][q]);
            }
        }
      }
    }
  }
#pragma unroll
  for (int oi = 0; oi < 4; ++oi) {
    int oc = oi * 8 + ocg;
    float bb = bs[oc];
#pragma unroll
    for (int r = 0; r < 2; ++r) {
      int orow = R0 + 2 * rg + r;
#pragma unroll
      for (int q = 0; q < 4; ++q)
        out[((n * 32 + oc) * 32 + orow) * 32 + 4 * cg + q] = acc[oi][r][q] + bb;
    }
  }
}

// ================= conv3: 32->64, 32->16 =================
// grid 512 (one image per block). in y2 pre-BN.
__global__ __launch_bounds__(TPB, 2) void conv3_tiled(
    const float* __restrict__ in, const float* __restrict__ ss,
    const float* __restrict__ w, const float* __restrict__ bias,
    float* __restrict__ out) {
  __shared__ float xin[8][33][35];
  __shared__ float ws[8][64][12];
  __shared__ float bs[64];
  const int tid = threadIdx.x;
  const int n = blockIdx.x;
  if (tid < 64) bs[tid] = bias[tid];

  const int ocg = (tid >> 3) & 7;
  const int cg = tid & 3;
  const int rg = ((tid >> 2) & 1) | ((tid >> 6) << 1);
  float acc[8][2][4];
#pragma unroll
  for (int a = 0; a < 8; ++a)
#pragma unroll
    for (int r = 0; r < 2; ++r)
#pragma unroll
      for (int q = 0; q < 4; ++q) acc[a][r][q] = 0.f;

  for (int ch = 0; ch < 4; ++ch) {
    __syncthreads();
    for (int s = tid; s < 8 * 64 * 12; s += TPB) {
      int t = s % 12; int oc = (s / 12) & 63; int ic = s / 768;
      ws[ic][oc][t] = (t < 9) ? w[(oc * 32 + ch * 8 + ic) * 9 + t] : 0.f;
    }
    for (int s = tid; s < 8 * 33 * 8; s += TPB) {
      int g = s & 7; int l = (s >> 3) % 33; int ic = s / 264;
      int icg = ch * 8 + ic;
      int i = l - 1;
      int j0 = g * 4;
      float4 v = make_float4(0.f, 0.f, 0.f, 0.f);
      if (i >= 0) v = *(const float4*)&in[((n * 32 + icg) << 10) + (i << 5) + j0];
      float sc = ss[2 * icg], sh = ss[2 * icg + 1];
      float o0 = fmaxf(fmaf(v.x, sc, sh), 0.f), o1 = fmaxf(fmaf(v.y, sc, sh), 0.f);
      float o2 = fmaxf(fmaf(v.z, sc, sh), 0.f), o3 = fmaxf(fmaf(v.w, sc, sh), 0.f);
      if (i < 0) { o0 = 0.f; o1 = 0.f; o2 = 0.f; o3 = 0.f; }
      xin[ic][l][1 + j0] = o0; xin[ic][l][2 + j0] = o1;
      xin[ic][l][3 + j0] = o2; xin[ic][l][4 + j0] = o3;
      if (g == 0) xin[ic][l][0] = 0.f;
    }
    __syncthreads();
    for (int ic = 0; ic < 8; ++ic) {
      float wv[8][9];
#pragma unroll
      for (int oi = 0; oi < 8; ++oi) {
        int oc = oi * 8 + ocg;
        float4 w0 = *(const float4*)&ws[ic][oc][0];
        float4 w1 = *(const float4*)&ws[ic][oc][4];
        float4 w2 = *(const float4*)&ws[ic][oc][8];
        wv[oi][0] = w0.x; wv[oi][1] = w0.y; wv[oi][2] = w0.z; wv[oi][3] = w0.w;
        wv[oi][4] = w1.x; wv[oi][5] = w1.y; wv[oi][6] = w1.z; wv[oi][7] = w1.w;
        wv[oi][8] = w2.x;
      }
#pragma unroll
      for (int r = 0; r < 2; ++r) {
#pragma unroll
        for (int ki = 0; ki < 3; ++ki) {
          int l = 4 * rg + 2 * r + ki;
          float xr[9];
#pragma unroll
          for (int t = 0; t < 9; ++t) xr[t] = xin[ic][l][8 * cg + t];
#pragma unroll
          for (int oi = 0; oi < 8; ++oi)
#pragma unroll
            for (int kj = 0; kj < 3; ++kj) {
              float wc = wv[oi][ki * 3 + kj];
#pragma unroll
              for (int q = 0; q < 4; ++q)
                acc[oi][r][q] = fmaf(wc, xr[2 * q + kj], acc[oi][r][q]);
            }
        }
      }
    }
  }
#pragma unroll
  for (int oi = 0; oi < 8; ++oi) {
    int oc = oi * 8 + ocg;
    float bb = bs[oc];
#pragma unroll
    for (int r = 0; r < 2; ++r) {
      int orow = 2 * rg + r;
#pragma unroll
      for (int q = 0; q < 4; ++q)
        out[((n * 64 + oc) << 8) + (orow << 4) + 4 * cg + q] = acc[oi][r][q] + bb;
    }
  }
}

// ================= conv4: 64->128, 16->8 =================
// grid 512. in y3 pre-BN.
__global__ __launch_bounds__(TPB, 2) void conv4_tiled(
    const float* __restrict__ in, const float* __restrict__ ss,
    const float* __restrict__ w, const float* __restrict__ bias,
    float* __restrict__ out) {
  __shared__ float xin[8][17][19];
  __shared__ float ws[8][128][12];
  __shared__ float bs[128];
  const int tid = threadIdx.x;
  const int n = blockIdx.x;
  if (tid < 128) bs[tid] = bias[tid];

  const int ocg = (tid >> 2) & 15;
  const int cg = tid & 3;
  const int rg = tid >> 6;
  float acc[8][2][2];
#pragma unroll
  for (int a = 0; a < 8; ++a)
#pragma unroll
    for (int r = 0; r < 2; ++r)
#pragma unroll
      for (int q = 0; q < 2; ++q) acc[a][r][q] = 0.f;

  for (int ch = 0; ch < 8; ++ch) {
    __syncthreads();
    for (int s = tid; s < 8 * 128 * 12; s += TPB) {
      int t = s % 12; int oc = (s / 12) & 127; int ic = s / 1536;
      ws[ic][oc][t] = (t < 9) ? w[(oc * 64 + ch * 8 + ic) * 9 + t] : 0.f;
    }
    for (int s = tid; s < 8 * 17 * 4; s += TPB) {
      int g = s & 3; int l = (s >> 2) % 17; int ic = s / 68;
      int icg = ch * 8 + ic;
      int i = l - 1;
      int j0 = g * 4;
      float4 v = make_float4(0.f, 0.f, 0.f, 0.f);
      if (i >= 0) v = *(const float4*)&in[((n * 64 + icg) << 8) + (i << 4) + j0];
      float sc = ss[2 * icg], sh = ss[2 * icg + 1];
      float o0 = fmaxf(fmaf(v.x, sc, sh), 0.f), o1 = fmaxf(fmaf(v.y, sc, sh), 0.f);
      float o2 = fmaxf(fmaf(v.z, sc, sh), 0.f), o3 = fmaxf(fmaf(v.w, sc, sh), 0.f);
      if (i < 0) { o0 = 0.f; o1 = 0.f; o2 = 0.f; o3 = 0.f; }
      xin[ic][l][1 + j0] = o0; xin[ic][l][2 + j0] = o1;
      xin[ic][l][3 + j0] = o2; xin[ic][l][4 + j0] = o3;
      if (g == 0) xin[ic][l][0] = 0.f;
    }
    __syncthreads();
    for (int ic = 0; ic < 8; ++ic) {
      float wv[8][9];
#pragma unroll
      for (int oi = 0; oi < 8; ++oi) {
        int oc = oi * 16 + ocg;
        float4 w0 = *(const float4*)&ws[ic][oc][0];
        float4 w1 = *(const float4*)&ws[ic][oc][4];
        float4 w2 = *(const float4*)&ws[ic][oc][8];
        wv[oi][0] = w0.x; wv[oi][1] = w0.y; wv[oi][2] = w0.z; wv[oi][3] = w0.w;
        wv[oi][4] = w1.x; wv[oi][5] = w1.y; wv[oi][6] = w1.z; wv[oi][7] = w1.w;
        wv[oi][8] = w2.x;
      }
#pragma unroll
      for (int r = 0; r < 2; ++r) {
#pragma unroll
        for (int ki = 0; ki < 3; ++ki) {
          int l = 4 * rg + 2 * r + ki;
          float xr[5];
#pragma unroll
          for (int t = 0; t < 5; ++t) xr[t] = xin[ic][l][4 * cg + t];
#pragma unroll
          for (int oi = 0; oi < 8; ++oi)
#pragma unroll
            for (int kj = 0; kj < 3; ++kj) {
              float wc = wv[oi][ki * 3 + kj];
#pragma unroll
              for (int q = 0; q < 2; ++q)
                acc[oi][r][q] = fmaf(wc, xr[2 * q + kj], acc[oi][r][q]);
            }
        }
      }
    }
  }
#pragma unroll
  for (int oi = 0; oi < 8; ++oi) {
    int oc = oi * 16 + ocg;
    float bb = bs[oc];
#pragma unroll
    for (int r = 0; r < 2; ++r) {
      int orow = 2 * rg + r;
#pragma unroll
      for (int q = 0; q < 2; ++q)
        out[((n * 128 + oc) << 6) + (orow << 3) + 2 * cg + q] = acc[oi][r][q] + bb;
    }
  }
}

// ---------- BN statistics (deterministic two-stage) ----------
__global__ __launch_bounds__(TPB) void stats_partial_kernel(
    const float* __restrict__ y, float* __restrict__ part, int C, int HW) {
  int bid = blockIdx.x;
  int c = bid >> 6;
  int s = bid & 63;
  float sum = 0.f, sq = 0.f;
  for (int nn = 0; nn < 8; ++nn) {
    int n = s * 8 + nn;
    const float* p = y + (n * C + c) * HW;
    for (int i = threadIdx.x; i < HW; i += TPB) {
      float v = p[i];
      sum += v; sq = fmaf(v, v, sq);
    }
  }
  __shared__ float rs[TPB], rq[TPB];
  rs[threadIdx.x] = sum; rq[threadIdx.x] = sq;
  __syncthreads();
  for (int off = TPB / 2; off > 0; off >>= 1) {
    if (threadIdx.x < off) { rs[threadIdx.x] += rs[threadIdx.x + off]; rq[threadIdx.x] += rq[threadIdx.x + off]; }
    __syncthreads();
  }
  if (threadIdx.x == 0) { part[bid * 2] = rs[0]; part[bid * 2 + 1] = rq[0]; }
}

__global__ void stats_final_kernel(const float* __restrict__ part,
    const float* __restrict__ gamma, const float* __restrict__ beta,
    float* __restrict__ ss, float inv_count) {
  int c = blockIdx.x;
  int t = threadIdx.x;  // 64
  float sum = part[(c * 64 + t) * 2];
  float sq  = part[(c * 64 + t) * 2 + 1];
  for (int off = 32; off > 0; off >>= 1) {
    sum += __shfl_down(sum, off);
    sq  += __shfl_down(sq, off);
  }
  if (t == 0) {
    float mean = sum * inv_count;
    float var  = sq * inv_count - mean * mean;
    float rstd = rsqrtf(var + 1e-5f);
    float scl  = gamma[c] * rstd;
    ss[2 * c] = scl;
    ss[2 * c + 1] = beta[c] - mean * scl;
  }
}

__global__ __launch_bounds__(TPB) void bnrelu_kernel(float* __restrict__ y,
    const float* __restrict__ ss, int C, int HW, int total) {
  int i = blockIdx.x * TPB + threadIdx.x;
  if (i >= total) return;
  int c = (i / HW) % C;
  y[i] = fmaxf(fmaf(y[i], ss[2 * c], ss[2 * c + 1]), 0.f);
}

// ---------- generic tiled GEMM: out[m,n] = act(sum_k A[m,k]*W[n,k] + b[n]) ----------
__global__ __launch_bounds__(TPB) void gemm_rt(const float* __restrict__ A,
    const float* __restrict__ W, const float* __restrict__ bias,
    float* __restrict__ out, int M, int N, int K, int dorelu) {
  __shared__ float As[32][33];
  __shared__ float Ws[32][33];
  int tid = threadIdx.x;
  int tx = tid & 15, ty = tid >> 4;
  int bm = blockIdx.y << 5, bn = blockIdx.x << 5;
  float a00 = 0.f, a01 = 0.f, a10 = 0.f, a11 = 0.f;
  int nk = (K + 31) >> 5;
  for (int kt = 0; kt < nk; ++kt) {
    int k0 = kt << 5;
#pragma unroll
    for (int l = 0; l < 4; ++l) {
      int idx = tid + (l << 8);
      int r = idx >> 5, c = idx & 31;
      int gc = k0 + c;
      int ga = bm + r;
      As[c][r] = (ga < M && gc < K) ? A[ga * K + gc] : 0.f;
      int gw = bn + r;
      Ws[c][r] = (gw < N && gc < K) ? W[gw * K + gc] : 0.f;
    }
    __syncthreads();
#pragma unroll
    for (int k = 0; k < 32; ++k) {
      float x0 = As[k][ty], x1 = As[k][ty + 16];
      float y0 = Ws[k][tx], y1 = Ws[k][tx + 16];
      a00 = fmaf(x0, y0, a00); a01 = fmaf(x0, y1, a01);
      a10 = fmaf(x1, y0, a10); a11 = fmaf(x1, y1, a11);
    }
    __syncthreads();
  }
  int m0 = bm + ty, m1 = m0 + 16, n0 = bn + tx, n1 = n0 + 16;
  if (m0 < M && n0 < N) { float v = a00 + bias[n0]; out[m0 * N + n0] = dorelu ? fmaxf(v, 0.f) : v; }
  if (m0 < M && n1 < N) { float v = a01 + bias[n1]; out[m0 * N + n1] = dorelu ? fmaxf(v, 0.f) : v; }
  if (m1 < M && n0 < N) { float v = a10 + bias[n0]; out[m1 * N + n0] = dorelu ? fmaxf(v, 0.f) : v; }
  if (m1 < M && n1 < N) { float v = a11 + bias[n1]; out[m1 * N + n1] = dorelu ? fmaxf(v, 0.f) : v; }
}

// ---------- small builders ----------
__global__ __launch_bounds__(TPB) void build_enh_kernel(const float* __restrict__ cond,
    const float* __restrict__ steps, float* __restrict__ enh) {
  int i = blockIdx.x * TPB + threadIdx.x;
  if (i >= 512 * 6) return;
  int n = i / 6, k = i % 6;
  int b = n >> 6, s = n & 63;
  enh[i] = (k < 5) ? cond[b * 5 + k] : steps[b * 64 + s];
}

__global__ __launch_bounds__(TPB) void build_comb_kernel(const float* __restrict__ lo,
    const float* __restrict__ mapf, const float* __restrict__ condf, float* __restrict__ comb) {
  int i = blockIdx.x * TPB + threadIdx.x;
  if (i >= 512 * 576) return;
  int n = i / 576, k = i % 576;
  float v;
  if (k < 256)      v = lo[n * 256 + k];
  else if (k < 512) v = mapf[n * 256 + (k - 256)];
  else              v = condf[n * 64 + (k - 512)];
  comb[i] = v;
}

// ---------- LSTM: 64 blocks, weight-partitioned, pipelined ----------
__global__ __launch_bounds__(TPB) void lstm_kernel(
    const float* __restrict__ embv,
    const float* __restrict__ w_ih0, const float* __restrict__ w_hh0,
    const float* __restrict__ b_ih0, const float* __restrict__ b_hh0,
    const float* __restrict__ w_ih1, const float* __restrict__ w_hh1,
    const float* __restrict__ b_ih1, const float* __restrict__ b_hh1,
    float* __restrict__ h0_steps,   // [64][8][256]
    float* __restrict__ lstm_out,   // [8][64][256]
    int* __restrict__ bar) {
  const int tid = threadIdx.x;
  const int u0 = blockIdx.x * 4;

  __shared__ float whh0s[16][260];
  __shared__ float wih1s[16][260];
  __shared__ float whh1s[16][260];
  __shared__ float wih0s[16][32];
  __shared__ unsigned short hps[8][260];
  __shared__ unsigned short h1ps[8][260];
  __shared__ float x0s[8][32];
  __shared__ float zg0s[8][16];
  __shared__ float zg1s[8][16];
  __shared__ float bias0s[16], bias1s[16];
  __shared__ float c0s[8][4], c1s[8][4];

  for (int idx = tid; idx < 16 * 256; idx += TPB) {
    int r = idx >> 8, k = idx & 255;
    int gate = r >> 2, uu = r & 3;
    int R = gate * 256 + u0 + uu;
    whh0s[r][k] = w_hh0[R * 256 + k];
    wih1s[r][k] = w_ih1[R * 256 + k];
    whh1s[r][k] = w_hh1[R * 256 + k];
  }
  for (int idx = tid; idx < 16 * 32; idx += TPB) {
    int r = idx >> 5, k = idx & 31;
    int gate = r >> 2, uu = r & 3;
    int R = gate * 256 + u0 + uu;
    wih0s[r][k] = w_ih0[R * 32 + k];
  }
  if (tid < 16) {
    int gate = tid >> 2, uu = tid & 3;
    int R = gate * 256 + u0 + uu;
    bias0s[tid] = b_ih0[R] + b_hh0[R];
    bias1s[tid] = b_ih1[R] + b_hh1[R];
  }
  if (tid < 32) c0s[tid >> 2][tid & 3] = 0.f;
  else if (tid < 64) { int t = tid - 32; c1s[t >> 2][t & 3] = 0.f; }
  __syncthreads();

  for (int p = 0; p <= 64; ++p) {
    for (int idx = tid; idx < 2048; idx += TPB) {
      int b = idx >> 8, k = idx & 255;
      float h0v = (p == 0) ? 0.f : h0_steps[(p - 1) * 2048 + idx];
      hps[b][k] = f2bf(h0v);
      float h1v = (p < 2) ? 0.f : lstm_out[(b * 64 + (p - 2)) * 256 + k];
      h1ps[b][k] = f2bf(h1v);
    }
    {
      int b = tid >> 5, k = tid & 31;
      x0s[b][k] = (p < 64) ? embv[(b * 64 + p) * 32 + k] : 0.f;
    }
    __syncthreads();

    if (tid < 128) {
      if (p < 64) {
        int b = tid >> 4, r = tid & 15;
        float acc = bias0s[r];
#pragma unroll
        for (int k = 0; k < 32; k += 4) {
          float4 w4 = *(const float4*)&wih0s[r][k];
          acc = fmaf(w4.x, x0s[b][k],     acc);
          acc = fmaf(w4.y, x0s[b][k + 1], acc);
          acc = fmaf(w4.z, x0s[b][k + 2], acc);
          acc = fmaf(w4.w, x0s[b][k + 3], acc);
        }
        for (int k = 0; k < 256; k += 4) {
          float4 w4 = *(const float4*)&whh0s[r][k];
          ushort4 u = *(const ushort4*)&hps[b][k];
          acc = fmaf(w4.x, bf2f(u.x), acc);
          acc = fmaf(w4.y, bf2f(u.y), acc);
          acc = fmaf(w4.z, bf2f(u.z), acc);
          acc = fmaf(w4.w, bf2f(u.w), acc);
        }
        zg0s[b][r] = acc;
      }
    } else {
      if (p >= 1) {
        int t = tid - 128;
        int b = t >> 4, r = t & 15;
        float acc = bias1s[r];
        for (int k = 0; k < 256; k += 4) {
          float4 wa = *(const float4*)&wih1s[r][k];
          ushort4 ux = *(const ushort4*)&hps[b][k];
          float4 wb = *(const float4*)&whh1s[r][k];
          ushort4 uh = *(const ushort4*)&h1ps[b][k];
          acc = fmaf(wa.x, bf2f(ux.x), acc);
          acc = fmaf(wa.y, bf2f(ux.y), acc);
          acc = fmaf(wa.z, bf2f(ux.z), acc);
          acc = fmaf(wa.w, bf2f(ux.w), acc);
          acc = fmaf(wb.x, bf2f(uh.x), acc);
          acc = fmaf(wb.y, bf2f(uh.y), acc);
          acc = fmaf(wb.z, bf2f(uh.z), acc);
          acc = fmaf(wb.w, bf2f(uh.w), acc);
        }
        zg1s[b][r] = acc;
      }
    }
    __syncthreads();

    if (tid < 32 && p < 64) {
      int b = tid >> 2, uu = tid & 3;
      float zi = zg0s[b][uu], zf = zg0s[b][4 + uu], zg = zg0s[b][8 + uu], zo = zg0s[b][12 + uu];
      float c = sigf(zf) * c0s[b][uu] + sigf(zi) * tanhf(zg);
      c0s[b][uu] = c;
      h0_steps[p * 2048 + b * 256 + u0 + uu] = sigf(zo) * tanhf(c);
    }
    if (tid >= 32 && tid < 64 && p >= 1) {
      int t = tid - 32;
      int b = t >> 2, uu = t & 3;
      float zi = zg1s[b][uu], zf = zg1s[b][4 + uu], zg = zg1s[b][8 + uu], zo = zg1s[b][12 + uu];
      float c = sigf(zf) * c1s[b][uu] + sigf(zi) * tanhf(zg);
      c1s[b][uu] = c;
      lstm_out[(b * 64 + (p - 1)) * 256 + u0 + uu] = sigf(zo) * tanhf(c);
    }

    __syncthreads();
    if (tid == 0) {
      __threadfence();
      atomicAdd(&bar[p], 1);
      while (__hip_atomic_load(&bar[p], __ATOMIC_ACQUIRE, __HIP_MEMORY_SCOPE_AGENT) < NLB) {
        __builtin_amdgcn_s_sleep(2);
      }
      __threadfence();
    }
    __syncthreads();
  }
}

// ---------- launcher ----------
extern "C" void kernel_launch(void* const* d_in, const int* in_sizes, int n_in,
                              void* d_out, int out_size, void* d_ws, size_t ws_size,
                              hipStream_t stream) {
  const float* fmap  = (const float*)d_in[0];
  const float* cond  = (const float*)d_in[1];
  const float* iseq  = (const float*)d_in[2];
  const float* steps = (const float*)d_in[3];
  const float* cw1 = (const float*)d_in[4];  const float* cb1 = (const float*)d_in[5];
  const float* g1  = (const float*)d_in[6];  const float* be1 = (const float*)d_in[7];
  const float* cw2 = (const float*)d_in[8];  const float* cb2 = (const float*)d_in[9];
  const float* g2  = (const float*)d_in[10]; const float* be2 = (const float*)d_in[11];
  const float* cw3 = (const float*)d_in[12]; const float* cb3 = (const float*)d_in[13];
  const float* g3  = (const float*)d_in[14]; const float* be3 = (const float*)d_in[15];
  const float* cw4 = (const float*)d_in[16]; const float* cb4 = (const float*)d_in[17];
  const float* g4  = (const float*)d_in[18]; const float* be4 = (const float*)d_in[19];
  const float* fw1 = (const float*)d_in[20]; const float* fb1 = (const float*)d_in[21];
  const float* fw2 = (const float*)d_in[22]; const float* fb2 = (const float*)d_in[23];
  const float* ew1 = (const float*)d_in[24]; const float* eb1 = (const float*)d_in[25];
  const float* ew2 = (const float*)d_in[26]; const float* eb2 = (const float*)d_in[27];
  const float* mw  = (const float*)d_in[28]; const float* mb  = (const float*)d_in[29];
  const float* w_ih0 = (const float*)d_in[30]; const float* w_hh0 = (const float*)d_in[31];
  const float* b_ih0 = (const float*)d_in[32]; const float* b_hh0 = (const float*)d_in[33];
  const float* w_ih1 = (const float*)d_in[34]; const float* w_hh1 = (const float*)d_in[35];
  const float* b_ih1 = (const float*)d_in[36]; const float* b_hh1 = (const float*)d_in[37];
  const float* xw1 = (const float*)d_in[38]; const float* xb1 = (const float*)d_in[39];
  const float* xw2 = (const float*)d_in[40]; const float* xb2 = (const float*)d_in[41];
  const float* ow  = (const float*)d_in[42]; const float* ob  = (const float*)d_in[43];

  float* ws = (float*)d_ws;
  float* y1 = ws;                    // 33,554,432 f
  float* y2 = ws + 33554432;         // 16,777,216 f
  float* y3 = ws;                    // y1 dead
  float* y4 = ws + 33554432;         // y2 dead
  size_t base = 50331648;
  float* part  = ws + base; base += 16384;
  float* ss1   = ws + base; base += 32;
  float* ss2   = ws + base; base += 64;
  float* ss3   = ws + base; base += 128;
  float* ss4   = ws + base; base += 256;
  float* f1    = ws + base; base += 262144;
  float* mapf  = ws + base; base += 131072;
  float* enh   = ws + base; base += 3072;
  float* ceh   = ws + base; base += 65536;
  float* condf = ws + base; base += 32768;
  float* embb  = ws + base; base += 16384;
  float* h0st  = ws + base; base += 131072;
  float* lout  = ws + base; base += 131072;
  float* comb  = ws + base; base += 294912;
  float* cx1   = ws + base; base += 65536;
  float* cx2   = ws + base; base += 32768;
  int*   bar   = (int*)(ws + base); base += 128;

  // --- encoder convs (LDS-tiled) with batch-stat BN folded to scale/shift ---
  conv1_tiled<<<2048, TPB, 0, stream>>>(fmap, iseq, cw1, cb1, y1);
  stats_partial_kernel<<<16 * 64, TPB, 0, stream>>>(y1, part, 16, 4096);
  stats_final_kernel<<<16, 64, 0, stream>>>(part, g1, be1, ss1, 1.f / 2097152.f);
  conv2_tiled<<<2048, TPB, 0, stream>>>(y1, ss1, cw2, cb2, y2);
  stats_partial_kernel<<<32 * 64, TPB, 0, stream>>>(y2, part, 32, 1024);
  stats_final_kernel<<<32, 64, 0, stream>>>(part, g2, be2, ss2, 1.f / 524288.f);
  conv3_tiled<<<512, TPB, 0, stream>>>(y2, ss2, cw3, cb3, y3);
  stats_partial_kernel<<<64 * 64, TPB, 0, stream>>>(y3, part, 64, 256);
  stats_final_kernel<<<64, 64, 0, stream>>>(part, g3, be3, ss3, 1.f / 131072.f);
  conv4_tiled<<<512, TPB, 0, stream>>>(y3, ss3, cw4, cb4, y4);
  stats_partial_kernel<<<128 * 64, TPB, 0, stream>>>(y4, part, 128, 64);
  stats_final_kernel<<<128, 64, 0, stream>>>(part, g4, be4, ss4, 1.f / 32768.f);
  bnrelu_kernel<<<16384, TPB, 0, stream>>>(y4, ss4, 128, 64, 4194304);

  // --- map-feature MLP ---
  gemm_rt<<<dim3(16, 16), TPB, 0, stream>>>(y4, fw1, fb1, f1, 512, 512, 8192, 1);
  gemm_rt<<<dim3(8, 16),  TPB, 0, stream>>>(f1, fw2, fb2, mapf, 512, 256, 512, 0);

  // --- condition encoder ---
  build_enh_kernel<<<12, TPB, 0, stream>>>(cond, steps, enh);
  gemm_rt<<<dim3(4, 16), TPB, 0, stream>>>(enh, ew1, eb1, ceh, 512, 128, 6, 1);
  gemm_rt<<<dim3(2, 16), TPB, 0, stream>>>(ceh, ew2, eb2, condf, 512, 64, 128, 0);

  // --- coord embed + LSTM ---
  gemm_rt<<<dim3(1, 16), TPB, 0, stream>>>(iseq, mw, mb, embb, 512, 32, 2, 1);
  hipMemsetAsync(bar, 0, 65 * sizeof(int), stream);
  lstm_kernel<<<NLB, TPB, 0, stream>>>(embb, w_ih0, w_hh0, b_ih0, b_hh0,
                                       w_ih1, w_hh1, b_ih1, b_hh1, h0st, lout, bar);

  // --- head ---
  build_comb_kernel<<<1152, TPB, 0, stream>>>(lout, mapf, condf, comb);
  gemm_rt<<<dim3(4, 16), TPB, 0, stream>>>(comb, xw1, xb1, cx1, 512, 128, 576, 1);
  gemm_rt<<<dim3(2, 16), TPB, 0, stream>>>(cx1, xw2, xb2, cx2, 512, 64, 128, 1);
  gemm_rt<<<dim3(1, 16), TPB, 0, stream>>>(cx2, ow, ob, (float*)d_out, 512, 2, 64, 0);
}

// Round 3
// 1472.809 us; speedup vs baseline: 4.9967x; 1.6945x over previous
//
#include <hip/hip_runtime.h>

#define TPB 256
#define NLB 64   // LSTM blocks

typedef float f32x4 __attribute__((ext_vector_type(4)));
typedef short bf16x8 __attribute__((ext_vector_type(8)));

// ---------- helpers ----------
__device__ __forceinline__ float bf2f(unsigned short u) {
  union { unsigned int i; float f; } x; x.i = ((unsigned int)u) << 16; return x.f;
}
__device__ __forceinline__ unsigned short f2bf(float v) {
  union { float f; unsigned int i; } x; x.f = v;
  unsigned int r = (x.i + 0x7fffu + ((x.i >> 16) & 1u)) >> 16;
  return (unsigned short)r;
}
__device__ __forceinline__ float sigf(float x) { return 1.f / (1.f + __expf(-x)); }
__device__ __forceinline__ bf16x8 lda_bf8(const unsigned short* p) {
  union { uint4 u; bf16x8 v; } t; t.u = *(const uint4*)p; return t.v;
}

// ================= conv1: fused crop-gather + 3x3 s2 conv (tiled) =================
__global__ __launch_bounds__(TPB, 2) void conv1_tiled(
    const float* __restrict__ fmap, const float* __restrict__ iseq,
    const float* __restrict__ w, const float* __restrict__ bias,
    float* __restrict__ out) {
  __shared__ float xin[3][33][133];
  __shared__ float ws[3][16][12];
  __shared__ float bs[16];
  const int tid = threadIdx.x;
  const int blk = blockIdx.x;
  const int n = blk >> 2, R0 = (blk & 3) << 4;
  const int y = (int)iseq[n * 2 + 0];
  const int x = (int)iseq[n * 2 + 1];
  const int b = n >> 6;

  for (int s = tid; s < 3 * 16 * 12; s += TPB) {
    int t = s % 12; int oc = (s / 12) & 15; int ic = s / 192;
    ws[ic][oc][t] = (t < 9) ? w[(oc * 3 + ic) * 9 + t] : 0.f;
  }
  if (tid < 16) bs[tid] = bias[tid];
  for (int s = tid; s < 3 * 33 * 130; s += TPB) {
    int c = s % 130; int l = (s / 130) % 33; int ic = s / 4290;
    int i = 2 * R0 - 1 + l;
    int j = c - 1;
    float v = 0.f;
    if ((unsigned)i < 128u && (unsigned)j < 128u) {
      int r = y + i - 64, cc = x + j - 64;
      if ((unsigned)r < 1024u && (unsigned)cc < 1024u)
        v = fmap[(((size_t)b * 3 + ic) << 20) + ((size_t)r << 10) + cc];
    }
    xin[ic][l][c] = v;
  }
  __syncthreads();

  const int ocg = (tid >> 4) & 3;
  const int spg = (tid & 15) | ((tid >> 6) << 4);
  const int cg = spg & 7, rg = spg >> 3;
  float acc[4][16];
#pragma unroll
  for (int a = 0; a < 4; ++a)
#pragma unroll
    for (int s2 = 0; s2 < 16; ++s2) acc[a][s2] = 0.f;

  for (int ic = 0; ic < 3; ++ic) {
    float wv[4][9];
#pragma unroll
    for (int oi = 0; oi < 4; ++oi) {
      int oc = oi * 4 + ocg;
      float4 w0 = *(const float4*)&ws[ic][oc][0];
      float4 w1 = *(const float4*)&ws[ic][oc][4];
      float4 w2 = *(const float4*)&ws[ic][oc][8];
      wv[oi][0] = w0.x; wv[oi][1] = w0.y; wv[oi][2] = w0.z; wv[oi][3] = w0.w;
      wv[oi][4] = w1.x; wv[oi][5] = w1.y; wv[oi][6] = w1.z; wv[oi][7] = w1.w;
      wv[oi][8] = w2.x;
    }
#pragma unroll
    for (int r = 0; r < 2; ++r) {
#pragma unroll
      for (int ki = 0; ki < 3; ++ki) {
        int l = 4 * rg + 2 * r + ki;
        float xr[17];
#pragma unroll
        for (int t = 0; t < 17; ++t) xr[t] = xin[ic][l][16 * cg + t];
#pragma unroll
        for (int oi = 0; oi < 4; ++oi)
#pragma unroll
          for (int kj = 0; kj < 3; ++kj) {
            float wc = wv[oi][ki * 3 + kj];
#pragma unroll
            for (int q = 0; q < 8; ++q)
              acc[oi][r * 8 + q] = fmaf(wc, xr[2 * q + kj], acc[oi][r * 8 + q]);
          }
      }
    }
  }
#pragma unroll
  for (int oi = 0; oi < 4; ++oi) {
    int oc = oi * 4 + ocg;
    float bb = bs[oc];
#pragma unroll
    for (int r = 0; r < 2; ++r) {
      int orow = R0 + 2 * rg + r;
#pragma unroll
      for (int q = 0; q < 8; ++q)
        out[((n * 16 + oc) * 64 + orow) * 64 + 8 * cg + q] = acc[oi][r * 8 + q] + bb;
    }
  }
}

// ================= conv2: 16->32, 64->32 =================
__global__ __launch_bounds__(TPB, 2) void conv2_tiled(
    const float* __restrict__ in, const float* __restrict__ ss,
    const float* __restrict__ w, const float* __restrict__ bias,
    float* __restrict__ out) {
  __shared__ float xin[8][17][67];
  __shared__ float ws[16][32][12];
  __shared__ float bs[32];
  const int tid = threadIdx.x;
  const int blk = blockIdx.x;
  const int n = blk >> 2, R0 = (blk & 3) << 3;
  for (int s = tid; s < 16 * 32 * 12; s += TPB) {
    int t = s % 12; int oc = (s / 12) & 31; int ic = s / 384;
    ws[ic][oc][t] = (t < 9) ? w[(oc * 16 + ic) * 9 + t] : 0.f;
  }
  if (tid < 32) bs[tid] = bias[tid];

  const int ocg = (tid >> 3) & 7;
  const int cg = tid & 7;
  const int rg = tid >> 6;
  float acc[4][2][4];
#pragma unroll
  for (int a = 0; a < 4; ++a)
#pragma unroll
    for (int r = 0; r < 2; ++r)
#pragma unroll
      for (int q = 0; q < 4; ++q) acc[a][r][q] = 0.f;

  for (int ch = 0; ch < 2; ++ch) {
    __syncthreads();
    for (int s = tid; s < 8 * 17 * 16; s += TPB) {
      int g = s & 15; int l = (s >> 4) % 17; int ic = s / 272;
      int icg = ch * 8 + ic;
      int i = 2 * R0 - 1 + l;
      int j0 = g * 4;
      float4 v = make_float4(0.f, 0.f, 0.f, 0.f);
      if (i >= 0) v = *(const float4*)&in[((n * 16 + icg) << 12) + (i << 6) + j0];
      float sc = ss[2 * icg], sh = ss[2 * icg + 1];
      xin[ic][l][1 + j0]     = fmaxf(fmaf(v.x, sc, sh), 0.f);
      xin[ic][l][1 + j0 + 1] = fmaxf(fmaf(v.y, sc, sh), 0.f);
      xin[ic][l][1 + j0 + 2] = fmaxf(fmaf(v.z, sc, sh), 0.f);
      xin[ic][l][1 + j0 + 3] = fmaxf(fmaf(v.w, sc, sh), 0.f);
      if (g == 0) xin[ic][l][0] = 0.f;
      if (i < 0) {
        xin[ic][l][1+j0] = 0.f; xin[ic][l][2+j0] = 0.f; xin[ic][l][3+j0] = 0.f; xin[ic][l][4+j0] = 0.f;
      }
    }
    __syncthreads();
    for (int ic = 0; ic < 8; ++ic) {
      float wv[4][9];
#pragma unroll
      for (int oi = 0; oi < 4; ++oi) {
        int oc = oi * 8 + ocg;
        float4 w0 = *(const float4*)&ws[ch * 8 + ic][oc][0];
        float4 w1 = *(const float4*)&ws[ch * 8 + ic][oc][4];
        float4 w2 = *(const float4*)&ws[ch * 8 + ic][oc][8];
        wv[oi][0] = w0.x; wv[oi][1] = w0.y; wv[oi][2] = w0.z; wv[oi][3] = w0.w;
        wv[oi][4] = w1.x; wv[oi][5] = w1.y; wv[oi][6] = w1.z; wv[oi][7] = w1.w;
        wv[oi][8] = w2.x;
      }
#pragma unroll
      for (int r = 0; r < 2; ++r) {
#pragma unroll
        for (int ki = 0; ki < 3; ++ki) {
          int l = 4 * rg + 2 * r + ki;
          float xr[9];
#pragma unroll
          for (int t = 0; t < 9; ++t) xr[t] = xin[ic][l][8 * cg + t];
#pragma unroll
          for (int oi = 0; oi < 4; ++oi)
#pragma unroll
            for (int kj = 0; kj < 3; ++kj) {
              float wc = wv[oi][ki * 3 + kj];
#pragma unroll
              for (int q = 0; q < 4; ++q)
                acc[oi][r][q] = fmaf(wc, xr[2 * q + kj], acc[oi][r][q]);
            }
        }
      }
    }
  }
#pragma unroll
  for (int oi = 0; oi < 4; ++oi) {
    int oc = oi * 8 + ocg;
    float bb = bs[oc];
#pragma unroll
    for (int r = 0; r < 2; ++r) {
      int orow = R0 + 2 * rg + r;
#pragma unroll
      for (int q = 0; q < 4; ++q)
        out[((n * 32 + oc) * 32 + orow) * 32 + 4 * cg + q] = acc[oi][r][q] + bb;
    }
  }
}

// ================= conv3: 32->64, 32->16 =================
__global__ __launch_bounds__(TPB, 2) void conv3_tiled(
    const float* __restrict__ in, const float* __restrict__ ss,
    const float* __restrict__ w, const float* __restrict__ bias,
    float* __restrict__ out) {
  __shared__ float xin[8][33][35];
  __shared__ float ws[8][64][12];
  __shared__ float bs[64];
  const int tid = threadIdx.x;
  const int n = blockIdx.x;
  if (tid < 64) bs[tid] = bias[tid];

  const int ocg = (tid >> 3) & 7;
  const int cg = tid & 3;
  const int rg = ((tid >> 2) & 1) | ((tid >> 6) << 1);
  float acc[8][2][4];
#pragma unroll
  for (int a = 0; a < 8; ++a)
#pragma unroll
    for (int r = 0; r < 2; ++r)
#pragma unroll
      for (int q = 0; q < 4; ++q) acc[a][r][q] = 0.f;

  for (int ch = 0; ch < 4; ++ch) {
    __syncthreads();
    for (int s = tid; s < 8 * 64 * 12; s += TPB) {
      int t = s % 12; int oc = (s / 12) & 63; int ic = s / 768;
      ws[ic][oc][t] = (t < 9) ? w[(oc * 32 + ch * 8 + ic) * 9 + t] : 0.f;
    }
    for (int s = tid; s < 8 * 33 * 8; s += TPB) {
      int g = s & 7; int l = (s >> 3) % 33; int ic = s / 264;
      int icg = ch * 8 + ic;
      int i = l - 1;
      int j0 = g * 4;
      float4 v = make_float4(0.f, 0.f, 0.f, 0.f);
      if (i >= 0) v = *(const float4*)&in[((n * 32 + icg) << 10) + (i << 5) + j0];
      float sc = ss[2 * icg], sh = ss[2 * icg + 1];
      float o0 = fmaxf(fmaf(v.x, sc, sh), 0.f), o1 = fmaxf(fmaf(v.y, sc, sh), 0.f);
      float o2 = fmaxf(fmaf(v.z, sc, sh), 0.f), o3 = fmaxf(fmaf(v.w, sc, sh), 0.f);
      if (i < 0) { o0 = 0.f; o1 = 0.f; o2 = 0.f; o3 = 0.f; }
      xin[ic][l][1 + j0] = o0; xin[ic][l][2 + j0] = o1;
      xin[ic][l][3 + j0] = o2; xin[ic][l][4 + j0] = o3;
      if (g == 0) xin[ic][l][0] = 0.f;
    }
    __syncthreads();
    for (int ic = 0; ic < 8; ++ic) {
      float wv[8][9];
#pragma unroll
      for (int oi = 0; oi < 8; ++oi) {
        int oc = oi * 8 + ocg;
        float4 w0 = *(const float4*)&ws[ic][oc][0];
        float4 w1 = *(const float4*)&ws[ic][oc][4];
        float4 w2 = *(const float4*)&ws[ic][oc][8];
        wv[oi][0] = w0.x; wv[oi][1] = w0.y; wv[oi][2] = w0.z; wv[oi][3] = w0.w;
        wv[oi][4] = w1.x; wv[oi][5] = w1.y; wv[oi][6] = w1.z; wv[oi][7] = w1.w;
        wv[oi][8] = w2.x;
      }
#pragma unroll
      for (int r = 0; r < 2; ++r) {
#pragma unroll
        for (int ki = 0; ki < 3; ++ki) {
          int l = 4 * rg + 2 * r + ki;
          float xr[9];
#pragma unroll
          for (int t = 0; t < 9; ++t) xr[t] = xin[ic][l][8 * cg + t];
#pragma unroll
          for (int oi = 0; oi < 8; ++oi)
#pragma unroll
            for (int kj = 0; kj < 3; ++kj) {
              float wc = wv[oi][ki * 3 + kj];
#pragma unroll
              for (int q = 0; q < 4; ++q)
                acc[oi][r][q] = fmaf(wc, xr[2 * q + kj], acc[oi][r][q]);
            }
        }
      }
    }
  }
#pragma unroll
  for (int oi = 0; oi < 8; ++oi) {
    int oc = oi * 8 + ocg;
    float bb = bs[oc];
#pragma unroll
    for (int r = 0; r < 2; ++r) {
      int orow = 2 * rg + r;
#pragma unroll
      for (int q = 0; q < 4; ++q)
        out[((n * 64 + oc) << 8) + (orow << 4) + 4 * cg + q] = acc[oi][r][q] + bb;
    }
  }
}

// ================= conv4: 64->128, 16->8 =================
__global__ __launch_bounds__(TPB, 2) void conv4_tiled(
    const float* __restrict__ in, const float* __restrict__ ss,
    const float* __restrict__ w, const float* __restrict__ bias,
    float* __restrict__ out) {
  __shared__ float xin[8][17][19];
  __shared__ float ws[8][128][12];
  __shared__ float bs[128];
  const int tid = threadIdx.x;
  const int n = blockIdx.x;
  if (tid < 128) bs[tid] = bias[tid];

  const int ocg = (tid >> 2) & 15;
  const int cg = tid & 3;
  const int rg = tid >> 6;
  float acc[8][2][2];
#pragma unroll
  for (int a = 0; a < 8; ++a)
#pragma unroll
    for (int r = 0; r < 2; ++r)
#pragma unroll
      for (int q = 0; q < 2; ++q) acc[a][r][q] = 0.f;

  for (int ch = 0; ch < 8; ++ch) {
    __syncthreads();
    for (int s = tid; s < 8 * 128 * 12; s += TPB) {
      int t = s % 12; int oc = (s / 12) & 127; int ic = s / 1536;
      ws[ic][oc][t] = (t < 9) ? w[(oc * 64 + ch * 8 + ic) * 9 + t] : 0.f;
    }
    for (int s = tid; s < 8 * 17 * 4; s += TPB) {
      int g = s & 3; int l = (s >> 2) % 17; int ic = s / 68;
      int icg = ch * 8 + ic;
      int i = l - 1;
      int j0 = g * 4;
      float4 v = make_float4(0.f, 0.f, 0.f, 0.f);
      if (i >= 0) v = *(const float4*)&in[((n * 64 + icg) << 8) + (i << 4) + j0];
      float sc = ss[2 * icg], sh = ss[2 * icg + 1];
      float o0 = fmaxf(fmaf(v.x, sc, sh), 0.f), o1 = fmaxf(fmaf(v.y, sc, sh), 0.f);
      float o2 = fmaxf(fmaf(v.z, sc, sh), 0.f), o3 = fmaxf(fmaf(v.w, sc, sh), 0.f);
      if (i < 0) { o0 = 0.f; o1 = 0.f; o2 = 0.f; o3 = 0.f; }
      xin[ic][l][1 + j0] = o0; xin[ic][l][2 + j0] = o1;
      xin[ic][l][3 + j0] = o2; xin[ic][l][4 + j0] = o3;
      if (g == 0) xin[ic][l][0] = 0.f;
    }
    __syncthreads();
    for (int ic = 0; ic < 8; ++ic) {
      float wv[8][9];
#pragma unroll
      for (int oi = 0; oi < 8; ++oi) {
        int oc = oi * 16 + ocg;
        float4 w0 = *(const float4*)&ws[ic][oc][0];
        float4 w1 = *(const float4*)&ws[ic][oc][4];
        float4 w2 = *(const float4*)&ws[ic][oc][8];
        wv[oi][0] = w0.x; wv[oi][1] = w0.y; wv[oi][2] = w0.z; wv[oi][3] = w0.w;
        wv[oi][4] = w1.x; wv[oi][5] = w1.y; wv[oi][6] = w1.z; wv[oi][7] = w1.w;
        wv[oi][8] = w2.x;
      }
#pragma unroll
      for (int r = 0; r < 2; ++r) {
#pragma unroll
        for (int ki = 0; ki < 3; ++ki) {
          int l = 4 * rg + 2 * r + ki;
          float xr[5];
#pragma unroll
          for (int t = 0; t < 5; ++t) xr[t] = xin[ic][l][4 * cg + t];
#pragma unroll
          for (int oi = 0; oi < 8; ++oi)
#pragma unroll
            for (int kj = 0; kj < 3; ++kj) {
              float wc = wv[oi][ki * 3 + kj];
#pragma unroll
              for (int q = 0; q < 2; ++q)
                acc[oi][r][q] = fmaf(wc, xr[2 * q + kj], acc[oi][r][q]);
            }
        }
      }
    }
  }
#pragma unroll
  for (int oi = 0; oi < 8; ++oi) {
    int oc = oi * 16 + ocg;
    float bb = bs[oc];
#pragma unroll
    for (int r = 0; r < 2; ++r) {
      int orow = 2 * rg + r;
#pragma unroll
      for (int q = 0; q < 2; ++q)
        out[((n * 128 + oc) << 6) + (orow << 3) + 2 * cg + q] = acc[oi][r][q] + bb;
    }
  }
}

// ---------- BN statistics (deterministic two-stage) ----------
__global__ __launch_bounds__(TPB) void stats_partial_kernel(
    const float* __restrict__ y, float* __restrict__ part, int C, int HW) {
  int bid = blockIdx.x;
  int c = bid >> 6;
  int s = bid & 63;
  float sum = 0.f, sq = 0.f;
  for (int nn = 0; nn < 8; ++nn) {
    int n = s * 8 + nn;
    const float* p = y + (n * C + c) * HW;
    for (int i = threadIdx.x; i < HW; i += TPB) {
      float v = p[i];
      sum += v; sq = fmaf(v, v, sq);
    }
  }
  __shared__ float rs[TPB], rq[TPB];
  rs[threadIdx.x] = sum; rq[threadIdx.x] = sq;
  __syncthreads();
  for (int off = TPB / 2; off > 0; off >>= 1) {
    if (threadIdx.x < off) { rs[threadIdx.x] += rs[threadIdx.x + off]; rq[threadIdx.x] += rq[threadIdx.x + off]; }
    __syncthreads();
  }
  if (threadIdx.x == 0) { part[bid * 2] = rs[0]; part[bid * 2 + 1] = rq[0]; }
}

__global__ void stats_final_kernel(const float* __restrict__ part,
    const float* __restrict__ gamma, const float* __restrict__ beta,
    float* __restrict__ ss, float inv_count) {
  int c = blockIdx.x;
  int t = threadIdx.x;  // 64
  float sum = part[(c * 64 + t) * 2];
  float sq  = part[(c * 64 + t) * 2 + 1];
  for (int off = 32; off > 0; off >>= 1) {
    sum += __shfl_down(sum, off);
    sq  += __shfl_down(sq, off);
  }
  if (t == 0) {
    float mean = sum * inv_count;
    float var  = sq * inv_count - mean * mean;
    float rstd = rsqrtf(var + 1e-5f);
    float scl  = gamma[c] * rstd;
    ss[2 * c] = scl;
    ss[2 * c + 1] = beta[c] - mean * scl;
  }
}

// ---------- BN+ReLU for layer 4, writing bf16 for the MFMA FC ----------
__global__ __launch_bounds__(TPB) void bnrelu_bf16_kernel(const float* __restrict__ y,
    const float* __restrict__ ss, unsigned short* __restrict__ out) {
  int q = blockIdx.x * TPB + threadIdx.x;   // quad index, total 1048576
  if (q >= 1048576) return;
  int c = (q >> 4) & 127;
  float sc = ss[2 * c], sh = ss[2 * c + 1];
  float4 v = ((const float4*)y)[q];
  ushort4 o;
  o.x = f2bf(fmaxf(fmaf(v.x, sc, sh), 0.f));
  o.y = f2bf(fmaxf(fmaf(v.y, sc, sh), 0.f));
  o.z = f2bf(fmaxf(fmaf(v.z, sc, sh), 0.f));
  o.w = f2bf(fmaxf(fmaf(v.w, sc, sh), 0.f));
  ((ushort4*)out)[q] = o;
}

// ---------- fp32 -> bf16 cast (for fw1) ----------
__global__ __launch_bounds__(TPB) void cast_bf16_kernel(const float* __restrict__ in,
    unsigned short* __restrict__ out, int nquad) {
  int q = blockIdx.x * TPB + threadIdx.x;
  if (q >= nquad) return;
  float4 v = ((const float4*)in)[q];
  ushort4 o;
  o.x = f2bf(v.x); o.y = f2bf(v.y); o.z = f2bf(v.z); o.w = f2bf(v.w);
  ((ushort4*)out)[q] = o;
}

// ---------- fc1: bf16 MFMA GEMM, M=N=512, K=8192, relu epilogue ----------
// grid dim3(8,8), 256 threads. A,W row-major bf16. out fp32.
__global__ __launch_bounds__(TPB, 2) void fc1_mfma(
    const unsigned short* __restrict__ A, const unsigned short* __restrict__ W,
    const float* __restrict__ bias, float* __restrict__ out) {
  __shared__ unsigned short As[64][64];
  __shared__ unsigned short Bs[64][64];
  const int tid = threadIdx.x;
  const int lane = tid & 63, wave = tid >> 6;
  const int wr = (wave >> 1) * 32, wc = (wave & 1) * 32;
  const int bm = blockIdx.y * 64, bn = blockIdx.x * 64;
  f32x4 acc00 = {0.f, 0.f, 0.f, 0.f}, acc01 = acc00, acc10 = acc00, acc11 = acc00;
  const int r0 = tid >> 3, c0 = tid & 7;
  const int fr = lane & 15, kg = lane >> 4;
  for (int kt = 0; kt < 128; ++kt) {
    const int kb = kt * 64;
    uint4 av0 = *(const uint4*)&A[(size_t)(bm + r0) * 8192 + kb + c0 * 8];
    uint4 av1 = *(const uint4*)&A[(size_t)(bm + r0 + 32) * 8192 + kb + c0 * 8];
    uint4 bv0 = *(const uint4*)&W[(size_t)(bn + r0) * 8192 + kb + c0 * 8];
    uint4 bv1 = *(const uint4*)&W[(size_t)(bn + r0 + 32) * 8192 + kb + c0 * 8];
    __syncthreads();
    *(uint4*)&As[r0][(c0 ^ (r0 & 7)) * 8] = av0;
    *(uint4*)&As[r0 + 32][(c0 ^ (r0 & 7)) * 8] = av1;
    *(uint4*)&Bs[r0][(c0 ^ (r0 & 7)) * 8] = bv0;
    *(uint4*)&Bs[r0 + 32][(c0 ^ (r0 & 7)) * 8] = bv1;
    __syncthreads();
#pragma unroll
    for (int ks = 0; ks < 2; ++ks) {
      int ch = ks * 4 + kg;
      int ra0 = wr + fr, ra1 = wr + 16 + fr;
      int rb0 = wc + fr, rb1 = wc + 16 + fr;
      bf16x8 a_0 = lda_bf8(&As[ra0][(ch ^ (ra0 & 7)) * 8]);
      bf16x8 a_1 = lda_bf8(&As[ra1][(ch ^ (ra1 & 7)) * 8]);
      bf16x8 b_0 = lda_bf8(&Bs[rb0][(ch ^ (rb0 & 7)) * 8]);
      bf16x8 b_1 = lda_bf8(&Bs[rb1][(ch ^ (rb1 & 7)) * 8]);
      acc00 = __builtin_amdgcn_mfma_f32_16x16x32_bf16(a_0, b_0, acc00, 0, 0, 0);
      acc01 = __builtin_amdgcn_mfma_f32_16x16x32_bf16(a_0, b_1, acc01, 0, 0, 0);
      acc10 = __builtin_amdgcn_mfma_f32_16x16x32_bf16(a_1, b_0, acc10, 0, 0, 0);
      acc11 = __builtin_amdgcn_mfma_f32_16x16x32_bf16(a_1, b_1, acc11, 0, 0, 0);
    }
  }
  const int rg = lane >> 4;
  int n0 = bn + wc + fr, n1 = n0 + 16;
  float bi0 = bias[n0], bi1 = bias[n1];
#pragma unroll
  for (int r = 0; r < 4; ++r) {
    int m0 = bm + wr + rg * 4 + r, m1 = m0 + 16;
    out[m0 * 512 + n0] = fmaxf(acc00[r] + bi0, 0.f);
    out[m0 * 512 + n1] = fmaxf(acc01[r] + bi1, 0.f);
    out[m1 * 512 + n0] = fmaxf(acc10[r] + bi0, 0.f);
    out[m1 * 512 + n1] = fmaxf(acc11[r] + bi1, 0.f);
  }
}

// ---------- generic tiled GEMM (fp32, small layers) ----------
__global__ __launch_bounds__(TPB) void gemm_rt(const float* __restrict__ A,
    const float* __restrict__ W, const float* __restrict__ bias,
    float* __restrict__ out, int M, int N, int K, int dorelu) {
  __shared__ float As[32][33];
  __shared__ float Ws[32][33];
  int tid = threadIdx.x;
  int tx = tid & 15, ty = tid >> 4;
  int bm = blockIdx.y << 5, bn = blockIdx.x << 5;
  float a00 = 0.f, a01 = 0.f, a10 = 0.f, a11 = 0.f;
  int nk = (K + 31) >> 5;
  for (int kt = 0; kt < nk; ++kt) {
    int k0 = kt << 5;
#pragma unroll
    for (int l = 0; l < 4; ++l) {
      int idx = tid + (l << 8);
      int r = idx >> 5, c = idx & 31;
      int gc = k0 + c;
      int ga = bm + r;
      As[c][r] = (ga < M && gc < K) ? A[ga * K + gc] : 0.f;
      int gw = bn + r;
      Ws[c][r] = (gw < N && gc < K) ? W[gw * K + gc] : 0.f;
    }
    __syncthreads();
#pragma unroll
    for (int k = 0; k < 32; ++k) {
      float x0 = As[k][ty], x1 = As[k][ty + 16];
      float y0 = Ws[k][tx], y1 = Ws[k][tx + 16];
      a00 = fmaf(x0, y0, a00); a01 = fmaf(x0, y1, a01);
      a10 = fmaf(x1, y0, a10); a11 = fmaf(x1, y1, a11);
    }
    __syncthreads();
  }
  int m0 = bm + ty, m1 = m0 + 16, n0 = bn + tx, n1 = n0 + 16;
  if (m0 < M && n0 < N) { float v = a00 + bias[n0]; out[m0 * N + n0] = dorelu ? fmaxf(v, 0.f) : v; }
  if (m0 < M && n1 < N) { float v = a01 + bias[n1]; out[m0 * N + n1] = dorelu ? fmaxf(v, 0.f) : v; }
  if (m1 < M && n0 < N) { float v = a10 + bias[n0]; out[m1 * N + n0] = dorelu ? fmaxf(v, 0.f) : v; }
  if (m1 < M && n1 < N) { float v = a11 + bias[n1]; out[m1 * N + n1] = dorelu ? fmaxf(v, 0.f) : v; }
}

// ---------- small builders ----------
__global__ __launch_bounds__(TPB) void build_enh_kernel(const float* __restrict__ cond,
    const float* __restrict__ steps, float* __restrict__ enh) {
  int i = blockIdx.x * TPB + threadIdx.x;
  if (i >= 512 * 6) return;
  int n = i / 6, k = i % 6;
  int b = n >> 6, s = n & 63;
  enh[i] = (k < 5) ? cond[b * 5 + k] : steps[b * 64 + s];
}

__global__ __launch_bounds__(TPB) void build_comb_kernel(const float* __restrict__ lo,
    const float* __restrict__ mapf, const float* __restrict__ condf, float* __restrict__ comb) {
  int i = blockIdx.x * TPB + threadIdx.x;
  if (i >= 512 * 576) return;
  int n = i / 576, k = i % 576;
  float v;
  if (k < 256)      v = lo[n * 256 + k];
  else if (k < 512) v = mapf[n * 256 + (k - 256)];
  else              v = condf[n * 64 + (k - 512)];
  comb[i] = v;
}

// ---------- LSTM: 64 blocks, weight-partitioned, pipelined ----------
// Cross-block h exchange via RELAXED agent-scope atomics on packed 2xbf16
// (complete at IF$ = cross-XCD coherence point; no buffer_wbl2/buffer_inv).
__global__ __launch_bounds__(TPB) void lstm_kernel(
    const float* __restrict__ embv,
    const float* __restrict__ w_ih0, const float* __restrict__ w_hh0,
    const float* __restrict__ b_ih0, const float* __restrict__ b_hh0,
    const float* __restrict__ w_ih1, const float* __restrict__ w_hh1,
    const float* __restrict__ b_ih1, const float* __restrict__ b_hh1,
    unsigned int* __restrict__ h0x,   // [64][1024] packed bf16 pairs
    unsigned int* __restrict__ h1x,   // [64][1024]
    float* __restrict__ lstm_out,     // [8][64][256]
    int* __restrict__ bar) {
  const int tid = threadIdx.x;
  const int u0 = blockIdx.x * 4;

  __shared__ float whh0s[16][260];
  __shared__ float wih1s[16][260];
  __shared__ float whh1s[16][260];
  __shared__ float wih0s[16][32];
  __shared__ unsigned short hps[8][264];
  __shared__ unsigned short h1ps[8][264];
  __shared__ float x0s[8][32];
  __shared__ float zg0s[8][16];
  __shared__ float zg1s[8][16];
  __shared__ float bias0s[16], bias1s[16];
  __shared__ float c0s[8][4], c1s[8][4];
  __shared__ float h0loc[8][4], h1loc[8][4];

  for (int idx = tid; idx < 16 * 256; idx += TPB) {
    int r = idx >> 8, k = idx & 255;
    int gate = r >> 2, uu = r & 3;
    int R = gate * 256 + u0 + uu;
    whh0s[r][k] = w_hh0[R * 256 + k];
    wih1s[r][k] = w_ih1[R * 256 + k];
    whh1s[r][k] = w_hh1[R * 256 + k];
  }
  for (int idx = tid; idx < 16 * 32; idx += TPB) {
    int r = idx >> 5, k = idx & 31;
    int gate = r >> 2, uu = r & 3;
    int R = gate * 256 + u0 + uu;
    wih0s[r][k] = w_ih0[R * 32 + k];
  }
  if (tid < 16) {
    int gate = tid >> 2, uu = tid & 3;
    int R = gate * 256 + u0 + uu;
    bias0s[tid] = b_ih0[R] + b_hh0[R];
    bias1s[tid] = b_ih1[R] + b_hh1[R];
  }
  if (tid < 32) c0s[tid >> 2][tid & 3] = 0.f;
  else if (tid < 64) { int t = tid - 32; c1s[t >> 2][t & 3] = 0.f; }
  __syncthreads();

  for (int p = 0; p <= 64; ++p) {
    // stage previous h states (packed bf16, relaxed device-scope atomics)
#pragma unroll
    for (int q = 0; q < 4; ++q) {
      int idx = tid + q * 256;             // 0..1023
      int bb = idx >> 7, k2 = idx & 127;
      unsigned int d0 = 0u, d1 = 0u;
      if (p >= 1) d0 = __hip_atomic_load(&h0x[(p - 1) * 1024 + idx], __ATOMIC_RELAXED, __HIP_MEMORY_SCOPE_AGENT);
      if (p >= 2) d1 = __hip_atomic_load(&h1x[(p - 2) * 1024 + idx], __ATOMIC_RELAXED, __HIP_MEMORY_SCOPE_AGENT);
      *(unsigned int*)&hps[bb][k2 * 2] = d0;
      *(unsigned int*)&h1ps[bb][k2 * 2] = d1;
    }
    {
      int b = tid >> 5, k = tid & 31;
      x0s[b][k] = (p < 64) ? embv[(b * 64 + p) * 32 + k] : 0.f;
    }
    __syncthreads();

    if (tid < 128) {
      if (p < 64) {
        int b = tid >> 4, r = tid & 15;
        float acc = bias0s[r];
#pragma unroll
        for (int k = 0; k < 32; k += 4) {
          float4 w4 = *(const float4*)&wih0s[r][k];
          acc = fmaf(w4.x, x0s[b][k],     acc);
          acc = fmaf(w4.y, x0s[b][k + 1], acc);
          acc = fmaf(w4.z, x0s[b][k + 2], acc);
          acc = fmaf(w4.w, x0s[b][k + 3], acc);
        }
        for (int k = 0; k < 256; k += 4) {
          float4 w4 = *(const float4*)&whh0s[r][k];
          ushort4 u = *(const ushort4*)&hps[b][k];
          acc = fmaf(w4.x, bf2f(u.x), acc);
          acc = fmaf(w4.y, bf2f(u.y), acc);
          acc = fmaf(w4.z, bf2f(u.z), acc);
          acc = fmaf(w4.w, bf2f(u.w), acc);
        }
        zg0s[b][r] = acc;
      }
    } else {
      if (p >= 1) {
        int t = tid - 128;
        int b = t >> 4, r = t & 15;
        float acc = bias1s[r];
        for (int k = 0; k < 256; k += 4) {
          float4 wa = *(const float4*)&wih1s[r][k];
          ushort4 ux = *(const ushort4*)&hps[b][k];
          float4 wb = *(const float4*)&whh1s[r][k];
          ushort4 uh = *(const ushort4*)&h1ps[b][k];
          acc = fmaf(wa.x, bf2f(ux.x), acc);
          acc = fmaf(wa.y, bf2f(ux.y), acc);
          acc = fmaf(wa.z, bf2f(ux.z), acc);
          acc = fmaf(wa.w, bf2f(ux.w), acc);
          acc = fmaf(wb.x, bf2f(uh.x), acc);
          acc = fmaf(wb.y, bf2f(uh.y), acc);
          acc = fmaf(wb.z, bf2f(uh.z), acc);
          acc = fmaf(wb.w, bf2f(uh.w), acc);
        }
        zg1s[b][r] = acc;
      }
    }
    __syncthreads();

    if (tid < 32 && p < 64) {
      int b = tid >> 2, uu = tid & 3;
      float zi = zg0s[b][uu], zf = zg0s[b][4 + uu], zg = zg0s[b][8 + uu], zo = zg0s[b][12 + uu];
      float c = sigf(zf) * c0s[b][uu] + sigf(zi) * tanhf(zg);
      c0s[b][uu] = c;
      h0loc[b][uu] = sigf(zo) * tanhf(c);
    }
    if (tid >= 32 && tid < 64 && p >= 1) {
      int t = tid - 32;
      int b = t >> 2, uu = t & 3;
      float zi = zg1s[b][uu], zf = zg1s[b][4 + uu], zg = zg1s[b][8 + uu], zo = zg1s[b][12 + uu];
      float c = sigf(zf) * c1s[b][uu] + sigf(zi) * tanhf(zg);
      c1s[b][uu] = c;
      float h = sigf(zo) * tanhf(c);
      h1loc[b][uu] = h;
      lstm_out[(b * 64 + (p - 1)) * 256 + u0 + uu] = h;   // fp32 for the head
    }
    __syncthreads();

    // pack & publish this block's h values (2 bf16 per dword)
    if (tid < 16 && p < 64) {
      int b = tid >> 1, pp = tid & 1;
      unsigned int v = (unsigned int)f2bf(h0loc[b][2 * pp]) |
                       ((unsigned int)f2bf(h0loc[b][2 * pp + 1]) << 16);
      __hip_atomic_store(&h0x[p * 1024 + b * 128 + (u0 >> 1) + pp], v,
                         __ATOMIC_RELAXED, __HIP_MEMORY_SCOPE_AGENT);
    } else if (tid >= 16 && tid < 32 && p >= 1) {
      int t = tid - 16;
      int b = t >> 1, pp = t & 1;
      unsigned int v = (unsigned int)f2bf(h1loc[b][2 * pp]) |
                       ((unsigned int)f2bf(h1loc[b][2 * pp + 1]) << 16);
      __hip_atomic_store(&h1x[(p - 1) * 1024 + b * 128 + (u0 >> 1) + pp], v,
                         __ATOMIC_RELAXED, __HIP_MEMORY_SCOPE_AGENT);
    }
    asm volatile("s_waitcnt vmcnt(0)" ::: "memory");  // stores complete at IF$
    __syncthreads();

    if (tid == 0) {
      __hip_atomic_fetch_add(&bar[p], 1, __ATOMIC_RELAXED, __HIP_MEMORY_SCOPE_AGENT);
      while (__hip_atomic_load(&bar[p], __ATOMIC_RELAXED, __HIP_MEMORY_SCOPE_AGENT) < NLB)
        __builtin_amdgcn_s_sleep(1);
    }
    __syncthreads();
  }
}

// ---------- launcher ----------
extern "C" void kernel_launch(void* const* d_in, const int* in_sizes, int n_in,
                              void* d_out, int out_size, void* d_ws, size_t ws_size,
                              hipStream_t stream) {
  const float* fmap  = (const float*)d_in[0];
  const float* cond  = (const float*)d_in[1];
  const float* iseq  = (const float*)d_in[2];
  const float* steps = (const float*)d_in[3];
  const float* cw1 = (const float*)d_in[4];  const float* cb1 = (const float*)d_in[5];
  const float* g1  = (const float*)d_in[6];  const float* be1 = (const float*)d_in[7];
  const float* cw2 = (const float*)d_in[8];  const float* cb2 = (const float*)d_in[9];
  const float* g2  = (const float*)d_in[10]; const float* be2 = (const float*)d_in[11];
  const float* cw3 = (const float*)d_in[12]; const float* cb3 = (const float*)d_in[13];
  const float* g3  = (const float*)d_in[14]; const float* be3 = (const float*)d_in[15];
  const float* cw4 = (const float*)d_in[16]; const float* cb4 = (const float*)d_in[17];
  const float* g4  = (const float*)d_in[18]; const float* be4 = (const float*)d_in[19];
  const float* fw1 = (const float*)d_in[20]; const float* fb1 = (const float*)d_in[21];
  const float* fw2 = (const float*)d_in[22]; const float* fb2 = (const float*)d_in[23];
  const float* ew1 = (const float*)d_in[24]; const float* eb1 = (const float*)d_in[25];
  const float* ew2 = (const float*)d_in[26]; const float* eb2 = (const float*)d_in[27];
  const float* mw  = (const float*)d_in[28]; const float* mb  = (const float*)d_in[29];
  const float* w_ih0 = (const float*)d_in[30]; const float* w_hh0 = (const float*)d_in[31];
  const float* b_ih0 = (const float*)d_in[32]; const float* b_hh0 = (const float*)d_in[33];
  const float* w_ih1 = (const float*)d_in[34]; const float* w_hh1 = (const float*)d_in[35];
  const float* b_ih1 = (const float*)d_in[36]; const float* b_hh1 = (const float*)d_in[37];
  const float* xw1 = (const float*)d_in[38]; const float* xb1 = (const float*)d_in[39];
  const float* xw2 = (const float*)d_in[40]; const float* xb2 = (const float*)d_in[41];
  const float* ow  = (const float*)d_in[42]; const float* ob  = (const float*)d_in[43];

  float* ws = (float*)d_ws;
  float* y1 = ws;                    // 33,554,432 f (dead after conv2)
  float* y2 = ws + 33554432;         // 16,777,216 f (dead after conv3)
  float* y3 = ws;                    // 8,388,608 f (overlays y1; dead after conv4)
  float* y4 = ws + 33554432;         // 4,194,304 f (overlays y2)
  unsigned short* y4bf  = (unsigned short*)ws;              // 4,194,304 bf16 (after conv4)
  unsigned short* fw1bf = (unsigned short*)(ws + 8388608);  // 4,194,304 bf16 (after conv2)
  size_t base = 50331648;
  float* part  = ws + base; base += 16384;
  float* ss1   = ws + base; base += 32;
  float* ss2   = ws + base; base += 64;
  float* ss3   = ws + base; base += 128;
  float* ss4   = ws + base; base += 256;
  float* f1    = ws + base; base += 262144;
  float* mapf  = ws + base; base += 131072;
  float* enh   = ws + base; base += 3072;
  float* ceh   = ws + base; base += 65536;
  float* condf = ws + base; base += 32768;
  float* embb  = ws + base; base += 16384;
  unsigned int* h0x = (unsigned int*)(ws + base); base += 65536;
  unsigned int* h1x = (unsigned int*)(ws + base); base += 65536;
  float* lout  = ws + base; base += 131072;
  float* comb  = ws + base; base += 294912;
  float* cx1   = ws + base; base += 65536;
  float* cx2   = ws + base; base += 32768;
  int*   bar   = (int*)(ws + base); base += 128;

  // --- encoder convs (LDS-tiled) with batch-stat BN folded to scale/shift ---
  conv1_tiled<<<2048, TPB, 0, stream>>>(fmap, iseq, cw1, cb1, y1);
  stats_partial_kernel<<<16 * 64, TPB, 0, stream>>>(y1, part, 16, 4096);
  stats_final_kernel<<<16, 64, 0, stream>>>(part, g1, be1, ss1, 1.f / 2097152.f);
  conv2_tiled<<<2048, TPB, 0, stream>>>(y1, ss1, cw2, cb2, y2);
  cast_bf16_kernel<<<4096, TPB, 0, stream>>>(fw1, fw1bf, 1048576);   // y1 region now free
  stats_partial_kernel<<<32 * 64, TPB, 0, stream>>>(y2, part, 32, 1024);
  stats_final_kernel<<<32, 64, 0, stream>>>(part, g2, be2, ss2, 1.f / 524288.f);
  conv3_tiled<<<512, TPB, 0, stream>>>(y2, ss2, cw3, cb3, y3);
  stats_partial_kernel<<<64 * 64, TPB, 0, stream>>>(y3, part, 64, 256);
  stats_final_kernel<<<64, 64, 0, stream>>>(part, g3, be3, ss3, 1.f / 131072.f);
  conv4_tiled<<<512, TPB, 0, stream>>>(y3, ss3, cw4, cb4, y4);
  stats_partial_kernel<<<128 * 64, TPB, 0, stream>>>(y4, part, 128, 64);
  stats_final_kernel<<<128, 64, 0, stream>>>(part, g4, be4, ss4, 1.f / 32768.f);
  bnrelu_bf16_kernel<<<4096, TPB, 0, stream>>>(y4, ss4, y4bf);       // y3 region now free

  // --- map-feature MLP (fc1 via bf16 MFMA) ---
  fc1_mfma<<<dim3(8, 8), TPB, 0, stream>>>(y4bf, fw1bf, fb1, f1);
  gemm_rt<<<dim3(8, 16),  TPB, 0, stream>>>(f1, fw2, fb2, mapf, 512, 256, 512, 0);

  // --- condition encoder ---
  build_enh_kernel<<<12, TPB, 0, stream>>>(cond, steps, enh);
  gemm_rt<<<dim3(4, 16), TPB, 0, stream>>>(enh, ew1, eb1, ceh, 512, 128, 6, 1);
  gemm_rt<<<dim3(2, 16), TPB, 0, stream>>>(ceh, ew2, eb2, condf, 512, 64, 128, 0);

  // --- coord embed + LSTM ---
  gemm_rt<<<dim3(1, 16), TPB, 0, stream>>>(iseq, mw, mb, embb, 512, 32, 2, 1);
  hipMemsetAsync(bar, 0, 65 * sizeof(int), stream);
  lstm_kernel<<<NLB, TPB, 0, stream>>>(embb, w_ih0, w_hh0, b_ih0, b_hh0,
                                       w_ih1, w_hh1, b_ih1, b_hh1, h0x, h1x, lout, bar);

  // --- head ---
  build_comb_kernel<<<1152, TPB, 0, stream>>>(lout, mapf, condf, comb);
  gemm_rt<<<dim3(4, 16), TPB, 0, stream>>>(comb, xw1, xb1, cx1, 512, 128, 576, 1);
  gemm_rt<<<dim3(2, 16), TPB, 0, stream>>>(cx1, xw2, xb2, cx2, 512, 64, 128, 1);
  gemm_rt<<<dim3(1, 16), TPB, 0, stream>>>(cx2, ow, ob, (float*)d_out, 512, 2, 64, 0);
}

// Round 4
// 1199.049 us; speedup vs baseline: 6.1375x; 1.2283x over previous
//
#include <hip/hip_runtime.h>

#define TPB 256
#define NLB 64   // LSTM blocks

typedef float f32x4 __attribute__((ext_vector_type(4)));
typedef short bf16x8 __attribute__((ext_vector_type(8)));

// ---------- helpers ----------
__device__ __forceinline__ float bf2f(unsigned short u) {
  union { unsigned int i; float f; } x; x.i = ((unsigned int)u) << 16; return x.f;
}
__device__ __forceinline__ unsigned short f2bf(float v) {
  union { float f; unsigned int i; } x; x.f = v;
  unsigned int r = (x.i + 0x7fffu + ((x.i >> 16) & 1u)) >> 16;
  return (unsigned short)r;
}
__device__ __forceinline__ float sigf(float x) { return 1.f / (1.f + __expf(-x)); }
__device__ __forceinline__ bf16x8 lda_bf8(const unsigned short* p) {
  union { uint4 u; bf16x8 v; } t; t.u = *(const uint4*)p; return t.v;
}
// 8 bf16 (packed in uint4) * 8 fp32 weights -> acc
__device__ __forceinline__ float fma8(uint4 q, const float* w, float a) {
  union { unsigned int u; float f; } t;
  t.u = q.x << 16;         a = fmaf(w[0], t.f, a);
  t.u = q.x & 0xffff0000u; a = fmaf(w[1], t.f, a);
  t.u = q.y << 16;         a = fmaf(w[2], t.f, a);
  t.u = q.y & 0xffff0000u; a = fmaf(w[3], t.f, a);
  t.u = q.z << 16;         a = fmaf(w[4], t.f, a);
  t.u = q.z & 0xffff0000u; a = fmaf(w[5], t.f, a);
  t.u = q.w << 16;         a = fmaf(w[6], t.f, a);
  t.u = q.w & 0xffff0000u; a = fmaf(w[7], t.f, a);
  return a;
}

// ================= conv1: fused crop-gather + 3x3 s2 conv (tiled) =================
__global__ __launch_bounds__(TPB, 2) void conv1_tiled(
    const float* __restrict__ fmap, const float* __restrict__ iseq,
    const float* __restrict__ w, const float* __restrict__ bias,
    float* __restrict__ out) {
  __shared__ float xin[3][33][133];
  __shared__ float ws[3][16][12];
  __shared__ float bs[16];
  const int tid = threadIdx.x;
  const int blk = blockIdx.x;
  const int n = blk >> 2, R0 = (blk & 3) << 4;
  const int y = (int)iseq[n * 2 + 0];
  const int x = (int)iseq[n * 2 + 1];
  const int b = n >> 6;

  for (int s = tid; s < 3 * 16 * 12; s += TPB) {
    int t = s % 12; int oc = (s / 12) & 15; int ic = s / 192;
    ws[ic][oc][t] = (t < 9) ? w[(oc * 3 + ic) * 9 + t] : 0.f;
  }
  if (tid < 16) bs[tid] = bias[tid];
  for (int s = tid; s < 3 * 33 * 130; s += TPB) {
    int c = s % 130; int l = (s / 130) % 33; int ic = s / 4290;
    int i = 2 * R0 - 1 + l;
    int j = c - 1;
    float v = 0.f;
    if ((unsigned)i < 128u && (unsigned)j < 128u) {
      int r = y + i - 64, cc = x + j - 64;
      if ((unsigned)r < 1024u && (unsigned)cc < 1024u)
        v = fmap[(((size_t)b * 3 + ic) << 20) + ((size_t)r << 10) + cc];
    }
    xin[ic][l][c] = v;
  }
  __syncthreads();

  const int ocg = (tid >> 4) & 3;
  const int spg = (tid & 15) | ((tid >> 6) << 4);
  const int cg = spg & 7, rg = spg >> 3;
  float acc[4][16];
#pragma unroll
  for (int a = 0; a < 4; ++a)
#pragma unroll
    for (int s2 = 0; s2 < 16; ++s2) acc[a][s2] = 0.f;

  for (int ic = 0; ic < 3; ++ic) {
    float wv[4][9];
#pragma unroll
    for (int oi = 0; oi < 4; ++oi) {
      int oc = oi * 4 + ocg;
      float4 w0 = *(const float4*)&ws[ic][oc][0];
      float4 w1 = *(const float4*)&ws[ic][oc][4];
      float4 w2 = *(const float4*)&ws[ic][oc][8];
      wv[oi][0] = w0.x; wv[oi][1] = w0.y; wv[oi][2] = w0.z; wv[oi][3] = w0.w;
      wv[oi][4] = w1.x; wv[oi][5] = w1.y; wv[oi][6] = w1.z; wv[oi][7] = w1.w;
      wv[oi][8] = w2.x;
    }
#pragma unroll
    for (int r = 0; r < 2; ++r) {
#pragma unroll
      for (int ki = 0; ki < 3; ++ki) {
        int l = 4 * rg + 2 * r + ki;
        float xr[17];
#pragma unroll
        for (int t = 0; t < 17; ++t) xr[t] = xin[ic][l][16 * cg + t];
#pragma unroll
        for (int oi = 0; oi < 4; ++oi)
#pragma unroll
          for (int kj = 0; kj < 3; ++kj) {
            float wc = wv[oi][ki * 3 + kj];
#pragma unroll
            for (int q = 0; q < 8; ++q)
              acc[oi][r * 8 + q] = fmaf(wc, xr[2 * q + kj], acc[oi][r * 8 + q]);
          }
      }
    }
  }
#pragma unroll
  for (int oi = 0; oi < 4; ++oi) {
    int oc = oi * 4 + ocg;
    float bb = bs[oc];
#pragma unroll
    for (int r = 0; r < 2; ++r) {
      int orow = R0 + 2 * rg + r;
#pragma unroll
      for (int q = 0; q < 8; ++q)
        out[((n * 16 + oc) * 64 + orow) * 64 + 8 * cg + q] = acc[oi][r * 8 + q] + bb;
    }
  }
}

// ================= conv2: 16->32, 64->32 =================
__global__ __launch_bounds__(TPB, 2) void conv2_tiled(
    const float* __restrict__ in, const float* __restrict__ ss,
    const float* __restrict__ w, const float* __restrict__ bias,
    float* __restrict__ out) {
  __shared__ float xin[8][17][67];
  __shared__ float ws[16][32][12];
  __shared__ float bs[32];
  const int tid = threadIdx.x;
  const int blk = blockIdx.x;
  const int n = blk >> 2, R0 = (blk & 3) << 3;
  for (int s = tid; s < 16 * 32 * 12; s += TPB) {
    int t = s % 12; int oc = (s / 12) & 31; int ic = s / 384;
    ws[ic][oc][t] = (t < 9) ? w[(oc * 16 + ic) * 9 + t] : 0.f;
  }
  if (tid < 32) bs[tid] = bias[tid];

  const int ocg = (tid >> 3) & 7;
  const int cg = tid & 7;
  const int rg = tid >> 6;
  float acc[4][2][4];
#pragma unroll
  for (int a = 0; a < 4; ++a)
#pragma unroll
    for (int r = 0; r < 2; ++r)
#pragma unroll
      for (int q = 0; q < 4; ++q) acc[a][r][q] = 0.f;

  for (int ch = 0; ch < 2; ++ch) {
    __syncthreads();
    for (int s = tid; s < 8 * 17 * 16; s += TPB) {
      int g = s & 15; int l = (s >> 4) % 17; int ic = s / 272;
      int icg = ch * 8 + ic;
      int i = 2 * R0 - 1 + l;
      int j0 = g * 4;
      float4 v = make_float4(0.f, 0.f, 0.f, 0.f);
      if (i >= 0) v = *(const float4*)&in[((n * 16 + icg) << 12) + (i << 6) + j0];
      float sc = ss[2 * icg], sh = ss[2 * icg + 1];
      xin[ic][l][1 + j0]     = fmaxf(fmaf(v.x, sc, sh), 0.f);
      xin[ic][l][1 + j0 + 1] = fmaxf(fmaf(v.y, sc, sh), 0.f);
      xin[ic][l][1 + j0 + 2] = fmaxf(fmaf(v.z, sc, sh), 0.f);
      xin[ic][l][1 + j0 + 3] = fmaxf(fmaf(v.w, sc, sh), 0.f);
      if (g == 0) xin[ic][l][0] = 0.f;
      if (i < 0) {
        xin[ic][l][1+j0] = 0.f; xin[ic][l][2+j0] = 0.f; xin[ic][l][3+j0] = 0.f; xin[ic][l][4+j0] = 0.f;
      }
    }
    __syncthreads();
    for (int ic = 0; ic < 8; ++ic) {
      float wv[4][9];
#pragma unroll
      for (int oi = 0; oi < 4; ++oi) {
        int oc = oi * 8 + ocg;
        float4 w0 = *(const float4*)&ws[ch * 8 + ic][oc][0];
        float4 w1 = *(const float4*)&ws[ch * 8 + ic][oc][4];
        float4 w2 = *(const float4*)&ws[ch * 8 + ic][oc][8];
        wv[oi][0] = w0.x; wv[oi][1] = w0.y; wv[oi][2] = w0.z; wv[oi][3] = w0.w;
        wv[oi][4] = w1.x; wv[oi][5] = w1.y; wv[oi][6] = w1.z; wv[oi][7] = w1.w;
        wv[oi][8] = w2.x;
      }
#pragma unroll
      for (int r = 0; r < 2; ++r) {
#pragma unroll
        for (int ki = 0; ki < 3; ++ki) {
          int l = 4 * rg + 2 * r + ki;
          float xr[9];
#pragma unroll
          for (int t = 0; t < 9; ++t) xr[t] = xin[ic][l][8 * cg + t];
#pragma unroll
          for (int oi = 0; oi < 4; ++oi)
#pragma unroll
            for (int kj = 0; kj < 3; ++kj) {
              float wc = wv[oi][ki * 3 + kj];
#pragma unroll
              for (int q = 0; q < 4; ++q)
                acc[oi][r][q] = fmaf(wc, xr[2 * q + kj], acc[oi][r][q]);
            }
        }
      }
    }
  }
#pragma unroll
  for (int oi = 0; oi < 4; ++oi) {
    int oc = oi * 8 + ocg;
    float bb = bs[oc];
#pragma unroll
    for (int r = 0; r < 2; ++r) {
      int orow = R0 + 2 * rg + r;
#pragma unroll
      for (int q = 0; q < 4; ++q)
        out[((n * 32 + oc) * 32 + orow) * 32 + 4 * cg + q] = acc[oi][r][q] + bb;
    }
  }
}

// ================= conv3: 32->64, 32->16 =================
__global__ __launch_bounds__(TPB, 2) void conv3_tiled(
    const float* __restrict__ in, const float* __restrict__ ss,
    const float* __restrict__ w, const float* __restrict__ bias,
    float* __restrict__ out) {
  __shared__ float xin[8][33][35];
  __shared__ float ws[8][64][12];
  __shared__ float bs[64];
  const int tid = threadIdx.x;
  const int n = blockIdx.x;
  if (tid < 64) bs[tid] = bias[tid];

  const int ocg = (tid >> 3) & 7;
  const int cg = tid & 3;
  const int rg = ((tid >> 2) & 1) | ((tid >> 6) << 1);
  float acc[8][2][4];
#pragma unroll
  for (int a = 0; a < 8; ++a)
#pragma unroll
    for (int r = 0; r < 2; ++r)
#pragma unroll
      for (int q = 0; q < 4; ++q) acc[a][r][q] = 0.f;

  for (int ch = 0; ch < 4; ++ch) {
    __syncthreads();
    for (int s = tid; s < 8 * 64 * 12; s += TPB) {
      int t = s % 12; int oc = (s / 12) & 63; int ic = s / 768;
      ws[ic][oc][t] = (t < 9) ? w[(oc * 32 + ch * 8 + ic) * 9 + t] : 0.f;
    }
    for (int s = tid; s < 8 * 33 * 8; s += TPB) {
      int g = s & 7; int l = (s >> 3) % 33; int ic = s / 264;
      int icg = ch * 8 + ic;
      int i = l - 1;
      int j0 = g * 4;
      float4 v = make_float4(0.f, 0.f, 0.f, 0.f);
      if (i >= 0) v = *(const float4*)&in[((n * 32 + icg) << 10) + (i << 5) + j0];
      float sc = ss[2 * icg], sh = ss[2 * icg + 1];
      float o0 = fmaxf(fmaf(v.x, sc, sh), 0.f), o1 = fmaxf(fmaf(v.y, sc, sh), 0.f);
      float o2 = fmaxf(fmaf(v.z, sc, sh), 0.f), o3 = fmaxf(fmaf(v.w, sc, sh), 0.f);
      if (i < 0) { o0 = 0.f; o1 = 0.f; o2 = 0.f; o3 = 0.f; }
      xin[ic][l][1 + j0] = o0; xin[ic][l][2 + j0] = o1;
      xin[ic][l][3 + j0] = o2; xin[ic][l][4 + j0] = o3;
      if (g == 0) xin[ic][l][0] = 0.f;
    }
    __syncthreads();
    for (int ic = 0; ic < 8; ++ic) {
      float wv[8][9];
#pragma unroll
      for (int oi = 0; oi < 8; ++oi) {
        int oc = oi * 8 + ocg;
        float4 w0 = *(const float4*)&ws[ic][oc][0];
        float4 w1 = *(const float4*)&ws[ic][oc][4];
        float4 w2 = *(const float4*)&ws[ic][oc][8];
        wv[oi][0] = w0.x; wv[oi][1] = w0.y; wv[oi][2] = w0.z; wv[oi][3] = w0.w;
        wv[oi][4] = w1.x; wv[oi][5] = w1.y; wv[oi][6] = w1.z; wv[oi][7] = w1.w;
        wv[oi][8] = w2.x;
      }
#pragma unroll
      for (int r = 0; r < 2; ++r) {
#pragma unroll
        for (int ki = 0; ki < 3; ++ki) {
          int l = 4 * rg + 2 * r + ki;
          float xr[9];
#pragma unroll
          for (int t = 0; t < 9; ++t) xr[t] = xin[ic][l][8 * cg + t];
#pragma unroll
          for (int oi = 0; oi < 8; ++oi)
#pragma unroll
            for (int kj = 0; kj < 3; ++kj) {
              float wc = wv[oi][ki * 3 + kj];
#pragma unroll
              for (int q = 0; q < 4; ++q)
                acc[oi][r][q] = fmaf(wc, xr[2 * q + kj], acc[oi][r][q]);
            }
        }
      }
    }
  }
#pragma unroll
  for (int oi = 0; oi < 8; ++oi) {
    int oc = oi * 8 + ocg;
    float bb = bs[oc];
#pragma unroll
    for (int r = 0; r < 2; ++r) {
      int orow = 2 * rg + r;
#pragma unroll
      for (int q = 0; q < 4; ++q)
        out[((n * 64 + oc) << 8) + (orow << 4) + 4 * cg + q] = acc[oi][r][q] + bb;
    }
  }
}

// ================= conv4: 64->128, 16->8 =================
__global__ __launch_bounds__(TPB, 2) void conv4_tiled(
    const float* __restrict__ in, const float* __restrict__ ss,
    const float* __restrict__ w, const float* __restrict__ bias,
    float* __restrict__ out) {
  __shared__ float xin[8][17][19];
  __shared__ float ws[8][128][12];
  __shared__ float bs[128];
  const int tid = threadIdx.x;
  const int n = blockIdx.x;
  if (tid < 128) bs[tid] = bias[tid];

  const int ocg = (tid >> 2) & 15;
  const int cg = tid & 3;
  const int rg = tid >> 6;
  float acc[8][2][2];
#pragma unroll
  for (int a = 0; a < 8; ++a)
#pragma unroll
    for (int r = 0; r < 2; ++r)
#pragma unroll
      for (int q = 0; q < 2; ++q) acc[a][r][q] = 0.f;

  for (int ch = 0; ch < 8; ++ch) {
    __syncthreads();
    for (int s = tid; s < 8 * 128 * 12; s += TPB) {
      int t = s % 12; int oc = (s / 12) & 127; int ic = s / 1536;
      ws[ic][oc][t] = (t < 9) ? w[(oc * 64 + ch * 8 + ic) * 9 + t] : 0.f;
    }
    for (int s = tid; s < 8 * 17 * 4; s += TPB) {
      int g = s & 3; int l = (s >> 2) % 17; int ic = s / 68;
      int icg = ch * 8 + ic;
      int i = l - 1;
      int j0 = g * 4;
      float4 v = make_float4(0.f, 0.f, 0.f, 0.f);
      if (i >= 0) v = *(const float4*)&in[((n * 64 + icg) << 8) + (i << 4) + j0];
      float sc = ss[2 * icg], sh = ss[2 * icg + 1];
      float o0 = fmaxf(fmaf(v.x, sc, sh), 0.f), o1 = fmaxf(fmaf(v.y, sc, sh), 0.f);
      float o2 = fmaxf(fmaf(v.z, sc, sh), 0.f), o3 = fmaxf(fmaf(v.w, sc, sh), 0.f);
      if (i < 0) { o0 = 0.f; o1 = 0.f; o2 = 0.f; o3 = 0.f; }
      xin[ic][l][1 + j0] = o0; xin[ic][l][2 + j0] = o1;
      xin[ic][l][3 + j0] = o2; xin[ic][l][4 + j0] = o3;
      if (g == 0) xin[ic][l][0] = 0.f;
    }
    __syncthreads();
    for (int ic = 0; ic < 8; ++ic) {
      float wv[8][9];
#pragma unroll
      for (int oi = 0; oi < 8; ++oi) {
        int oc = oi * 16 + ocg;
        float4 w0 = *(const float4*)&ws[ic][oc][0];
        float4 w1 = *(const float4*)&ws[ic][oc][4];
        float4 w2 = *(const float4*)&ws[ic][oc][8];
        wv[oi][0] = w0.x; wv[oi][1] = w0.y; wv[oi][2] = w0.z; wv[oi][3] = w0.w;
        wv[oi][4] = w1.x; wv[oi][5] = w1.y; wv[oi][6] = w1.z; wv[oi][7] = w1.w;
        wv[oi][8] = w2.x;
      }
#pragma unroll
      for (int r = 0; r < 2; ++r) {
#pragma unroll
        for (int ki = 0; ki < 3; ++ki) {
          int l = 4 * rg + 2 * r + ki;
          float xr[5];
#pragma unroll
          for (int t = 0; t < 5; ++t) xr[t] = xin[ic][l][4 * cg + t];
#pragma unroll
          for (int oi = 0; oi < 8; ++oi)
#pragma unroll
            for (int kj = 0; kj < 3; ++kj) {
              float wc = wv[oi][ki * 3 + kj];
#pragma unroll
              for (int q = 0; q < 2; ++q)
                acc[oi][r][q] = fmaf(wc, xr[2 * q + kj], acc[oi][r][q]);
            }
        }
      }
    }
  }
#pragma unroll
  for (int oi = 0; oi < 8; ++oi) {
    int oc = oi * 16 + ocg;
    float bb = bs[oc];
#pragma unroll
    for (int r = 0; r < 2; ++r) {
      int orow = 2 * rg + r;
#pragma unroll
      for (int q = 0; q < 2; ++q)
        out[((n * 128 + oc) << 6) + (orow << 3) + 2 * cg + q] = acc[oi][r][q] + bb;
    }
  }
}

// ---------- BN statistics (deterministic two-stage) ----------
__global__ __launch_bounds__(TPB) void stats_partial_kernel(
    const float* __restrict__ y, float* __restrict__ part, int C, int HW) {
  int bid = blockIdx.x;
  int c = bid >> 6;
  int s = bid & 63;
  float sum = 0.f, sq = 0.f;
  for (int nn = 0; nn < 8; ++nn) {
    int n = s * 8 + nn;
    const float* p = y + (n * C + c) * HW;
    for (int i = threadIdx.x; i < HW; i += TPB) {
      float v = p[i];
      sum += v; sq = fmaf(v, v, sq);
    }
  }
  __shared__ float rs[TPB], rq[TPB];
  rs[threadIdx.x] = sum; rq[threadIdx.x] = sq;
  __syncthreads();
  for (int off = TPB / 2; off > 0; off >>= 1) {
    if (threadIdx.x < off) { rs[threadIdx.x] += rs[threadIdx.x + off]; rq[threadIdx.x] += rq[threadIdx.x + off]; }
    __syncthreads();
  }
  if (threadIdx.x == 0) { part[bid * 2] = rs[0]; part[bid * 2 + 1] = rq[0]; }
}

__global__ void stats_final_kernel(const float* __restrict__ part,
    const float* __restrict__ gamma, const float* __restrict__ beta,
    float* __restrict__ ss, float inv_count) {
  int c = blockIdx.x;
  int t = threadIdx.x;  // 64
  float sum = part[(c * 64 + t) * 2];
  float sq  = part[(c * 64 + t) * 2 + 1];
  for (int off = 32; off > 0; off >>= 1) {
    sum += __shfl_down(sum, off);
    sq  += __shfl_down(sq, off);
  }
  if (t == 0) {
    float mean = sum * inv_count;
    float var  = sq * inv_count - mean * mean;
    float rstd = rsqrtf(var + 1e-5f);
    float scl  = gamma[c] * rstd;
    ss[2 * c] = scl;
    ss[2 * c + 1] = beta[c] - mean * scl;
  }
}

// ---------- BN+ReLU for layer 4, writing bf16 for the MFMA FC ----------
__global__ __launch_bounds__(TPB) void bnrelu_bf16_kernel(const float* __restrict__ y,
    const float* __restrict__ ss, unsigned short* __restrict__ out) {
  int q = blockIdx.x * TPB + threadIdx.x;   // quad index, total 1048576
  if (q >= 1048576) return;
  int c = (q >> 4) & 127;
  float sc = ss[2 * c], sh = ss[2 * c + 1];
  float4 v = ((const float4*)y)[q];
  ushort4 o;
  o.x = f2bf(fmaxf(fmaf(v.x, sc, sh), 0.f));
  o.y = f2bf(fmaxf(fmaf(v.y, sc, sh), 0.f));
  o.z = f2bf(fmaxf(fmaf(v.z, sc, sh), 0.f));
  o.w = f2bf(fmaxf(fmaf(v.w, sc, sh), 0.f));
  ((ushort4*)out)[q] = o;
}

// ---------- fp32 -> bf16 cast (for fw1) ----------
__global__ __launch_bounds__(TPB) void cast_bf16_kernel(const float* __restrict__ in,
    unsigned short* __restrict__ out, int nquad) {
  int q = blockIdx.x * TPB + threadIdx.x;
  if (q >= nquad) return;
  float4 v = ((const float4*)in)[q];
  ushort4 o;
  o.x = f2bf(v.x); o.y = f2bf(v.y); o.z = f2bf(v.z); o.w = f2bf(v.w);
  ((ushort4*)out)[q] = o;
}

// ---------- fc1: bf16 MFMA GEMM, M=N=512, K=8192, relu epilogue ----------
__global__ __launch_bounds__(TPB, 2) void fc1_mfma(
    const unsigned short* __restrict__ A, const unsigned short* __restrict__ W,
    const float* __restrict__ bias, float* __restrict__ out) {
  __shared__ unsigned short As[64][64];
  __shared__ unsigned short Bs[64][64];
  const int tid = threadIdx.x;
  const int lane = tid & 63, wave = tid >> 6;
  const int wr = (wave >> 1) * 32, wc = (wave & 1) * 32;
  const int bm = blockIdx.y * 64, bn = blockIdx.x * 64;
  f32x4 acc00 = {0.f, 0.f, 0.f, 0.f}, acc01 = acc00, acc10 = acc00, acc11 = acc00;
  const int r0 = tid >> 3, c0 = tid & 7;
  const int fr = lane & 15, kg = lane >> 4;
  for (int kt = 0; kt < 128; ++kt) {
    const int kb = kt * 64;
    uint4 av0 = *(const uint4*)&A[(size_t)(bm + r0) * 8192 + kb + c0 * 8];
    uint4 av1 = *(const uint4*)&A[(size_t)(bm + r0 + 32) * 8192 + kb + c0 * 8];
    uint4 bv0 = *(const uint4*)&W[(size_t)(bn + r0) * 8192 + kb + c0 * 8];
    uint4 bv1 = *(const uint4*)&W[(size_t)(bn + r0 + 32) * 8192 + kb + c0 * 8];
    __syncthreads();
    *(uint4*)&As[r0][(c0 ^ (r0 & 7)) * 8] = av0;
    *(uint4*)&As[r0 + 32][(c0 ^ (r0 & 7)) * 8] = av1;
    *(uint4*)&Bs[r0][(c0 ^ (r0 & 7)) * 8] = bv0;
    *(uint4*)&Bs[r0 + 32][(c0 ^ (r0 & 7)) * 8] = bv1;
    __syncthreads();
#pragma unroll
    for (int ks = 0; ks < 2; ++ks) {
      int ch = ks * 4 + kg;
      int ra0 = wr + fr, ra1 = wr + 16 + fr;
      int rb0 = wc + fr, rb1 = wc + 16 + fr;
      bf16x8 a_0 = lda_bf8(&As[ra0][(ch ^ (ra0 & 7)) * 8]);
      bf16x8 a_1 = lda_bf8(&As[ra1][(ch ^ (ra1 & 7)) * 8]);
      bf16x8 b_0 = lda_bf8(&Bs[rb0][(ch ^ (rb0 & 7)) * 8]);
      bf16x8 b_1 = lda_bf8(&Bs[rb1][(ch ^ (rb1 & 7)) * 8]);
      acc00 = __builtin_amdgcn_mfma_f32_16x16x32_bf16(a_0, b_0, acc00, 0, 0, 0);
      acc01 = __builtin_amdgcn_mfma_f32_16x16x32_bf16(a_0, b_1, acc01, 0, 0, 0);
      acc10 = __builtin_amdgcn_mfma_f32_16x16x32_bf16(a_1, b_0, acc10, 0, 0, 0);
      acc11 = __builtin_amdgcn_mfma_f32_16x16x32_bf16(a_1, b_1, acc11, 0, 0, 0);
    }
  }
  const int rg = lane >> 4;
  int n0 = bn + wc + fr, n1 = n0 + 16;
  float bi0 = bias[n0], bi1 = bias[n1];
#pragma unroll
  for (int r = 0; r < 4; ++r) {
    int m0 = bm + wr + rg * 4 + r, m1 = m0 + 16;
    out[m0 * 512 + n0] = fmaxf(acc00[r] + bi0, 0.f);
    out[m0 * 512 + n1] = fmaxf(acc01[r] + bi1, 0.f);
    out[m1 * 512 + n0] = fmaxf(acc10[r] + bi0, 0.f);
    out[m1 * 512 + n1] = fmaxf(acc11[r] + bi1, 0.f);
  }
}

// ---------- generic tiled GEMM (fp32, small layers) ----------
__global__ __launch_bounds__(TPB) void gemm_rt(const float* __restrict__ A,
    const float* __restrict__ W, const float* __restrict__ bias,
    float* __restrict__ out, int M, int N, int K, int dorelu) {
  __shared__ float As[32][33];
  __shared__ float Ws[32][33];
  int tid = threadIdx.x;
  int tx = tid & 15, ty = tid >> 4;
  int bm = blockIdx.y << 5, bn = blockIdx.x << 5;
  float a00 = 0.f, a01 = 0.f, a10 = 0.f, a11 = 0.f;
  int nk = (K + 31) >> 5;
  for (int kt = 0; kt < nk; ++kt) {
    int k0 = kt << 5;
#pragma unroll
    for (int l = 0; l < 4; ++l) {
      int idx = tid + (l << 8);
      int r = idx >> 5, c = idx & 31;
      int gc = k0 + c;
      int ga = bm + r;
      As[c][r] = (ga < M && gc < K) ? A[ga * K + gc] : 0.f;
      int gw = bn + r;
      Ws[c][r] = (gw < N && gc < K) ? W[gw * K + gc] : 0.f;
    }
    __syncthreads();
#pragma unroll
    for (int k = 0; k < 32; ++k) {
      float x0 = As[k][ty], x1 = As[k][ty + 16];
      float y0 = Ws[k][tx], y1 = Ws[k][tx + 16];
      a00 = fmaf(x0, y0, a00); a01 = fmaf(x0, y1, a01);
      a10 = fmaf(x1, y0, a10); a11 = fmaf(x1, y1, a11);
    }
    __syncthreads();
  }
  int m0 = bm + ty, m1 = m0 + 16, n0 = bn + tx, n1 = n0 + 16;
  if (m0 < M && n0 < N) { float v = a00 + bias[n0]; out[m0 * N + n0] = dorelu ? fmaxf(v, 0.f) : v; }
  if (m0 < M && n1 < N) { float v = a01 + bias[n1]; out[m0 * N + n1] = dorelu ? fmaxf(v, 0.f) : v; }
  if (m1 < M && n0 < N) { float v = a10 + bias[n0]; out[m1 * N + n0] = dorelu ? fmaxf(v, 0.f) : v; }
  if (m1 < M && n1 < N) { float v = a11 + bias[n1]; out[m1 * N + n1] = dorelu ? fmaxf(v, 0.f) : v; }
}

// ---------- small builders ----------
__global__ __launch_bounds__(TPB) void build_enh_kernel(const float* __restrict__ cond,
    const float* __restrict__ steps, float* __restrict__ enh) {
  int i = blockIdx.x * TPB + threadIdx.x;
  if (i >= 512 * 6) return;
  int n = i / 6, k = i % 6;
  int b = n >> 6, s = n & 63;
  enh[i] = (k < 5) ? cond[b * 5 + k] : steps[b * 64 + s];
}

// fills comb columns 256..575 (mapf, condf); columns 0..255 are written by lstm
__global__ __launch_bounds__(TPB) void build_comb2_kernel(const float* __restrict__ mapf,
    const float* __restrict__ condf, float* __restrict__ comb) {
  int i = blockIdx.x * TPB + threadIdx.x;
  if (i >= 512 * 320) return;
  int n = i / 320, k = i % 320;
  float v = (k < 256) ? mapf[n * 256 + k] : condf[n * 64 + (k - 256)];
  comb[n * 576 + 256 + k] = v;
}

// ---------- LSTM: 64 blocks, register-resident weights, data-tagged exchange ----------
// Cross-block h exchange: one 64-bit relaxed agent atomic per 2 bf16 values,
// tag (= phase stamp) packed in the high dword -> sync and data fused, no barrier.
__global__ __launch_bounds__(TPB, 1) void lstm_kernel(
    const float* __restrict__ iseq,
    const float* __restrict__ mw, const float* __restrict__ mb,
    const float* __restrict__ w_ih0, const float* __restrict__ w_hh0,
    const float* __restrict__ b_ih0, const float* __restrict__ b_hh0,
    const float* __restrict__ w_ih1, const float* __restrict__ w_hh1,
    const float* __restrict__ b_ih1, const float* __restrict__ b_hh1,
    unsigned long long* __restrict__ h0x,   // [64][1024] (tag | 2xbf16)
    unsigned long long* __restrict__ h1x,   // [64][1024]
    float* __restrict__ comb) {             // [512][576]; cols 0..255 = lstm h1
  const int tid = threadIdx.x;
  const int blkid = blockIdx.x;
  const int u0 = blkid * 4;

  __shared__ float xz[64][8][16];                 // 32KB persistent: x-part of layer0 gates (+bias0)
  __shared__ __align__(16) char reg2[26112];      // overlay region
  __shared__ float bias1s[16];

  // prologue overlays
  float (*embc)[8][32] = (float (*)[8][32])reg2;            // [16][8][32] fp32 (16KB)
  float* mwmb = (float*)(reg2 + 16384);                     // 96 floats
  // main-loop overlays
  unsigned short (*v0s)[256] = (unsigned short (*)[256])reg2;            // h0(p-1) bf16, 4KB
  unsigned short (*w1h)[256] = (unsigned short (*)[256])(reg2 + 4096);   // h1(p-2) bf16, 4KB
  float (*part0)[8][16] = (float (*)[8][16])(reg2 + 8192);               // [ks][b][r] 8KB
  float (*part1)[8][16] = (float (*)[8][16])(reg2 + 16384);              // 8KB
  float (*zg0)[16] = (float (*)[16])(reg2 + 24576);                      // [b][r] 512B
  float (*zg1)[16] = (float (*)[16])(reg2 + 25088);                      // 512B

  const int r = tid & 15, ks = tid >> 4;
  const int R = (r >> 2) * 256 + u0 + (r & 3);

  // --- weights to registers ---
  float w0reg[16], w1reg[32], wtmp[32];
#pragma unroll
  for (int i = 0; i < 16; ++i) w0reg[i] = w_hh0[R * 256 + ks * 16 + i];
  if (ks < 8) {
#pragma unroll
    for (int i = 0; i < 32; ++i) w1reg[i] = w_ih1[R * 256 + ks * 32 + i];
  } else {
#pragma unroll
    for (int i = 0; i < 32; ++i) w1reg[i] = w_hh1[R * 256 + (ks - 8) * 32 + i];
  }
#pragma unroll
  for (int i = 0; i < 32; ++i) wtmp[i] = w_ih0[R * 32 + i];
  const float bias0r = b_ih0[R] + b_hh0[R];
  if (tid < 16) bias1s[tid] = b_ih1[R] + b_hh1[R];
  if (tid < 96) mwmb[tid] = (tid < 64) ? mw[tid] : mb[tid - 64];
  __syncthreads();

  // --- prologue: emb (inlined coord embedder) + x-part of layer0 gates, 4 chunks ---
  for (int chunk = 0; chunk < 4; ++chunk) {
    if (tid < 128) {
      int pp = tid >> 3, b = tid & 7;
      int pg = chunk * 16 + pp;
      float s0 = iseq[(b * 64 + pg) * 2 + 0];
      float s1 = iseq[(b * 64 + pg) * 2 + 1];
      for (int k = 0; k < 32; ++k)
        embc[pp][b][k] = fmaxf(fmaf(mwmb[2 * k], s0, fmaf(mwmb[2 * k + 1], s1, mwmb[64 + k])), 0.f);
    }
    __syncthreads();
    {
      int pg = chunk * 16 + ks;
      for (int b = 0; b < 8; ++b) {
        float a = bias0r;
        const float* e = &embc[ks][b][0];
#pragma unroll
        for (int k = 0; k < 32; ++k) a = fmaf(wtmp[k], e[k], a);
        xz[pg][b][r] = a;
      }
    }
    __syncthreads();
  }

  // --- main loop: phase p = layer0 step p (p<64) + layer1 step p-1 (p>=1) ---
  float c0 = 0.f, c1 = 0.f;
  for (int p = 0; p <= 64; ++p) {
    // ---- A: poll + stage exchange ----
    if (p >= 1) {
      const unsigned tag0 = (unsigned)p, tag1 = (unsigned)(p - 1);
      const unsigned long long* s0p = &h0x[(size_t)(p - 1) * 1024 + tid * 4];
      const unsigned long long* s1p = (p >= 2) ? &h1x[(size_t)(p - 2) * 1024 + tid * 4] : nullptr;
      unsigned long long a0, a1, a2, a3, e0 = 0, e1 = 0, e2 = 0, e3 = 0;
      for (;;) {
        a0 = __hip_atomic_load(&s0p[0], __ATOMIC_RELAXED, __HIP_MEMORY_SCOPE_AGENT);
        a1 = __hip_atomic_load(&s0p[1], __ATOMIC_RELAXED, __HIP_MEMORY_SCOPE_AGENT);
        a2 = __hip_atomic_load(&s0p[2], __ATOMIC_RELAXED, __HIP_MEMORY_SCOPE_AGENT);
        a3 = __hip_atomic_load(&s0p[3], __ATOMIC_RELAXED, __HIP_MEMORY_SCOPE_AGENT);
        bool ok = ((unsigned)(a0 >> 32) == tag0) & ((unsigned)(a1 >> 32) == tag0) &
                  ((unsigned)(a2 >> 32) == tag0) & ((unsigned)(a3 >> 32) == tag0);
        if (p >= 2) {
          e0 = __hip_atomic_load(&s1p[0], __ATOMIC_RELAXED, __HIP_MEMORY_SCOPE_AGENT);
          e1 = __hip_atomic_load(&s1p[1], __ATOMIC_RELAXED, __HIP_MEMORY_SCOPE_AGENT);
          e2 = __hip_atomic_load(&s1p[2], __ATOMIC_RELAXED, __HIP_MEMORY_SCOPE_AGENT);
          e3 = __hip_atomic_load(&s1p[3], __ATOMIC_RELAXED, __HIP_MEMORY_SCOPE_AGENT);
          ok &= ((unsigned)(e0 >> 32) == tag1) & ((unsigned)(e1 >> 32) == tag1) &
                ((unsigned)(e2 >> 32) == tag1) & ((unsigned)(e3 >> 32) == tag1);
        }
        if (ok) break;
        __builtin_amdgcn_s_sleep(2);
      }
#pragma unroll
      for (int i = 0; i < 4; ++i) {
        int g = tid * 4 + i;
        int bb = (g & 15) >> 1, ub = (g >> 4) * 4 + (g & 1) * 2;
        unsigned long long va = (i == 0) ? a0 : (i == 1) ? a1 : (i == 2) ? a2 : a3;
        *(unsigned int*)&v0s[bb][ub] = (unsigned int)va;
        if (p >= 2) {
          unsigned long long ve = (i == 0) ? e0 : (i == 1) ? e1 : (i == 2) ? e2 : e3;
          *(unsigned int*)&w1h[bb][ub] = (unsigned int)ve;
        }
      }
    }
    if (p < 1) {
#pragma unroll
      for (int i = 0; i < 4; ++i) ((unsigned int*)v0s)[tid * 4 + i] = 0u;
    }
    if (p < 2) {
#pragma unroll
      for (int i = 0; i < 4; ++i) ((unsigned int*)w1h)[tid * 4 + i] = 0u;
    }
    __syncthreads();

    // ---- B: K-sliced partial dot products (weights in registers) ----
    if (p < 64) {
#pragma unroll
      for (int b = 0; b < 8; ++b) {
        uint4 q0 = *(const uint4*)&v0s[b][ks * 16];
        uint4 q1 = *(const uint4*)&v0s[b][ks * 16 + 8];
        float a = 0.f;
        a = fma8(q0, &w0reg[0], a);
        a = fma8(q1, &w0reg[8], a);
        part0[ks][b][r] = a;
      }
    }
    if (p >= 1) {
      const unsigned short* sp = (ks < 8) ? &v0s[0][ks * 32] : &w1h[0][(ks - 8) * 32];
#pragma unroll
      for (int b = 0; b < 8; ++b) {
        const uint4* qp = (const uint4*)(sp + b * 256);
        float a = 0.f;
        a = fma8(qp[0], &w1reg[0], a);
        a = fma8(qp[1], &w1reg[8], a);
        a = fma8(qp[2], &w1reg[16], a);
        a = fma8(qp[3], &w1reg[24], a);
        part1[ks][b][r] = a;
      }
    }
    __syncthreads();

    // ---- C: reduce partials -> gate pre-activations ----
    if (tid < 128) {
      int b = tid >> 4, rr = tid & 15;
      if (p < 64) {
        float s = xz[p][b][rr];
#pragma unroll
        for (int k2 = 0; k2 < 16; ++k2) s += part0[k2][b][rr];
        zg0[b][rr] = s;
      }
    } else {
      int t2 = tid - 128, b = t2 >> 4, rr = t2 & 15;
      if (p >= 1) {
        float s = bias1s[rr];
#pragma unroll
        for (int k2 = 0; k2 < 16; ++k2) s += part1[k2][b][rr];
        zg1[b][rr] = s;
      }
    }
    __syncthreads();

    // ---- D: state update + tagged publish ----
    if (tid < 32) {
      if (p < 64) {
        int b = tid >> 2, uu = tid & 3;
        float zi = zg0[b][uu], zf = zg0[b][4 + uu], zgv = zg0[b][8 + uu], zo = zg0[b][12 + uu];
        c0 = sigf(zf) * c0 + sigf(zi) * tanhf(zgv);
        float h = sigf(zo) * tanhf(c0);
        float hp = __shfl_xor(h, 1);
        if (!(uu & 1)) {
          unsigned int d = (unsigned int)f2bf(h) | ((unsigned int)f2bf(hp) << 16);
          unsigned long long v = ((unsigned long long)(unsigned)(p + 1) << 32) | d;
          __hip_atomic_store(&h0x[(size_t)p * 1024 + blkid * 16 + b * 2 + (uu >> 1)], v,
                             __ATOMIC_RELAXED, __HIP_MEMORY_SCOPE_AGENT);
        }
      }
    } else if (tid < 64) {
      if (p >= 1) {
        int t2 = tid - 32, b = t2 >> 2, uu = t2 & 3;
        float zi = zg1[b][uu], zf = zg1[b][4 + uu], zgv = zg1[b][8 + uu], zo = zg1[b][12 + uu];
        c1 = sigf(zf) * c1 + sigf(zi) * tanhf(zgv);
        float h = sigf(zo) * tanhf(c1);
        comb[(size_t)(b * 64 + (p - 1)) * 576 + u0 + uu] = h;   // fp32 h1 -> head input
        float hp = __shfl_xor(h, 1);
        if (!(uu & 1)) {
          unsigned int d = (unsigned int)f2bf(h) | ((unsigned int)f2bf(hp) << 16);
          unsigned long long v = ((unsigned long long)(unsigned)p << 32) | d;
          __hip_atomic_store(&h1x[(size_t)(p - 1) * 1024 + blkid * 16 + b * 2 + (uu >> 1)], v,
                             __ATOMIC_RELAXED, __HIP_MEMORY_SCOPE_AGENT);
        }
      }
    }
    // no trailing sync needed: next phase's poll orders everything
  }
}

// ---------- launcher ----------
extern "C" void kernel_launch(void* const* d_in, const int* in_sizes, int n_in,
                              void* d_out, int out_size, void* d_ws, size_t ws_size,
                              hipStream_t stream) {
  const float* fmap  = (const float*)d_in[0];
  const float* cond  = (const float*)d_in[1];
  const float* iseq  = (const float*)d_in[2];
  const float* steps = (const float*)d_in[3];
  const float* cw1 = (const float*)d_in[4];  const float* cb1 = (const float*)d_in[5];
  const float* g1  = (const float*)d_in[6];  const float* be1 = (const float*)d_in[7];
  const float* cw2 = (const float*)d_in[8];  const float* cb2 = (const float*)d_in[9];
  const float* g2  = (const float*)d_in[10]; const float* be2 = (const float*)d_in[11];
  const float* cw3 = (const float*)d_in[12]; const float* cb3 = (const float*)d_in[13];
  const float* g3  = (const float*)d_in[14]; const float* be3 = (const float*)d_in[15];
  const float* cw4 = (const float*)d_in[16]; const float* cb4 = (const float*)d_in[17];
  const float* g4  = (const float*)d_in[18]; const float* be4 = (const float*)d_in[19];
  const float* fw1 = (const float*)d_in[20]; const float* fb1 = (const float*)d_in[21];
  const float* fw2 = (const float*)d_in[22]; const float* fb2 = (const float*)d_in[23];
  const float* ew1 = (const float*)d_in[24]; const float* eb1 = (const float*)d_in[25];
  const float* ew2 = (const float*)d_in[26]; const float* eb2 = (const float*)d_in[27];
  const float* mw  = (const float*)d_in[28]; const float* mb  = (const float*)d_in[29];
  const float* w_ih0 = (const float*)d_in[30]; const float* w_hh0 = (const float*)d_in[31];
  const float* b_ih0 = (const float*)d_in[32]; const float* b_hh0 = (const float*)d_in[33];
  const float* w_ih1 = (const float*)d_in[34]; const float* w_hh1 = (const float*)d_in[35];
  const float* b_ih1 = (const float*)d_in[36]; const float* b_hh1 = (const float*)d_in[37];
  const float* xw1 = (const float*)d_in[38]; const float* xb1 = (const float*)d_in[39];
  const float* xw2 = (const float*)d_in[40]; const float* xb2 = (const float*)d_in[41];
  const float* ow  = (const float*)d_in[42]; const float* ob  = (const float*)d_in[43];

  float* ws = (float*)d_ws;
  float* y1 = ws;                    // 33,554,432 f (dead after conv2)
  float* y2 = ws + 33554432;         // 16,777,216 f (dead after conv3)
  float* y3 = ws;                    // overlays y1 (dead after conv4)
  float* y4 = ws + 33554432;         // overlays y2
  unsigned short* y4bf  = (unsigned short*)ws;              // after conv4
  unsigned short* fw1bf = (unsigned short*)(ws + 8388608);  // after conv2
  size_t base = 50331648;
  float* part  = ws + base; base += 16384;
  float* ss1   = ws + base; base += 32;
  float* ss2   = ws + base; base += 64;
  float* ss3   = ws + base; base += 128;
  float* ss4   = ws + base; base += 256;
  float* f1    = ws + base; base += 262144;
  float* mapf  = ws + base; base += 131072;
  float* enh   = ws + base; base += 3072;
  float* ceh   = ws + base; base += 65536;
  float* condf = ws + base; base += 32768;
  unsigned long long* h0x = (unsigned long long*)(ws + base); base += 131072; // 64*1024 u64
  unsigned long long* h1x = (unsigned long long*)(ws + base); base += 131072;
  float* comb  = ws + base; base += 294912;
  float* cx1   = ws + base; base += 65536;
  float* cx2   = ws + base; base += 32768;

  // --- encoder convs (LDS-tiled) with batch-stat BN folded to scale/shift ---
  conv1_tiled<<<2048, TPB, 0, stream>>>(fmap, iseq, cw1, cb1, y1);
  stats_partial_kernel<<<16 * 64, TPB, 0, stream>>>(y1, part, 16, 4096);
  stats_final_kernel<<<16, 64, 0, stream>>>(part, g1, be1, ss1, 1.f / 2097152.f);
  conv2_tiled<<<2048, TPB, 0, stream>>>(y1, ss1, cw2, cb2, y2);
  cast_bf16_kernel<<<4096, TPB, 0, stream>>>(fw1, fw1bf, 1048576);   // y1 region now free
  stats_partial_kernel<<<32 * 64, TPB, 0, stream>>>(y2, part, 32, 1024);
  stats_final_kernel<<<32, 64, 0, stream>>>(part, g2, be2, ss2, 1.f / 524288.f);
  conv3_tiled<<<512, TPB, 0, stream>>>(y2, ss2, cw3, cb3, y3);
  stats_partial_kernel<<<64 * 64, TPB, 0, stream>>>(y3, part, 64, 256);
  stats_final_kernel<<<64, 64, 0, stream>>>(part, g3, be3, ss3, 1.f / 131072.f);
  conv4_tiled<<<512, TPB, 0, stream>>>(y3, ss3, cw4, cb4, y4);
  stats_partial_kernel<<<128 * 64, TPB, 0, stream>>>(y4, part, 128, 64);
  stats_final_kernel<<<128, 64, 0, stream>>>(part, g4, be4, ss4, 1.f / 32768.f);
  bnrelu_bf16_kernel<<<4096, TPB, 0, stream>>>(y4, ss4, y4bf);       // y3 region now free

  // --- LSTM (tag-fused exchange); clears exchange tags first ---
  hipMemsetAsync(h0x, 0, 2 * 64 * 1024 * sizeof(unsigned long long), stream);
  lstm_kernel<<<NLB, TPB, 0, stream>>>(iseq, mw, mb,
                                       w_ih0, w_hh0, b_ih0, b_hh0,
                                       w_ih1, w_hh1, b_ih1, b_hh1,
                                       h0x, h1x, comb);

  // --- map-feature MLP (fc1 via bf16 MFMA) ---
  fc1_mfma<<<dim3(8, 8), TPB, 0, stream>>>(y4bf, fw1bf, fb1, f1);
  gemm_rt<<<dim3(8, 16),  TPB, 0, stream>>>(f1, fw2, fb2, mapf, 512, 256, 512, 0);

  // --- condition encoder ---
  build_enh_kernel<<<12, TPB, 0, stream>>>(cond, steps, enh);
  gemm_rt<<<dim3(4, 16), TPB, 0, stream>>>(enh, ew1, eb1, ceh, 512, 128, 6, 1);
  gemm_rt<<<dim3(2, 16), TPB, 0, stream>>>(ceh, ew2, eb2, condf, 512, 64, 128, 0);

  // --- head ---
  build_comb2_kernel<<<640, TPB, 0, stream>>>(mapf, condf, comb);
  gemm_rt<<<dim3(4, 16), TPB, 0, stream>>>(comb, xw1, xb1, cx1, 512, 128, 576, 1);
  gemm_rt<<<dim3(2, 16), TPB, 0, stream>>>(cx1, xw2, xb2, cx2, 512, 64, 128, 1);
  gemm_rt<<<dim3(1, 16), TPB, 0, stream>>>(cx2, ow, ob, (float*)d_out, 512, 2, 64, 0);
}

// Round 5
// 950.120 us; speedup vs baseline: 7.7455x; 1.2620x over previous
//
#include <hip/hip_runtime.h>

#define TPB 256
#define NLB 64   // LSTM blocks

typedef float f32x4 __attribute__((ext_vector_type(4)));
typedef short bf16x8 __attribute__((ext_vector_type(8)));

// ---------- helpers ----------
__device__ __forceinline__ float bf2f(unsigned short u) {
  union { unsigned int i; float f; } x; x.i = ((unsigned int)u) << 16; return x.f;
}
__device__ __forceinline__ unsigned short f2bf(float v) {
  union { float f; unsigned int i; } x; x.f = v;
  unsigned int r = (x.i + 0x7fffu + ((x.i >> 16) & 1u)) >> 16;
  return (unsigned short)r;
}
__device__ __forceinline__ float sigf(float x) { return 1.f / (1.f + __expf(-x)); }
__device__ __forceinline__ bf16x8 lda_bf8(const unsigned short* p) {
  union { uint4 u; bf16x8 v; } t; t.u = *(const uint4*)p; return t.v;
}
// 8 bf16 (packed in uint4) * 8 fp32 weights -> acc
__device__ __forceinline__ float fma8(uint4 q, const float* w, float a) {
  union { unsigned int u; float f; } t;
  t.u = q.x << 16;         a = fmaf(w[0], t.f, a);
  t.u = q.x & 0xffff0000u; a = fmaf(w[1], t.f, a);
  t.u = q.y << 16;         a = fmaf(w[2], t.f, a);
  t.u = q.y & 0xffff0000u; a = fmaf(w[3], t.f, a);
  t.u = q.z << 16;         a = fmaf(w[4], t.f, a);
  t.u = q.z & 0xffff0000u; a = fmaf(w[5], t.f, a);
  t.u = q.w << 16;         a = fmaf(w[6], t.f, a);
  t.u = q.w & 0xffff0000u; a = fmaf(w[7], t.f, a);
  return a;
}

// ================= unified conv: 3x3 s2 conv as MFMA implicit GEMM =================
// Each block: 64 output positions (one image) x all COUT. K = CIN*9 in 32-chunks.
// im2col tile built in LDS per chunk (BN+ReLU on input for !CROP; crop gather for CROP).
// Output bf16 (pre-BN of this layer). Bias added in epilogue.
template<int CIN, int COUT, int HIN, int HOUT, bool CROP>
__global__ __launch_bounds__(TPB, 4) void conv_mfma(
    const unsigned short* __restrict__ inb,   // bf16 prev activation (null if CROP)
    const float* __restrict__ fmap,           // fp32 full map (CROP only)
    const float* __restrict__ iseq,           // crop coords (CROP only)
    const float* __restrict__ ss,             // BN scale/shift of prev layer (!CROP)
    const float* __restrict__ w,              // [COUT][K] fp32
    const float* __restrict__ bias,
    unsigned short* __restrict__ out) {       // bf16 [n][COUT][HOUT][HOUT]
  constexpr int K = CIN * 9;
  constexpr int NCH = (K + 31) / 32;
  constexpr int NT = COUT / 16;               // N tiles (per wave M-tile = wave)
  constexpr int RGR = (HOUT * HOUT) / 64;     // row-groups per image
  constexpr int RPB = 64 / HOUT;              // out rows per block

  __shared__ unsigned short Asm[64][40];
  __shared__ unsigned short Bsm[COUT][40];
  __shared__ float ssl[CIN * 2];
  __shared__ unsigned int lut[NCH * 32];

  const int tid = threadIdx.x;
  const int wave = tid >> 6, lane = tid & 63;
  const int fr = lane & 15, kg = lane >> 4;
  const int n = blockIdx.x / RGR;
  const int row0 = (blockIdx.x % RGR) * RPB;

  for (int k = tid; k < NCH * 32; k += TPB)
    lut[k] = (k < K) ? (((unsigned)(k / 9) << 8) | ((unsigned)((k % 9) / 3) << 4) | (unsigned)(k % 3))
                     : 0xFFFFFFFFu;
  if (!CROP) {
    for (int i = tid; i < CIN * 2; i += TPB) ssl[i] = ss[i];
  }
  int cy = 0, cx = 0;
  if (CROP) { cy = (int)iseq[n * 2]; cx = (int)iseq[n * 2 + 1]; }

  f32x4 acc[NT];
#pragma unroll
  for (int j = 0; j < NT; ++j) acc[j] = {0.f, 0.f, 0.f, 0.f};

  for (int ch = 0; ch < NCH; ++ch) {
    const int kb = ch * 32;
    __syncthreads();
    // ---- build A (im2col 64x32, k-major across waves, p per lane) ----
#pragma unroll
    for (int jj = 0; jj < 8; ++jj) {
      int e = jj * 256 + tid;
      int k = e >> 6, p = e & 63;
      unsigned info = lut[kb + k];
      int oi = row0 + p / HOUT;
      int oj = p % HOUT;
      float v = 0.f;
      if (info != 0xFFFFFFFFu) {
        int ic = info >> 8, ki = (info >> 4) & 15, kj = info & 15;
        int ir = 2 * oi - 1 + ki;
        int jc = 2 * oj - 1 + kj;
        if (CROP) {
          if ((unsigned)ir < (unsigned)HIN && (unsigned)jc < (unsigned)HIN) {
            int mr = cy + ir - 64, mc = cx + jc - 64;
            if ((unsigned)mr < 1024u && (unsigned)mc < 1024u)
              v = fmap[(((size_t)(n >> 6) * 3 + ic) << 20) + ((size_t)mr << 10) + mc];
          }
        } else {
          if ((unsigned)ir < (unsigned)HIN && (unsigned)jc < (unsigned)HIN) {
            float x = bf2f(inb[((size_t)(n * CIN + ic) * HIN + ir) * HIN + jc]);
            v = fmaxf(fmaf(x, ssl[2 * ic], ssl[2 * ic + 1]), 0.f);
          }
        }
      }
      Asm[p][k] = f2bf(v);
    }
    // ---- stage B (weights, naturally k-contiguous) ----
#pragma unroll
    for (int jj = 0; jj < COUT / 8; ++jj) {
      int e = jj * 256 + tid;
      int oc = e >> 5, t = e & 31;
      int kk = kb + t;
      float v = (kk < K) ? w[(size_t)oc * K + kk] : 0.f;
      Bsm[oc][t] = f2bf(v);
    }
    __syncthreads();
    // ---- MFMA: wave's M-tile = wave ----
    bf16x8 af = lda_bf8(&Asm[wave * 16 + fr][kg * 8]);
#pragma unroll
    for (int j = 0; j < NT; ++j) {
      bf16x8 bf = lda_bf8(&Bsm[j * 16 + fr][kg * 8]);
      acc[j] = __builtin_amdgcn_mfma_f32_16x16x32_bf16(af, bf, acc[j], 0, 0, 0);
    }
  }
  // ---- epilogue: C row = P (A-row), col = oc (B-row) ----
  const int rg = lane >> 4;
#pragma unroll
  for (int j = 0; j < NT; ++j) {
    int oc = j * 16 + fr;
    float bb = bias[oc];
#pragma unroll
    for (int r = 0; r < 4; ++r) {
      int p = wave * 16 + rg * 4 + r;
      int oi = row0 + p / HOUT, oj = p % HOUT;
      out[((size_t)(n * COUT + oc) * HOUT + oi) * HOUT + oj] = f2bf(acc[j][r] + bb);
    }
  }
}

// ---------- BN statistics over bf16 y (deterministic two-stage) ----------
__global__ __launch_bounds__(TPB) void stats_partial_bf16(
    const unsigned short* __restrict__ y, float* __restrict__ part, int C, int HW) {
  int bid = blockIdx.x;
  int c = bid >> 6;
  int s = bid & 63;
  float sum = 0.f, sq = 0.f;
  for (int nn = 0; nn < 8; ++nn) {
    const unsigned short* p = y + ((size_t)(s * 8 + nn) * C + c) * HW;
    for (int i = threadIdx.x * 8; i < HW; i += TPB * 8) {
      uint4 q = *(const uint4*)(p + i);
      unsigned int d[4] = {q.x, q.y, q.z, q.w};
#pragma unroll
      for (int t = 0; t < 4; ++t) {
        float a = bf2f((unsigned short)(d[t] & 0xffff));
        float b = bf2f((unsigned short)(d[t] >> 16));
        sum += a + b; sq = fmaf(a, a, fmaf(b, b, sq));
      }
    }
  }
  __shared__ float rs[TPB], rq[TPB];
  rs[threadIdx.x] = sum; rq[threadIdx.x] = sq;
  __syncthreads();
  for (int off = TPB / 2; off > 0; off >>= 1) {
    if (threadIdx.x < off) { rs[threadIdx.x] += rs[threadIdx.x + off]; rq[threadIdx.x] += rq[threadIdx.x + off]; }
    __syncthreads();
  }
  if (threadIdx.x == 0) { part[bid * 2] = rs[0]; part[bid * 2 + 1] = rq[0]; }
}

__global__ void stats_final_kernel(const float* __restrict__ part,
    const float* __restrict__ gamma, const float* __restrict__ beta,
    float* __restrict__ ss, float inv_count) {
  int c = blockIdx.x;
  int t = threadIdx.x;  // 64
  float sum = part[(c * 64 + t) * 2];
  float sq  = part[(c * 64 + t) * 2 + 1];
  for (int off = 32; off > 0; off >>= 1) {
    sum += __shfl_down(sum, off);
    sq  += __shfl_down(sq, off);
  }
  if (t == 0) {
    float mean = sum * inv_count;
    float var  = sq * inv_count - mean * mean;
    float rstd = rsqrtf(var + 1e-5f);
    float scl  = gamma[c] * rstd;
    ss[2 * c] = scl;
    ss[2 * c + 1] = beta[c] - mean * scl;
  }
}

// ---------- BN+ReLU for layer 4 (bf16 in -> bf16 out for the MFMA FC) ----------
__global__ __launch_bounds__(TPB) void bnrelu_bf16b(const unsigned short* __restrict__ y,
    const float* __restrict__ ss, unsigned short* __restrict__ out) {
  int q = blockIdx.x * TPB + threadIdx.x;   // 8-wide groups, total 524288
  if (q >= 524288) return;
  int c = (q >> 3) & 127;                   // 64 elems = 8 groups per channel
  float sc = ss[2 * c], sh = ss[2 * c + 1];
  uint4 v = ((const uint4*)y)[q];
  unsigned int d[4] = {v.x, v.y, v.z, v.w};
  uint4 o;
  unsigned int* op = (unsigned int*)&o;
#pragma unroll
  for (int t = 0; t < 4; ++t) {
    float a = fmaxf(fmaf(bf2f((unsigned short)(d[t] & 0xffff)), sc, sh), 0.f);
    float b = fmaxf(fmaf(bf2f((unsigned short)(d[t] >> 16)), sc, sh), 0.f);
    op[t] = (unsigned int)f2bf(a) | ((unsigned int)f2bf(b) << 16);
  }
  ((uint4*)out)[q] = o;
}

// ---------- fp32 -> bf16 cast (for fw1) ----------
__global__ __launch_bounds__(TPB) void cast_bf16_kernel(const float* __restrict__ in,
    unsigned short* __restrict__ out, int nquad) {
  int q = blockIdx.x * TPB + threadIdx.x;
  if (q >= nquad) return;
  float4 v = ((const float4*)in)[q];
  ushort4 o;
  o.x = f2bf(v.x); o.y = f2bf(v.y); o.z = f2bf(v.z); o.w = f2bf(v.w);
  ((ushort4*)out)[q] = o;
}

// ---------- fc1: bf16 MFMA GEMM, M=N=512, K=8192, relu epilogue ----------
__global__ __launch_bounds__(TPB, 2) void fc1_mfma(
    const unsigned short* __restrict__ A, const unsigned short* __restrict__ W,
    const float* __restrict__ bias, float* __restrict__ out) {
  __shared__ unsigned short As[64][64];
  __shared__ unsigned short Bs[64][64];
  const int tid = threadIdx.x;
  const int lane = tid & 63, wave = tid >> 6;
  const int wr = (wave >> 1) * 32, wc = (wave & 1) * 32;
  const int bm = blockIdx.y * 64, bn = blockIdx.x * 64;
  f32x4 acc00 = {0.f, 0.f, 0.f, 0.f}, acc01 = acc00, acc10 = acc00, acc11 = acc00;
  const int r0 = tid >> 3, c0 = tid & 7;
  const int fr = lane & 15, kg = lane >> 4;
  for (int kt = 0; kt < 128; ++kt) {
    const int kb = kt * 64;
    uint4 av0 = *(const uint4*)&A[(size_t)(bm + r0) * 8192 + kb + c0 * 8];
    uint4 av1 = *(const uint4*)&A[(size_t)(bm + r0 + 32) * 8192 + kb + c0 * 8];
    uint4 bv0 = *(const uint4*)&W[(size_t)(bn + r0) * 8192 + kb + c0 * 8];
    uint4 bv1 = *(const uint4*)&W[(size_t)(bn + r0 + 32) * 8192 + kb + c0 * 8];
    __syncthreads();
    *(uint4*)&As[r0][(c0 ^ (r0 & 7)) * 8] = av0;
    *(uint4*)&As[r0 + 32][(c0 ^ (r0 & 7)) * 8] = av1;
    *(uint4*)&Bs[r0][(c0 ^ (r0 & 7)) * 8] = bv0;
    *(uint4*)&Bs[r0 + 32][(c0 ^ (r0 & 7)) * 8] = bv1;
    __syncthreads();
#pragma unroll
    for (int ks = 0; ks < 2; ++ks) {
      int ch = ks * 4 + kg;
      int ra0 = wr + fr, ra1 = wr + 16 + fr;
      int rb0 = wc + fr, rb1 = wc + 16 + fr;
      bf16x8 a_0 = lda_bf8(&As[ra0][(ch ^ (ra0 & 7)) * 8]);
      bf16x8 a_1 = lda_bf8(&As[ra1][(ch ^ (ra1 & 7)) * 8]);
      bf16x8 b_0 = lda_bf8(&Bs[rb0][(ch ^ (rb0 & 7)) * 8]);
      bf16x8 b_1 = lda_bf8(&Bs[rb1][(ch ^ (rb1 & 7)) * 8]);
      acc00 = __builtin_amdgcn_mfma_f32_16x16x32_bf16(a_0, b_0, acc00, 0, 0, 0);
      acc01 = __builtin_amdgcn_mfma_f32_16x16x32_bf16(a_0, b_1, acc01, 0, 0, 0);
      acc10 = __builtin_amdgcn_mfma_f32_16x16x32_bf16(a_1, b_0, acc10, 0, 0, 0);
      acc11 = __builtin_amdgcn_mfma_f32_16x16x32_bf16(a_1, b_1, acc11, 0, 0, 0);
    }
  }
  const int rg = lane >> 4;
  int n0 = bn + wc + fr, n1 = n0 + 16;
  float bi0 = bias[n0], bi1 = bias[n1];
#pragma unroll
  for (int r = 0; r < 4; ++r) {
    int m0 = bm + wr + rg * 4 + r, m1 = m0 + 16;
    out[m0 * 512 + n0] = fmaxf(acc00[r] + bi0, 0.f);
    out[m0 * 512 + n1] = fmaxf(acc01[r] + bi1, 0.f);
    out[m1 * 512 + n0] = fmaxf(acc10[r] + bi0, 0.f);
    out[m1 * 512 + n1] = fmaxf(acc11[r] + bi1, 0.f);
  }
}

// ---------- generic tiled GEMM (fp32, small layers) ----------
__global__ __launch_bounds__(TPB) void gemm_rt(const float* __restrict__ A,
    const float* __restrict__ W, const float* __restrict__ bias,
    float* __restrict__ out, int M, int N, int K, int dorelu) {
  __shared__ float As[32][33];
  __shared__ float Ws[32][33];
  int tid = threadIdx.x;
  int tx = tid & 15, ty = tid >> 4;
  int bm = blockIdx.y << 5, bn = blockIdx.x << 5;
  float a00 = 0.f, a01 = 0.f, a10 = 0.f, a11 = 0.f;
  int nk = (K + 31) >> 5;
  for (int kt = 0; kt < nk; ++kt) {
    int k0 = kt << 5;
#pragma unroll
    for (int l = 0; l < 4; ++l) {
      int idx = tid + (l << 8);
      int r = idx >> 5, c = idx & 31;
      int gc = k0 + c;
      int ga = bm + r;
      As[c][r] = (ga < M && gc < K) ? A[ga * K + gc] : 0.f;
      int gw = bn + r;
      Ws[c][r] = (gw < N && gc < K) ? W[gw * K + gc] : 0.f;
    }
    __syncthreads();
#pragma unroll
    for (int k = 0; k < 32; ++k) {
      float x0 = As[k][ty], x1 = As[k][ty + 16];
      float y0 = Ws[k][tx], y1 = Ws[k][tx + 16];
      a00 = fmaf(x0, y0, a00); a01 = fmaf(x0, y1, a01);
      a10 = fmaf(x1, y0, a10); a11 = fmaf(x1, y1, a11);
    }
    __syncthreads();
  }
  int m0 = bm + ty, m1 = m0 + 16, n0 = bn + tx, n1 = n0 + 16;
  if (m0 < M && n0 < N) { float v = a00 + bias[n0]; out[m0 * N + n0] = dorelu ? fmaxf(v, 0.f) : v; }
  if (m0 < M && n1 < N) { float v = a01 + bias[n1]; out[m0 * N + n1] = dorelu ? fmaxf(v, 0.f) : v; }
  if (m1 < M && n0 < N) { float v = a10 + bias[n0]; out[m1 * N + n0] = dorelu ? fmaxf(v, 0.f) : v; }
  if (m1 < M && n1 < N) { float v = a11 + bias[n1]; out[m1 * N + n1] = dorelu ? fmaxf(v, 0.f) : v; }
}

// ---------- small builders ----------
__global__ __launch_bounds__(TPB) void build_enh_kernel(const float* __restrict__ cond,
    const float* __restrict__ steps, float* __restrict__ enh) {
  int i = blockIdx.x * TPB + threadIdx.x;
  if (i >= 512 * 6) return;
  int n = i / 6, k = i % 6;
  int b = n >> 6, s = n & 63;
  enh[i] = (k < 5) ? cond[b * 5 + k] : steps[b * 64 + s];
}

// fills comb columns 256..575 (mapf, condf); columns 0..255 are written by lstm
__global__ __launch_bounds__(TPB) void build_comb2_kernel(const float* __restrict__ mapf,
    const float* __restrict__ condf, float* __restrict__ comb) {
  int i = blockIdx.x * TPB + threadIdx.x;
  if (i >= 512 * 320) return;
  int n = i / 320, k = i % 320;
  float v = (k < 256) ? mapf[n * 256 + k] : condf[n * 64 + (k - 256)];
  comb[n * 576 + 256 + k] = v;
}

// ---------- LSTM: 64 blocks, register-resident weights, data-tagged exchange ----------
__global__ __launch_bounds__(TPB, 1) void lstm_kernel(
    const float* __restrict__ iseq,
    const float* __restrict__ mw, const float* __restrict__ mb,
    const float* __restrict__ w_ih0, const float* __restrict__ w_hh0,
    const float* __restrict__ b_ih0, const float* __restrict__ b_hh0,
    const float* __restrict__ w_ih1, const float* __restrict__ w_hh1,
    const float* __restrict__ b_ih1, const float* __restrict__ b_hh1,
    unsigned long long* __restrict__ h0x,   // [64][1024] (tag | 2xbf16)
    unsigned long long* __restrict__ h1x,   // [64][1024]
    float* __restrict__ comb) {             // [512][576]; cols 0..255 = lstm h1
  const int tid = threadIdx.x;
  const int blkid = blockIdx.x;
  const int u0 = blkid * 4;

  __shared__ float xz[64][8][16];
  __shared__ __align__(16) char reg2[26112];
  __shared__ float bias1s[16];

  float (*embc)[8][32] = (float (*)[8][32])reg2;
  float* mwmb = (float*)(reg2 + 16384);
  unsigned short (*v0s)[256] = (unsigned short (*)[256])reg2;
  unsigned short (*w1h)[256] = (unsigned short (*)[256])(reg2 + 4096);
  float (*part0)[8][16] = (float (*)[8][16])(reg2 + 8192);
  float (*part1)[8][16] = (float (*)[8][16])(reg2 + 16384);
  float (*zg0)[16] = (float (*)[16])(reg2 + 24576);
  float (*zg1)[16] = (float (*)[16])(reg2 + 25088);

  const int r = tid & 15, ks = tid >> 4;
  const int R = (r >> 2) * 256 + u0 + (r & 3);

  float w0reg[16], w1reg[32], wtmp[32];
#pragma unroll
  for (int i = 0; i < 16; ++i) w0reg[i] = w_hh0[R * 256 + ks * 16 + i];
  if (ks < 8) {
#pragma unroll
    for (int i = 0; i < 32; ++i) w1reg[i] = w_ih1[R * 256 + ks * 32 + i];
  } else {
#pragma unroll
    for (int i = 0; i < 32; ++i) w1reg[i] = w_hh1[R * 256 + (ks - 8) * 32 + i];
  }
#pragma unroll
  for (int i = 0; i < 32; ++i) wtmp[i] = w_ih0[R * 32 + i];
  const float bias0r = b_ih0[R] + b_hh0[R];
  if (tid < 16) bias1s[tid] = b_ih1[R] + b_hh1[R];
  if (tid < 96) mwmb[tid] = (tid < 64) ? mw[tid] : mb[tid - 64];
  __syncthreads();

  for (int chunk = 0; chunk < 4; ++chunk) {
    if (tid < 128) {
      int pp = tid >> 3, b = tid & 7;
      int pg = chunk * 16 + pp;
      float s0 = iseq[(b * 64 + pg) * 2 + 0];
      float s1 = iseq[(b * 64 + pg) * 2 + 1];
      for (int k = 0; k < 32; ++k)
        embc[pp][b][k] = fmaxf(fmaf(mwmb[2 * k], s0, fmaf(mwmb[2 * k + 1], s1, mwmb[64 + k])), 0.f);
    }
    __syncthreads();
    {
      int pg = chunk * 16 + ks;
      for (int b = 0; b < 8; ++b) {
        float a = bias0r;
        const float* e = &embc[ks][b][0];
#pragma unroll
        for (int k = 0; k < 32; ++k) a = fmaf(wtmp[k], e[k], a);
        xz[pg][b][r] = a;
      }
    }
    __syncthreads();
  }

  float c0 = 0.f, c1 = 0.f;
  for (int p = 0; p <= 64; ++p) {
    if (p >= 1) {
      const unsigned tag0 = (unsigned)p, tag1 = (unsigned)(p - 1);
      const unsigned long long* s0p = &h0x[(size_t)(p - 1) * 1024 + tid * 4];
      const unsigned long long* s1p = (p >= 2) ? &h1x[(size_t)(p - 2) * 1024 + tid * 4] : nullptr;
      unsigned long long a0, a1, a2, a3, e0 = 0, e1 = 0, e2 = 0, e3 = 0;
      for (;;) {
        a0 = __hip_atomic_load(&s0p[0], __ATOMIC_RELAXED, __HIP_MEMORY_SCOPE_AGENT);
        a1 = __hip_atomic_load(&s0p[1], __ATOMIC_RELAXED, __HIP_MEMORY_SCOPE_AGENT);
        a2 = __hip_atomic_load(&s0p[2], __ATOMIC_RELAXED, __HIP_MEMORY_SCOPE_AGENT);
        a3 = __hip_atomic_load(&s0p[3], __ATOMIC_RELAXED, __HIP_MEMORY_SCOPE_AGENT);
        bool ok = ((unsigned)(a0 >> 32) == tag0) & ((unsigned)(a1 >> 32) == tag0) &
                  ((unsigned)(a2 >> 32) == tag0) & ((unsigned)(a3 >> 32) == tag0);
        if (p >= 2) {
          e0 = __hip_atomic_load(&s1p[0], __ATOMIC_RELAXED, __HIP_MEMORY_SCOPE_AGENT);
          e1 = __hip_atomic_load(&s1p[1], __ATOMIC_RELAXED, __HIP_MEMORY_SCOPE_AGENT);
          e2 = __hip_atomic_load(&s1p[2], __ATOMIC_RELAXED, __HIP_MEMORY_SCOPE_AGENT);
          e3 = __hip_atomic_load(&s1p[3], __ATOMIC_RELAXED, __HIP_MEMORY_SCOPE_AGENT);
          ok &= ((unsigned)(e0 >> 32) == tag1) & ((unsigned)(e1 >> 32) == tag1) &
                ((unsigned)(e2 >> 32) == tag1) & ((unsigned)(e3 >> 32) == tag1);
        }
        if (ok) break;
        __builtin_amdgcn_s_sleep(2);
      }
#pragma unroll
      for (int i = 0; i < 4; ++i) {
        int g = tid * 4 + i;
        int bb = (g & 15) >> 1, ub = (g >> 4) * 4 + (g & 1) * 2;
        unsigned long long va = (i == 0) ? a0 : (i == 1) ? a1 : (i == 2) ? a2 : a3;
        *(unsigned int*)&v0s[bb][ub] = (unsigned int)va;
        if (p >= 2) {
          unsigned long long ve = (i == 0) ? e0 : (i == 1) ? e1 : (i == 2) ? e2 : e3;
          *(unsigned int*)&w1h[bb][ub] = (unsigned int)ve;
        }
      }
    }
    if (p < 1) {
#pragma unroll
      for (int i = 0; i < 4; ++i) ((unsigned int*)v0s)[tid * 4 + i] = 0u;
    }
    if (p < 2) {
#pragma unroll
      for (int i = 0; i < 4; ++i) ((unsigned int*)w1h)[tid * 4 + i] = 0u;
    }
    __syncthreads();

    if (p < 64) {
#pragma unroll
      for (int b = 0; b < 8; ++b) {
        uint4 q0 = *(const uint4*)&v0s[b][ks * 16];
        uint4 q1 = *(const uint4*)&v0s[b][ks * 16 + 8];
        float a = 0.f;
        a = fma8(q0, &w0reg[0], a);
        a = fma8(q1, &w0reg[8], a);
        part0[ks][b][r] = a;
      }
    }
    if (p >= 1) {
      const unsigned short* sp = (ks < 8) ? &v0s[0][ks * 32] : &w1h[0][(ks - 8) * 32];
#pragma unroll
      for (int b = 0; b < 8; ++b) {
        const uint4* qp = (const uint4*)(sp + b * 256);
        float a = 0.f;
        a = fma8(qp[0], &w1reg[0], a);
        a = fma8(qp[1], &w1reg[8], a);
        a = fma8(qp[2], &w1reg[16], a);
        a = fma8(qp[3], &w1reg[24], a);
        part1[ks][b][r] = a;
      }
    }
    __syncthreads();

    if (tid < 128) {
      int b = tid >> 4, rr = tid & 15;
      if (p < 64) {
        float s = xz[p][b][rr];
#pragma unroll
        for (int k2 = 0; k2 < 16; ++k2) s += part0[k2][b][rr];
        zg0[b][rr] = s;
      }
    } else {
      int t2 = tid - 128, b = t2 >> 4, rr = t2 & 15;
      if (p >= 1) {
        float s = bias1s[rr];
#pragma unroll
        for (int k2 = 0; k2 < 16; ++k2) s += part1[k2][b][rr];
        zg1[b][rr] = s;
      }
    }
    __syncthreads();

    if (tid < 32) {
      if (p < 64) {
        int b = tid >> 2, uu = tid & 3;
        float zi = zg0[b][uu], zf = zg0[b][4 + uu], zgv = zg0[b][8 + uu], zo = zg0[b][12 + uu];
        c0 = sigf(zf) * c0 + sigf(zi) * tanhf(zgv);
        float h = sigf(zo) * tanhf(c0);
        float hp = __shfl_xor(h, 1);
        if (!(uu & 1)) {
          unsigned int d = (unsigned int)f2bf(h) | ((unsigned int)f2bf(hp) << 16);
          unsigned long long v = ((unsigned long long)(unsigned)(p + 1) << 32) | d;
          __hip_atomic_store(&h0x[(size_t)p * 1024 + blkid * 16 + b * 2 + (uu >> 1)], v,
                             __ATOMIC_RELAXED, __HIP_MEMORY_SCOPE_AGENT);
        }
      }
    } else if (tid < 64) {
      if (p >= 1) {
        int t2 = tid - 32, b = t2 >> 2, uu = t2 & 3;
        float zi = zg1[b][uu], zf = zg1[b][4 + uu], zgv = zg1[b][8 + uu], zo = zg1[b][12 + uu];
        c1 = sigf(zf) * c1 + sigf(zi) * tanhf(zgv);
        float h = sigf(zo) * tanhf(c1);
        comb[(size_t)(b * 64 + (p - 1)) * 576 + u0 + uu] = h;
        float hp = __shfl_xor(h, 1);
        if (!(uu & 1)) {
          unsigned int d = (unsigned int)f2bf(h) | ((unsigned int)f2bf(hp) << 16);
          unsigned long long v = ((unsigned long long)(unsigned)p << 32) | d;
          __hip_atomic_store(&h1x[(size_t)(p - 1) * 1024 + blkid * 16 + b * 2 + (uu >> 1)], v,
                             __ATOMIC_RELAXED, __HIP_MEMORY_SCOPE_AGENT);
        }
      }
    }
  }
}

// ---------- launcher ----------
extern "C" void kernel_launch(void* const* d_in, const int* in_sizes, int n_in,
                              void* d_out, int out_size, void* d_ws, size_t ws_size,
                              hipStream_t stream) {
  const float* fmap  = (const float*)d_in[0];
  const float* cond  = (const float*)d_in[1];
  const float* iseq  = (const float*)d_in[2];
  const float* steps = (const float*)d_in[3];
  const float* cw1 = (const float*)d_in[4];  const float* cb1 = (const float*)d_in[5];
  const float* g1  = (const float*)d_in[6];  const float* be1 = (const float*)d_in[7];
  const float* cw2 = (const float*)d_in[8];  const float* cb2 = (const float*)d_in[9];
  const float* g2  = (const float*)d_in[10]; const float* be2 = (const float*)d_in[11];
  const float* cw3 = (const float*)d_in[12]; const float* cb3 = (const float*)d_in[13];
  const float* g3  = (const float*)d_in[14]; const float* be3 = (const float*)d_in[15];
  const float* cw4 = (const float*)d_in[16]; const float* cb4 = (const float*)d_in[17];
  const float* g4  = (const float*)d_in[18]; const float* be4 = (const float*)d_in[19];
  const float* fw1 = (const float*)d_in[20]; const float* fb1 = (const float*)d_in[21];
  const float* fw2 = (const float*)d_in[22]; const float* fb2 = (const float*)d_in[23];
  const float* ew1 = (const float*)d_in[24]; const float* eb1 = (const float*)d_in[25];
  const float* ew2 = (const float*)d_in[26]; const float* eb2 = (const float*)d_in[27];
  const float* mw  = (const float*)d_in[28]; const float* mb  = (const float*)d_in[29];
  const float* w_ih0 = (const float*)d_in[30]; const float* w_hh0 = (const float*)d_in[31];
  const float* b_ih0 = (const float*)d_in[32]; const float* b_hh0 = (const float*)d_in[33];
  const float* w_ih1 = (const float*)d_in[34]; const float* w_hh1 = (const float*)d_in[35];
  const float* b_ih1 = (const float*)d_in[36]; const float* b_hh1 = (const float*)d_in[37];
  const float* xw1 = (const float*)d_in[38]; const float* xb1 = (const float*)d_in[39];
  const float* xw2 = (const float*)d_in[40]; const float* xb2 = (const float*)d_in[41];
  const float* ow  = (const float*)d_in[42]; const float* ob  = (const float*)d_in[43];

  float* ws = (float*)d_ws;
  unsigned short* y1bf  = (unsigned short*)ws;                 // [0, 16777216) f
  unsigned short* y2bf  = (unsigned short*)(ws + 16777216);    // 8388608 f
  unsigned short* y3bf  = (unsigned short*)(ws + 25165824);    // 4194304 f
  unsigned short* y4pre = (unsigned short*)(ws + 29360128);    // 2097152 f
  unsigned short* y4bn  = (unsigned short*)(ws + 31457280);    // 2097152 f
  unsigned short* fw1bf = (unsigned short*)(ws + 33554432);    // 2097152 f
  size_t base = 35651584;
  float* part  = ws + base; base += 16384;
  float* ss1   = ws + base; base += 32;
  float* ss2   = ws + base; base += 64;
  float* ss3   = ws + base; base += 128;
  float* ss4   = ws + base; base += 256;
  float* f1    = ws + base; base += 262144;
  float* mapf  = ws + base; base += 131072;
  float* enh   = ws + base; base += 3072;
  float* ceh   = ws + base; base += 65536;
  float* condf = ws + base; base += 32768;
  unsigned long long* h0x = (unsigned long long*)(ws + base); base += 131072;
  unsigned long long* h1x = (unsigned long long*)(ws + base); base += 131072;
  float* comb  = ws + base; base += 294912;
  float* cx1   = ws + base; base += 65536;
  float* cx2   = ws + base; base += 32768;

  // --- encoder convs (MFMA implicit GEMM, bf16) with batch-stat BN folded ---
  conv_mfma<3, 16, 128, 64, true><<<32768, TPB, 0, stream>>>(nullptr, fmap, iseq, nullptr, cw1, cb1, y1bf);
  cast_bf16_kernel<<<4096, TPB, 0, stream>>>(fw1, fw1bf, 1048576);
  stats_partial_bf16<<<16 * 64, TPB, 0, stream>>>(y1bf, part, 16, 4096);
  stats_final_kernel<<<16, 64, 0, stream>>>(part, g1, be1, ss1, 1.f / 2097152.f);
  conv_mfma<16, 32, 64, 32, false><<<8192, TPB, 0, stream>>>(y1bf, nullptr, nullptr, ss1, cw2, cb2, y2bf);
  stats_partial_bf16<<<32 * 64, TPB, 0, stream>>>(y2bf, part, 32, 1024);
  stats_final_kernel<<<32, 64, 0, stream>>>(part, g2, be2, ss2, 1.f / 524288.f);
  conv_mfma<32, 64, 32, 16, false><<<2048, TPB, 0, stream>>>(y2bf, nullptr, nullptr, ss2, cw3, cb3, y3bf);
  stats_partial_bf16<<<64 * 64, TPB, 0, stream>>>(y3bf, part, 64, 256);
  stats_final_kernel<<<64, 64, 0, stream>>>(part, g3, be3, ss3, 1.f / 131072.f);
  conv_mfma<64, 128, 16, 8, false><<<512, TPB, 0, stream>>>(y3bf, nullptr, nullptr, ss3, cw4, cb4, y4pre);
  stats_partial_bf16<<<128 * 64, TPB, 0, stream>>>(y4pre, part, 128, 64);
  stats_final_kernel<<<128, 64, 0, stream>>>(part, g4, be4, ss4, 1.f / 32768.f);
  bnrelu_bf16b<<<2048, TPB, 0, stream>>>(y4pre, ss4, y4bn);

  // --- LSTM (tag-fused exchange); clears exchange tags first ---
  hipMemsetAsync(h0x, 0, 2 * 64 * 1024 * sizeof(unsigned long long), stream);
  lstm_kernel<<<NLB, TPB, 0, stream>>>(iseq, mw, mb,
                                       w_ih0, w_hh0, b_ih0, b_hh0,
                                       w_ih1, w_hh1, b_ih1, b_hh1,
                                       h0x, h1x, comb);

  // --- map-feature MLP (fc1 via bf16 MFMA) ---
  fc1_mfma<<<dim3(8, 8), TPB, 0, stream>>>(y4bn, fw1bf, fb1, f1);
  gemm_rt<<<dim3(8, 16),  TPB, 0, stream>>>(f1, fw2, fb2, mapf, 512, 256, 512, 0);

  // --- condition encoder ---
  build_enh_kernel<<<12, TPB, 0, stream>>>(cond, steps, enh);
  gemm_rt<<<dim3(4, 16), TPB, 0, stream>>>(enh, ew1, eb1, ceh, 512, 128, 6, 1);
  gemm_rt<<<dim3(2, 16), TPB, 0, stream>>>(ceh, ew2, eb2, condf, 512, 64, 128, 0);

  // --- head ---
  build_comb2_kernel<<<640, TPB, 0, stream>>>(mapf, condf, comb);
  gemm_rt<<<dim3(4, 16), TPB, 0, stream>>>(comb, xw1, xb1, cx1, 512, 128, 576, 1);
  gemm_rt<<<dim3(2, 16), TPB, 0, stream>>>(cx1, xw2, xb2, cx2, 512, 64, 128, 1);
  gemm_rt<<<dim3(1, 16), TPB, 0, stream>>>(cx2, ow, ob, (float*)d_out, 512, 2, 64, 0);
}

// Round 6
// 933.245 us; speedup vs baseline: 7.8855x; 1.0181x over previous
//
#include <hip/hip_runtime.h>

#define TPB 256
#define NLB 64   // LSTM blocks

typedef float f32x4 __attribute__((ext_vector_type(4)));
typedef short bf16x8 __attribute__((ext_vector_type(8)));

// ---------- helpers ----------
__device__ __forceinline__ float bf2f(unsigned short u) {
  union { unsigned int i; float f; } x; x.i = ((unsigned int)u) << 16; return x.f;
}
__device__ __forceinline__ unsigned short f2bf(float v) {
  union { float f; unsigned int i; } x; x.f = v;
  unsigned int r = (x.i + 0x7fffu + ((x.i >> 16) & 1u)) >> 16;
  return (unsigned short)r;
}
__device__ __forceinline__ float sigf(float x) { return 1.f / (1.f + __expf(-x)); }
__device__ __forceinline__ bf16x8 lda_bf8(const unsigned short* p) {
  union { uint4 u; bf16x8 v; } t; t.u = *(const uint4*)p; return t.v;
}
__device__ __forceinline__ float fma8(uint4 q, const float* w, float a) {
  union { unsigned int u; float f; } t;
  t.u = q.x << 16;         a = fmaf(w[0], t.f, a);
  t.u = q.x & 0xffff0000u; a = fmaf(w[1], t.f, a);
  t.u = q.y << 16;         a = fmaf(w[2], t.f, a);
  t.u = q.y & 0xffff0000u; a = fmaf(w[3], t.f, a);
  t.u = q.z << 16;         a = fmaf(w[4], t.f, a);
  t.u = q.z & 0xffff0000u; a = fmaf(w[5], t.f, a);
  t.u = q.w << 16;         a = fmaf(w[6], t.f, a);
  t.u = q.w & 0xffff0000u; a = fmaf(w[7], t.f, a);
  return a;
}

// ================= conv1: crop-gather im2col MFMA (unchanged from r5) =================
template<int CIN, int COUT, int HIN, int HOUT, bool CROP>
__global__ __launch_bounds__(TPB, 4) void conv_mfma(
    const unsigned short* __restrict__ inb,
    const float* __restrict__ fmap,
    const float* __restrict__ iseq,
    const float* __restrict__ ss,
    const float* __restrict__ w,
    const float* __restrict__ bias,
    unsigned short* __restrict__ out) {
  constexpr int K = CIN * 9;
  constexpr int NCH = (K + 31) / 32;
  constexpr int NT = COUT / 16;
  constexpr int RGR = (HOUT * HOUT) / 64;
  constexpr int RPB = 64 / HOUT;

  __shared__ unsigned short Asm[64][40];
  __shared__ unsigned short Bsm[COUT][40];
  __shared__ unsigned int lut[NCH * 32];

  const int tid = threadIdx.x;
  const int wave = tid >> 6, lane = tid & 63;
  const int fr = lane & 15, kg = lane >> 4;
  const int n = blockIdx.x / RGR;
  const int row0 = (blockIdx.x % RGR) * RPB;

  for (int k = tid; k < NCH * 32; k += TPB)
    lut[k] = (k < K) ? (((unsigned)(k / 9) << 8) | ((unsigned)((k % 9) / 3) << 4) | (unsigned)(k % 3))
                     : 0xFFFFFFFFu;
  int cy = 0, cx = 0;
  if (CROP) { cy = (int)iseq[n * 2]; cx = (int)iseq[n * 2 + 1]; }

  f32x4 acc[NT];
#pragma unroll
  for (int j = 0; j < NT; ++j) acc[j] = {0.f, 0.f, 0.f, 0.f};

  for (int ch = 0; ch < NCH; ++ch) {
    const int kb = ch * 32;
    __syncthreads();
#pragma unroll
    for (int jj = 0; jj < 8; ++jj) {
      int e = jj * 256 + tid;
      int k = e >> 6, p = e & 63;
      unsigned info = lut[kb + k];
      int oi = row0 + p / HOUT;
      int oj = p % HOUT;
      float v = 0.f;
      if (info != 0xFFFFFFFFu) {
        int ic = info >> 8, ki = (info >> 4) & 15, kj = info & 15;
        int ir = 2 * oi - 1 + ki;
        int jc = 2 * oj - 1 + kj;
        if ((unsigned)ir < (unsigned)HIN && (unsigned)jc < (unsigned)HIN) {
          int mr = cy + ir - 64, mc = cx + jc - 64;
          if ((unsigned)mr < 1024u && (unsigned)mc < 1024u)
            v = fmap[(((size_t)(n >> 6) * 3 + ic) << 20) + ((size_t)mr << 10) + mc];
        }
      }
      Asm[p][k] = f2bf(v);
    }
#pragma unroll
    for (int jj = 0; jj < COUT / 8; ++jj) {
      int e = jj * 256 + tid;
      int oc = e >> 5, t = e & 31;
      int kk = kb + t;
      float v = (kk < K) ? w[(size_t)oc * K + kk] : 0.f;
      Bsm[oc][t] = f2bf(v);
    }
    __syncthreads();
    bf16x8 af = lda_bf8(&Asm[wave * 16 + fr][kg * 8]);
#pragma unroll
    for (int j = 0; j < NT; ++j) {
      bf16x8 bfr = lda_bf8(&Bsm[j * 16 + fr][kg * 8]);
      acc[j] = __builtin_amdgcn_mfma_f32_16x16x32_bf16(af, bfr, acc[j], 0, 0, 0);
    }
  }
  const int rg = lane >> 4;
#pragma unroll
  for (int j = 0; j < NT; ++j) {
    int oc = j * 16 + fr;
    float bb = bias[oc];
#pragma unroll
    for (int r = 0; r < 4; ++r) {
      int p = wave * 16 + rg * 4 + r;
      int oi = row0 + p / HOUT, oj = p % HOUT;
      out[((size_t)(n * COUT + oc) * HOUT + oi) * HOUT + oj] = f2bf(acc[j][r] + bb);
    }
  }
}

// ================= tap-shifted MFMA conv (conv2/3/4) =================
// Block: 8x8 output tile of one image x COUT_BLK channels. Patch staged ONCE
// ([17][17][CIN+8] bf16, BN+ReLU applied); weights pre-transposed tap-major.
// MFMA A-fragments read directly from the patch at (ki,kj)-shifted addresses.
template<int CIN, int COUT_BLK, int NSPLIT, int HIN, int HOUT>
__global__ __launch_bounds__(TPB, 2) void conv_tap(
    const unsigned short* __restrict__ inb,   // bf16 prev activation (pre-BN)
    const float* __restrict__ ss,             // prev-layer BN scale/shift
    const unsigned short* __restrict__ wT,    // [COUT_TOT][K] bf16, k = tap*CIN+ic
    const float* __restrict__ bias,
    unsigned short* __restrict__ out) {       // bf16 [n][COUT_TOT][HOUT][HOUT]
  constexpr int K = CIN * 9;
  constexpr int K8 = K / 8;
  constexpr int NCH = (K8 + 3) / 4;
  constexpr int KPAD = NCH * 32;
  constexpr int BS = KPAD + 8;                // bank-friendly row stride (2-way)
  constexpr int CINP = CIN + 8;               // bank-friendly col stride (2-way)
  constexpr int ICG_SH = (CIN == 16) ? 1 : (CIN == 32) ? 2 : 3;
  constexpr int TPR = HOUT / 8;
  constexpr int TILES = TPR * TPR;
  constexpr int NT = COUT_BLK / 16;
  constexpr int COUT_TOT = COUT_BLK * NSPLIT;

  __shared__ unsigned short patch[289 * CINP];
  __shared__ unsigned short Bsm[COUT_BLK * BS];
  __shared__ float ssl[CIN * 2];

  const int tid = threadIdx.x;
  const int bid = blockIdx.x;
  const int n = bid / (TILES * NSPLIT);
  const int rem = bid % (TILES * NSPLIT);
  const int tile = rem / NSPLIT;
  const int split = rem % NSPLIT;
  const int TR0 = (tile / TPR) * 8, TC0 = (tile % TPR) * 8;
  const int oc0 = split * COUT_BLK;

  for (int i = tid; i < CIN * 2; i += TPB) ssl[i] = ss[i];
  __syncthreads();

  // ---- patch stage (once) ----
  for (int e = tid; e < 289 * CIN; e += TPB) {
    int ic = e / 289, pix = e % 289;
    int row = pix / 17, col = pix % 17;
    int ir = 2 * TR0 - 1 + row, jc = 2 * TC0 - 1 + col;
    float v = 0.f;
    if ((unsigned)ir < (unsigned)HIN && (unsigned)jc < (unsigned)HIN) {
      float x = bf2f(inb[((size_t)(n * CIN + ic) * HIN + ir) * HIN + jc]);
      v = fmaxf(fmaf(x, ssl[2 * ic], ssl[2 * ic + 1]), 0.f);
    }
    patch[pix * CINP + ic] = f2bf(v);
  }
  // ---- B stage (uint4, pre-transposed weights) ----
  constexpr int B8 = COUT_BLK * (KPAD / 8);
  for (int e = tid; e < B8; e += TPB) {
    int oc = e / (KPAD / 8), k8i = e % (KPAD / 8);
    uint4 v = {0u, 0u, 0u, 0u};
    if (k8i * 8 < K) v = *(const uint4*)&wT[(size_t)(oc0 + oc) * K + k8i * 8];
    *(uint4*)&Bsm[oc * BS + k8i * 8] = v;
  }
  __syncthreads();

  const int wave = tid >> 6, lane = tid & 63;
  const int fr = lane & 15, kg = lane >> 4;
  const int p = wave * 16 + fr;
  const int pr = p >> 3, pc = p & 7;
  f32x4 acc[NT];
#pragma unroll
  for (int j = 0; j < NT; ++j) acc[j] = {0.f, 0.f, 0.f, 0.f};

#pragma unroll
  for (int ch = 0; ch < NCH; ++ch) {
    int k8 = ch * 4 + kg;
    int tap = k8 >> ICG_SH, icg = k8 & ((1 << ICG_SH) - 1);
    int ki = (tap * 11) >> 5;       // tap/3 for tap<=9
    int kj = tap - 3 * ki;
    int addr = ((2 * pr + ki) * 17 + (2 * pc + kj)) * CINP + icg * 8;
    if (tap >= 9) addr = 0;         // zero-weight pad slices
    bf16x8 af = lda_bf8(&patch[addr]);
#pragma unroll
    for (int j = 0; j < NT; ++j) {
      bf16x8 bfr = lda_bf8(&Bsm[(j * 16 + fr) * BS + ch * 32 + kg * 8]);
      acc[j] = __builtin_amdgcn_mfma_f32_16x16x32_bf16(af, bfr, acc[j], 0, 0, 0);
    }
  }
  const int rg = lane >> 4;
#pragma unroll
  for (int j = 0; j < NT; ++j) {
    int oc = oc0 + j * 16 + fr;
    float bb = bias[oc];
#pragma unroll
    for (int r = 0; r < 4; ++r) {
      int pp = wave * 16 + rg * 4 + r;
      int orow = TR0 + (pp >> 3), ocol = TC0 + (pp & 7);
      out[((size_t)(n * COUT_TOT + oc) * HOUT + orow) * HOUT + ocol] = f2bf(acc[j][r] + bb);
    }
  }
}

// ---------- weight transpose+cast prep (tap-major bf16) ----------
__global__ __launch_bounds__(TPB) void prep_wt(
    const float* __restrict__ w2, const float* __restrict__ w3, const float* __restrict__ w4,
    unsigned short* __restrict__ wt2, unsigned short* __restrict__ wt3, unsigned short* __restrict__ wt4) {
  int i = blockIdx.x * TPB + threadIdx.x;
  if (i < 4608) {                               // conv2: 32 x 144
    int oc = i / 144, k = i % 144;
    wt2[i] = f2bf(w2[(oc * 16 + (k & 15)) * 9 + (k >> 4)]);
  } else if (i < 4608 + 18432) {                // conv3: 64 x 288
    int j = i - 4608;
    int oc = j / 288, k = j % 288;
    wt3[j] = f2bf(w3[(oc * 32 + (k & 31)) * 9 + (k >> 5)]);
  } else if (i < 96768) {                       // conv4: 128 x 576
    int j = i - 23040;
    int oc = j / 576, k = j % 576;
    wt4[j] = f2bf(w4[(oc * 64 + (k & 63)) * 9 + (k >> 6)]);
  }
}

// ---------- BN statistics over bf16 y (deterministic two-stage) ----------
__global__ __launch_bounds__(TPB) void stats_partial_bf16(
    const unsigned short* __restrict__ y, float* __restrict__ part, int C, int HW) {
  int bid = blockIdx.x;
  int c = bid >> 6;
  int s = bid & 63;
  float sum = 0.f, sq = 0.f;
  for (int nn = 0; nn < 8; ++nn) {
    const unsigned short* p = y + ((size_t)(s * 8 + nn) * C + c) * HW;
    for (int i = threadIdx.x * 8; i < HW; i += TPB * 8) {
      uint4 q = *(const uint4*)(p + i);
      unsigned int d[4] = {q.x, q.y, q.z, q.w};
#pragma unroll
      for (int t = 0; t < 4; ++t) {
        float a = bf2f((unsigned short)(d[t] & 0xffff));
        float b = bf2f((unsigned short)(d[t] >> 16));
        sum += a + b; sq = fmaf(a, a, fmaf(b, b, sq));
      }
    }
  }
  __shared__ float rs[TPB], rq[TPB];
  rs[threadIdx.x] = sum; rq[threadIdx.x] = sq;
  __syncthreads();
  for (int off = TPB / 2; off > 0; off >>= 1) {
    if (threadIdx.x < off) { rs[threadIdx.x] += rs[threadIdx.x + off]; rq[threadIdx.x] += rq[threadIdx.x + off]; }
    __syncthreads();
  }
  if (threadIdx.x == 0) { part[bid * 2] = rs[0]; part[bid * 2 + 1] = rq[0]; }
}

__global__ void stats_final_kernel(const float* __restrict__ part,
    const float* __restrict__ gamma, const float* __restrict__ beta,
    float* __restrict__ ss, float inv_count) {
  int c = blockIdx.x;
  int t = threadIdx.x;  // 64
  float sum = part[(c * 64 + t) * 2];
  float sq  = part[(c * 64 + t) * 2 + 1];
  for (int off = 32; off > 0; off >>= 1) {
    sum += __shfl_down(sum, off);
    sq  += __shfl_down(sq, off);
  }
  if (t == 0) {
    float mean = sum * inv_count;
    float var  = sq * inv_count - mean * mean;
    float rstd = rsqrtf(var + 1e-5f);
    float scl  = gamma[c] * rstd;
    ss[2 * c] = scl;
    ss[2 * c + 1] = beta[c] - mean * scl;
  }
}

// ---------- BN+ReLU for layer 4 (bf16 -> bf16) ----------
__global__ __launch_bounds__(TPB) void bnrelu_bf16b(const unsigned short* __restrict__ y,
    const float* __restrict__ ss, unsigned short* __restrict__ out) {
  int q = blockIdx.x * TPB + threadIdx.x;
  if (q >= 524288) return;
  int c = (q >> 3) & 127;
  float sc = ss[2 * c], sh = ss[2 * c + 1];
  uint4 v = ((const uint4*)y)[q];
  unsigned int d[4] = {v.x, v.y, v.z, v.w};
  uint4 o;
  unsigned int* op = (unsigned int*)&o;
#pragma unroll
  for (int t = 0; t < 4; ++t) {
    float a = fmaxf(fmaf(bf2f((unsigned short)(d[t] & 0xffff)), sc, sh), 0.f);
    float b = fmaxf(fmaf(bf2f((unsigned short)(d[t] >> 16)), sc, sh), 0.f);
    op[t] = (unsigned int)f2bf(a) | ((unsigned int)f2bf(b) << 16);
  }
  ((uint4*)out)[q] = o;
}

// ---------- fp32 -> bf16 cast (for fw1) ----------
__global__ __launch_bounds__(TPB) void cast_bf16_kernel(const float* __restrict__ in,
    unsigned short* __restrict__ out, int nquad) {
  int q = blockIdx.x * TPB + threadIdx.x;
  if (q >= nquad) return;
  float4 v = ((const float4*)in)[q];
  ushort4 o;
  o.x = f2bf(v.x); o.y = f2bf(v.y); o.z = f2bf(v.z); o.w = f2bf(v.w);
  ((ushort4*)out)[q] = o;
}

// ---------- fc1: bf16 MFMA GEMM, M=N=512, K=8192, relu epilogue ----------
__global__ __launch_bounds__(TPB, 2) void fc1_mfma(
    const unsigned short* __restrict__ A, const unsigned short* __restrict__ W,
    const float* __restrict__ bias, float* __restrict__ out) {
  __shared__ unsigned short As[64][64];
  __shared__ unsigned short Bs[64][64];
  const int tid = threadIdx.x;
  const int lane = tid & 63, wave = tid >> 6;
  const int wr = (wave >> 1) * 32, wc = (wave & 1) * 32;
  const int bm = blockIdx.y * 64, bn = blockIdx.x * 64;
  f32x4 acc00 = {0.f, 0.f, 0.f, 0.f}, acc01 = acc00, acc10 = acc00, acc11 = acc00;
  const int r0 = tid >> 3, c0 = tid & 7;
  const int fr = lane & 15, kg = lane >> 4;
  for (int kt = 0; kt < 128; ++kt) {
    const int kb = kt * 64;
    uint4 av0 = *(const uint4*)&A[(size_t)(bm + r0) * 8192 + kb + c0 * 8];
    uint4 av1 = *(const uint4*)&A[(size_t)(bm + r0 + 32) * 8192 + kb + c0 * 8];
    uint4 bv0 = *(const uint4*)&W[(size_t)(bn + r0) * 8192 + kb + c0 * 8];
    uint4 bv1 = *(const uint4*)&W[(size_t)(bn + r0 + 32) * 8192 + kb + c0 * 8];
    __syncthreads();
    *(uint4*)&As[r0][(c0 ^ (r0 & 7)) * 8] = av0;
    *(uint4*)&As[r0 + 32][(c0 ^ (r0 & 7)) * 8] = av1;
    *(uint4*)&Bs[r0][(c0 ^ (r0 & 7)) * 8] = bv0;
    *(uint4*)&Bs[r0 + 32][(c0 ^ (r0 & 7)) * 8] = bv1;
    __syncthreads();
#pragma unroll
    for (int ks = 0; ks < 2; ++ks) {
      int ch = ks * 4 + kg;
      int ra0 = wr + fr, ra1 = wr + 16 + fr;
      int rb0 = wc + fr, rb1 = wc + 16 + fr;
      bf16x8 a_0 = lda_bf8(&As[ra0][(ch ^ (ra0 & 7)) * 8]);
      bf16x8 a_1 = lda_bf8(&As[ra1][(ch ^ (ra1 & 7)) * 8]);
      bf16x8 b_0 = lda_bf8(&Bs[rb0][(ch ^ (rb0 & 7)) * 8]);
      bf16x8 b_1 = lda_bf8(&Bs[rb1][(ch ^ (rb1 & 7)) * 8]);
      acc00 = __builtin_amdgcn_mfma_f32_16x16x32_bf16(a_0, b_0, acc00, 0, 0, 0);
      acc01 = __builtin_amdgcn_mfma_f32_16x16x32_bf16(a_0, b_1, acc01, 0, 0, 0);
      acc10 = __builtin_amdgcn_mfma_f32_16x16x32_bf16(a_1, b_0, acc10, 0, 0, 0);
      acc11 = __builtin_amdgcn_mfma_f32_16x16x32_bf16(a_1, b_1, acc11, 0, 0, 0);
    }
  }
  const int rg = lane >> 4;
  int n0 = bn + wc + fr, n1 = n0 + 16;
  float bi0 = bias[n0], bi1 = bias[n1];
#pragma unroll
  for (int r = 0; r < 4; ++r) {
    int m0 = bm + wr + rg * 4 + r, m1 = m0 + 16;
    out[m0 * 512 + n0] = fmaxf(acc00[r] + bi0, 0.f);
    out[m0 * 512 + n1] = fmaxf(acc01[r] + bi1, 0.f);
    out[m1 * 512 + n0] = fmaxf(acc10[r] + bi0, 0.f);
    out[m1 * 512 + n1] = fmaxf(acc11[r] + bi1, 0.f);
  }
}

// ---------- small GEMM via MFMA: out[m,n] = act(A[m,:]@W[n,:] + b[n]), fp32 I/O ----------
// grid (ceil(N/64), M/64). Casts fp32->bf16 in staging. K, N runtime.
__global__ __launch_bounds__(TPB, 2) void gemm_m64(
    const float* __restrict__ A, const float* __restrict__ W,
    const float* __restrict__ bias, float* __restrict__ out,
    int N, int K, int relu) {
  __shared__ unsigned short As[64 * 40];
  __shared__ unsigned short Bs[64 * 40];
  const int tid = threadIdx.x, lane = tid & 63, wave = tid >> 6;
  const int wr = (wave >> 1) * 32, wc = (wave & 1) * 32;
  const int bm = blockIdx.y * 64, bn = blockIdx.x * 64;
  const int fr = lane & 15, kg = lane >> 4;
  const int sr = tid >> 2, sc = (tid & 3) * 8;
  f32x4 a00 = {0.f, 0.f, 0.f, 0.f}, a01 = a00, a10 = a00, a11 = a00;
  int nch = (K + 31) >> 5;
  for (int ch = 0; ch < nch; ++ch) {
    int kb = ch * 32;
    __syncthreads();
    {
      unsigned short tmp[8];
#pragma unroll
      for (int j = 0; j < 8; ++j) {
        int k = kb + sc + j;
        tmp[j] = (k < K) ? f2bf(A[(size_t)(bm + sr) * K + k]) : (unsigned short)0;
      }
      *(uint4*)&As[sr * 40 + sc] = *(const uint4*)tmp;
      int wrow = bn + sr;
#pragma unroll
      for (int j = 0; j < 8; ++j) {
        int k = kb + sc + j;
        tmp[j] = (wrow < N && k < K) ? f2bf(W[(size_t)wrow * K + k]) : (unsigned short)0;
      }
      *(uint4*)&Bs[sr * 40 + sc] = *(const uint4*)tmp;
    }
    __syncthreads();
    bf16x8 af0 = lda_bf8(&As[(wr + fr) * 40 + kg * 8]);
    bf16x8 af1 = lda_bf8(&As[(wr + 16 + fr) * 40 + kg * 8]);
    bf16x8 bf0 = lda_bf8(&Bs[(wc + fr) * 40 + kg * 8]);
    bf16x8 bf1 = lda_bf8(&Bs[(wc + 16 + fr) * 40 + kg * 8]);
    a00 = __builtin_amdgcn_mfma_f32_16x16x32_bf16(af0, bf0, a00, 0, 0, 0);
    a01 = __builtin_amdgcn_mfma_f32_16x16x32_bf16(af0, bf1, a01, 0, 0, 0);
    a10 = __builtin_amdgcn_mfma_f32_16x16x32_bf16(af1, bf0, a10, 0, 0, 0);
    a11 = __builtin_amdgcn_mfma_f32_16x16x32_bf16(af1, bf1, a11, 0, 0, 0);
  }
  const int rg = lane >> 4;
  int n0 = bn + wc + fr, n1 = n0 + 16;
  float bi0 = (n0 < N) ? bias[n0] : 0.f;
  float bi1 = (n1 < N) ? bias[n1] : 0.f;
#pragma unroll
  for (int r = 0; r < 4; ++r) {
    int m0 = bm + wr + rg * 4 + r, m1 = m0 + 16;
    if (n0 < N) {
      float v = a00[r] + bi0; out[(size_t)m0 * N + n0] = relu ? fmaxf(v, 0.f) : v;
      v = a10[r] + bi0;       out[(size_t)m1 * N + n0] = relu ? fmaxf(v, 0.f) : v;
    }
    if (n1 < N) {
      float v = a01[r] + bi1; out[(size_t)m0 * N + n1] = relu ? fmaxf(v, 0.f) : v;
      v = a11[r] + bi1;       out[(size_t)m1 * N + n1] = relu ? fmaxf(v, 0.f) : v;
    }
  }
}

// ---------- small builders ----------
__global__ __launch_bounds__(TPB) void build_enh_kernel(const float* __restrict__ cond,
    const float* __restrict__ steps, float* __restrict__ enh) {
  int i = blockIdx.x * TPB + threadIdx.x;
  if (i >= 512 * 6) return;
  int n = i / 6, k = i % 6;
  int b = n >> 6, s = n & 63;
  enh[i] = (k < 5) ? cond[b * 5 + k] : steps[b * 64 + s];
}

__global__ __launch_bounds__(TPB) void build_comb2_kernel(const float* __restrict__ mapf,
    const float* __restrict__ condf, float* __restrict__ comb) {
  int i = blockIdx.x * TPB + threadIdx.x;
  if (i >= 512 * 320) return;
  int n = i / 320, k = i % 320;
  float v = (k < 256) ? mapf[n * 256 + k] : condf[n * 64 + (k - 256)];
  comb[n * 576 + 256 + k] = v;
}

// ---------- LSTM: 64 blocks, register-resident weights, data-tagged exchange ----------
__global__ __launch_bounds__(TPB, 1) void lstm_kernel(
    const float* __restrict__ iseq,
    const float* __restrict__ mw, const float* __restrict__ mb,
    const float* __restrict__ w_ih0, const float* __restrict__ w_hh0,
    const float* __restrict__ b_ih0, const float* __restrict__ b_hh0,
    const float* __restrict__ w_ih1, const float* __restrict__ w_hh1,
    const float* __restrict__ b_ih1, const float* __restrict__ b_hh1,
    unsigned long long* __restrict__ h0x,
    unsigned long long* __restrict__ h1x,
    float* __restrict__ comb) {
  const int tid = threadIdx.x;
  const int blkid = blockIdx.x;
  const int u0 = blkid * 4;

  __shared__ float xz[64][8][16];
  __shared__ __align__(16) char reg2[26112];
  __shared__ float bias1s[16];

  float (*embc)[8][32] = (float (*)[8][32])reg2;
  float* mwmb = (float*)(reg2 + 16384);
  unsigned short (*v0s)[256] = (unsigned short (*)[256])reg2;
  unsigned short (*w1h)[256] = (unsigned short (*)[256])(reg2 + 4096);
  float (*part0)[8][16] = (float (*)[8][16])(reg2 + 8192);
  float (*part1)[8][16] = (float (*)[8][16])(reg2 + 16384);
  float (*zg0)[16] = (float (*)[16])(reg2 + 24576);
  float (*zg1)[16] = (float (*)[16])(reg2 + 25088);

  const int r = tid & 15, ks = tid >> 4;
  const int R = (r >> 2) * 256 + u0 + (r & 3);

  float w0reg[16], w1reg[32], wtmp[32];
#pragma unroll
  for (int i = 0; i < 16; ++i) w0reg[i] = w_hh0[R * 256 + ks * 16 + i];
  if (ks < 8) {
#pragma unroll
    for (int i = 0; i < 32; ++i) w1reg[i] = w_ih1[R * 256 + ks * 32 + i];
  } else {
#pragma unroll
    for (int i = 0; i < 32; ++i) w1reg[i] = w_hh1[R * 256 + (ks - 8) * 32 + i];
  }
#pragma unroll
  for (int i = 0; i < 32; ++i) wtmp[i] = w_ih0[R * 32 + i];
  const float bias0r = b_ih0[R] + b_hh0[R];
  if (tid < 16) bias1s[tid] = b_ih1[R] + b_hh1[R];
  if (tid < 96) mwmb[tid] = (tid < 64) ? mw[tid] : mb[tid - 64];
  __syncthreads();

  for (int chunk = 0; chunk < 4; ++chunk) {
    if (tid < 128) {
      int pp = tid >> 3, b = tid & 7;
      int pg = chunk * 16 + pp;
      float s0 = iseq[(b * 64 + pg) * 2 + 0];
      float s1 = iseq[(b * 64 + pg) * 2 + 1];
      for (int k = 0; k < 32; ++k)
        embc[pp][b][k] = fmaxf(fmaf(mwmb[2 * k], s0, fmaf(mwmb[2 * k + 1], s1, mwmb[64 + k])), 0.f);
    }
    __syncthreads();
    {
      int pg = chunk * 16 + ks;
      for (int b = 0; b < 8; ++b) {
        float a = bias0r;
        const float* e = &embc[ks][b][0];
#pragma unroll
        for (int k = 0; k < 32; ++k) a = fmaf(wtmp[k], e[k], a);
        xz[pg][b][r] = a;
      }
    }
    __syncthreads();
  }

  float c0 = 0.f, c1 = 0.f;
  for (int p = 0; p <= 64; ++p) {
    if (p >= 1) {
      const unsigned tag0 = (unsigned)p, tag1 = (unsigned)(p - 1);
      const unsigned long long* s0p = &h0x[(size_t)(p - 1) * 1024 + tid * 4];
      const unsigned long long* s1p = (p >= 2) ? &h1x[(size_t)(p - 2) * 1024 + tid * 4] : nullptr;
      unsigned long long a0, a1, a2, a3, e0 = 0, e1 = 0, e2 = 0, e3 = 0;
      for (;;) {
        a0 = __hip_atomic_load(&s0p[0], __ATOMIC_RELAXED, __HIP_MEMORY_SCOPE_AGENT);
        a1 = __hip_atomic_load(&s0p[1], __ATOMIC_RELAXED, __HIP_MEMORY_SCOPE_AGENT);
        a2 = __hip_atomic_load(&s0p[2], __ATOMIC_RELAXED, __HIP_MEMORY_SCOPE_AGENT);
        a3 = __hip_atomic_load(&s0p[3], __ATOMIC_RELAXED, __HIP_MEMORY_SCOPE_AGENT);
        bool ok = ((unsigned)(a0 >> 32) == tag0) & ((unsigned)(a1 >> 32) == tag0) &
                  ((unsigned)(a2 >> 32) == tag0) & ((unsigned)(a3 >> 32) == tag0);
        if (p >= 2) {
          e0 = __hip_atomic_load(&s1p[0], __ATOMIC_RELAXED, __HIP_MEMORY_SCOPE_AGENT);
          e1 = __hip_atomic_load(&s1p[1], __ATOMIC_RELAXED, __HIP_MEMORY_SCOPE_AGENT);
          e2 = __hip_atomic_load(&s1p[2], __ATOMIC_RELAXED, __HIP_MEMORY_SCOPE_AGENT);
          e3 = __hip_atomic_load(&s1p[3], __ATOMIC_RELAXED, __HIP_MEMORY_SCOPE_AGENT);
          ok &= ((unsigned)(e0 >> 32) == tag1) & ((unsigned)(e1 >> 32) == tag1) &
                ((unsigned)(e2 >> 32) == tag1) & ((unsigned)(e3 >> 32) == tag1);
        }
        if (ok) break;
        __builtin_amdgcn_s_sleep(2);
      }
#pragma unroll
      for (int i = 0; i < 4; ++i) {
        int g = tid * 4 + i;
        int bb = (g & 15) >> 1, ub = (g >> 4) * 4 + (g & 1) * 2;
        unsigned long long va = (i == 0) ? a0 : (i == 1) ? a1 : (i == 2) ? a2 : a3;
        *(unsigned int*)&v0s[bb][ub] = (unsigned int)va;
        if (p >= 2) {
          unsigned long long ve = (i == 0) ? e0 : (i == 1) ? e1 : (i == 2) ? e2 : e3;
          *(unsigned int*)&w1h[bb][ub] = (unsigned int)ve;
        }
      }
    }
    if (p < 1) {
#pragma unroll
      for (int i = 0; i < 4; ++i) ((unsigned int*)v0s)[tid * 4 + i] = 0u;
    }
    if (p < 2) {
#pragma unroll
      for (int i = 0; i < 4; ++i) ((unsigned int*)w1h)[tid * 4 + i] = 0u;
    }
    __syncthreads();

    if (p < 64) {
#pragma unroll
      for (int b = 0; b < 8; ++b) {
        uint4 q0 = *(const uint4*)&v0s[b][ks * 16];
        uint4 q1 = *(const uint4*)&v0s[b][ks * 16 + 8];
        float a = 0.f;
        a = fma8(q0, &w0reg[0], a);
        a = fma8(q1, &w0reg[8], a);
        part0[ks][b][r] = a;
      }
    }
    if (p >= 1) {
      const unsigned short* sp = (ks < 8) ? &v0s[0][ks * 32] : &w1h[0][(ks - 8) * 32];
#pragma unroll
      for (int b = 0; b < 8; ++b) {
        const uint4* qp = (const uint4*)(sp + b * 256);
        float a = 0.f;
        a = fma8(qp[0], &w1reg[0], a);
        a = fma8(qp[1], &w1reg[8], a);
        a = fma8(qp[2], &w1reg[16], a);
        a = fma8(qp[3], &w1reg[24], a);
        part1[ks][b][r] = a;
      }
    }
    __syncthreads();

    if (tid < 128) {
      int b = tid >> 4, rr = tid & 15;
      if (p < 64) {
        float s = xz[p][b][rr];
#pragma unroll
        for (int k2 = 0; k2 < 16; ++k2) s += part0[k2][b][rr];
        zg0[b][rr] = s;
      }
    } else {
      int t2 = tid - 128, b = t2 >> 4, rr = t2 & 15;
      if (p >= 1) {
        float s = bias1s[rr];
#pragma unroll
        for (int k2 = 0; k2 < 16; ++k2) s += part1[k2][b][rr];
        zg1[b][rr] = s;
      }
    }
    __syncthreads();

    if (tid < 32) {
      if (p < 64) {
        int b = tid >> 2, uu = tid & 3;
        float zi = zg0[b][uu], zf = zg0[b][4 + uu], zgv = zg0[b][8 + uu], zo = zg0[b][12 + uu];
        c0 = sigf(zf) * c0 + sigf(zi) * tanhf(zgv);
        float h = sigf(zo) * tanhf(c0);
        float hp = __shfl_xor(h, 1);
        if (!(uu & 1)) {
          unsigned int d = (unsigned int)f2bf(h) | ((unsigned int)f2bf(hp) << 16);
          unsigned long long v = ((unsigned long long)(unsigned)(p + 1) << 32) | d;
          __hip_atomic_store(&h0x[(size_t)p * 1024 + blkid * 16 + b * 2 + (uu >> 1)], v,
                             __ATOMIC_RELAXED, __HIP_MEMORY_SCOPE_AGENT);
        }
      }
    } else if (tid < 64) {
      if (p >= 1) {
        int t2 = tid - 32, b = t2 >> 2, uu = t2 & 3;
        float zi = zg1[b][uu], zf = zg1[b][4 + uu], zgv = zg1[b][8 + uu], zo = zg1[b][12 + uu];
        c1 = sigf(zf) * c1 + sigf(zi) * tanhf(zgv);
        float h = sigf(zo) * tanhf(c1);
        comb[(size_t)(b * 64 + (p - 1)) * 576 + u0 + uu] = h;
        float hp = __shfl_xor(h, 1);
        if (!(uu & 1)) {
          unsigned int d = (unsigned int)f2bf(h) | ((unsigned int)f2bf(hp) << 16);
          unsigned long long v = ((unsigned long long)(unsigned)p << 32) | d;
          __hip_atomic_store(&h1x[(size_t)(p - 1) * 1024 + blkid * 16 + b * 2 + (uu >> 1)], v,
                             __ATOMIC_RELAXED, __HIP_MEMORY_SCOPE_AGENT);
        }
      }
    }
  }
}

// ---------- launcher ----------
extern "C" void kernel_launch(void* const* d_in, const int* in_sizes, int n_in,
                              void* d_out, int out_size, void* d_ws, size_t ws_size,
                              hipStream_t stream) {
  const float* fmap  = (const float*)d_in[0];
  const float* cond  = (const float*)d_in[1];
  const float* iseq  = (const float*)d_in[2];
  const float* steps = (const float*)d_in[3];
  const float* cw1 = (const float*)d_in[4];  const float* cb1 = (const float*)d_in[5];
  const float* g1  = (const float*)d_in[6];  const float* be1 = (const float*)d_in[7];
  const float* cw2 = (const float*)d_in[8];  const float* cb2 = (const float*)d_in[9];
  const float* g2  = (const float*)d_in[10]; const float* be2 = (const float*)d_in[11];
  const float* cw3 = (const float*)d_in[12]; const float* cb3 = (const float*)d_in[13];
  const float* g3  = (const float*)d_in[14]; const float* be3 = (const float*)d_in[15];
  const float* cw4 = (const float*)d_in[16]; const float* cb4 = (const float*)d_in[17];
  const float* g4  = (const float*)d_in[18]; const float* be4 = (const float*)d_in[19];
  const float* fw1 = (const float*)d_in[20]; const float* fb1 = (const float*)d_in[21];
  const float* fw2 = (const float*)d_in[22]; const float* fb2 = (const float*)d_in[23];
  const float* ew1 = (const float*)d_in[24]; const float* eb1 = (const float*)d_in[25];
  const float* ew2 = (const float*)d_in[26]; const float* eb2 = (const float*)d_in[27];
  const float* mw  = (const float*)d_in[28]; const float* mb  = (const float*)d_in[29];
  const float* w_ih0 = (const float*)d_in[30]; const float* w_hh0 = (const float*)d_in[31];
  const float* b_ih0 = (const float*)d_in[32]; const float* b_hh0 = (const float*)d_in[33];
  const float* w_ih1 = (const float*)d_in[34]; const float* w_hh1 = (const float*)d_in[35];
  const float* b_ih1 = (const float*)d_in[36]; const float* b_hh1 = (const float*)d_in[37];
  const float* xw1 = (const float*)d_in[38]; const float* xb1 = (const float*)d_in[39];
  const float* xw2 = (const float*)d_in[40]; const float* xb2 = (const float*)d_in[41];
  const float* ow  = (const float*)d_in[42]; const float* ob  = (const float*)d_in[43];

  float* ws = (float*)d_ws;
  unsigned short* y1bf  = (unsigned short*)ws;
  unsigned short* y2bf  = (unsigned short*)(ws + 16777216);
  unsigned short* y3bf  = (unsigned short*)(ws + 25165824);
  unsigned short* y4pre = (unsigned short*)(ws + 29360128);
  unsigned short* y4bn  = (unsigned short*)(ws + 31457280);
  unsigned short* fw1bf = (unsigned short*)(ws + 33554432);
  size_t base = 35651584;
  float* part  = ws + base; base += 16384;
  float* ss1   = ws + base; base += 32;
  float* ss2   = ws + base; base += 64;
  float* ss3   = ws + base; base += 128;
  float* ss4   = ws + base; base += 256;
  float* f1    = ws + base; base += 262144;
  float* mapf  = ws + base; base += 131072;
  float* enh   = ws + base; base += 3072;
  float* ceh   = ws + base; base += 65536;
  float* condf = ws + base; base += 32768;
  unsigned long long* h0x = (unsigned long long*)(ws + base); base += 131072;
  unsigned long long* h1x = (unsigned long long*)(ws + base); base += 131072;
  float* comb  = ws + base; base += 294912;
  float* cx1   = ws + base; base += 65536;
  float* cx2   = ws + base; base += 32768;
  unsigned short* wt2 = (unsigned short*)(ws + base); base += 2304;   // 4608 shorts
  unsigned short* wt3 = (unsigned short*)(ws + base); base += 9216;   // 18432 shorts
  unsigned short* wt4 = (unsigned short*)(ws + base); base += 36864;  // 73728 shorts

  // --- prep: weight transpose/cast ---
  prep_wt<<<378, TPB, 0, stream>>>(cw2, cw3, cw4, wt2, wt3, wt4);
  cast_bf16_kernel<<<4096, TPB, 0, stream>>>(fw1, fw1bf, 1048576);

  // --- encoder convs ---
  conv_mfma<3, 16, 128, 64, true><<<32768, TPB, 0, stream>>>(nullptr, fmap, iseq, nullptr, cw1, cb1, y1bf);
  stats_partial_bf16<<<16 * 64, TPB, 0, stream>>>(y1bf, part, 16, 4096);
  stats_final_kernel<<<16, 64, 0, stream>>>(part, g1, be1, ss1, 1.f / 2097152.f);
  conv_tap<16, 32, 1, 64, 32><<<8192, TPB, 0, stream>>>(y1bf, ss1, wt2, cb2, y2bf);
  stats_partial_bf16<<<32 * 64, TPB, 0, stream>>>(y2bf, part, 32, 1024);
  stats_final_kernel<<<32, 64, 0, stream>>>(part, g2, be2, ss2, 1.f / 524288.f);
  conv_tap<32, 64, 1, 32, 16><<<2048, TPB, 0, stream>>>(y2bf, ss2, wt3, cb3, y3bf);
  stats_partial_bf16<<<64 * 64, TPB, 0, stream>>>(y3bf, part, 64, 256);
  stats_final_kernel<<<64, 64, 0, stream>>>(part, g3, be3, ss3, 1.f / 131072.f);
  conv_tap<64, 32, 4, 16, 8><<<2048, TPB, 0, stream>>>(y3bf, ss3, wt4, cb4, y4pre);
  stats_partial_bf16<<<128 * 64, TPB, 0, stream>>>(y4pre, part, 128, 64);
  stats_final_kernel<<<128, 64, 0, stream>>>(part, g4, be4, ss4, 1.f / 32768.f);
  bnrelu_bf16b<<<2048, TPB, 0, stream>>>(y4pre, ss4, y4bn);

  // --- LSTM ---
  hipMemsetAsync(h0x, 0, 2 * 64 * 1024 * sizeof(unsigned long long), stream);
  lstm_kernel<<<NLB, TPB, 0, stream>>>(iseq, mw, mb,
                                       w_ih0, w_hh0, b_ih0, b_hh0,
                                       w_ih1, w_hh1, b_ih1, b_hh1,
                                       h0x, h1x, comb);

  // --- map-feature MLP ---
  fc1_mfma<<<dim3(8, 8), TPB, 0, stream>>>(y4bn, fw1bf, fb1, f1);
  gemm_m64<<<dim3(4, 8), TPB, 0, stream>>>(f1, fw2, fb2, mapf, 256, 512, 0);

  // --- condition encoder ---
  build_enh_kernel<<<12, TPB, 0, stream>>>(cond, steps, enh);
  gemm_m64<<<dim3(2, 8), TPB, 0, stream>>>(enh, ew1, eb1, ceh, 128, 6, 1);
  gemm_m64<<<dim3(1, 8), TPB, 0, stream>>>(ceh, ew2, eb2, condf, 64, 128, 0);

  // --- head ---
  build_comb2_kernel<<<640, TPB, 0, stream>>>(mapf, condf, comb);
  gemm_m64<<<dim3(2, 8), TPB, 0, stream>>>(comb, xw1, xb1, cx1, 128, 576, 1);
  gemm_m64<<<dim3(1, 8), TPB, 0, stream>>>(cx1, xw2, xb2, cx2, 64, 128, 1);
  gemm_m64<<<dim3(1, 8), TPB, 0, stream>>>(cx2, ow, ob, (float*)d_out, 2, 64, 0);
}